// Round 6
// baseline (3816.479 us; speedup 1.0000x reference)
//
#include <hip/hip_runtime.h>

#define DEVI __device__ __forceinline__

constexpr int N_  = 8192;
constexpr int K_  = 15;
constexpr int E_  = N_ * K_;     // 122880
constexpr int FTS = 12;
constexpr float DT_ = 0.25f;

typedef __attribute__((ext_vector_type(8))) short short8x;
typedef __attribute__((ext_vector_type(4))) float float4x;

union U8 { unsigned int u[4]; short8x v; };

DEVI float sigf(float x) { return 1.0f / (1.0f + __expf(-x)); }
DEVI float tanhf_fast(float x) { float e = __expf(2.f * x); return 1.f - 2.f / (e + 1.f); }
DEVI unsigned int f2u(float x) { union { float f; unsigned int u; } c; c.f = x; return c.u; }
DEVI float u2f(unsigned int x) { union { unsigned int u; float f; } c; c.u = x; return c.f; }

DEVI void split8(const float* __restrict__ s, short8x& hi8, short8x& lo8) {
  U8 ph, pl;
#pragma unroll
  for (int p = 0; p < 4; p++) {
    float a0 = s[2*p], a1 = s[2*p+1];
    unsigned int u0 = f2u(a0), u1 = f2u(a1);
    unsigned int h0 = u0 & 0xFFFF0000u, h1 = u1 & 0xFFFF0000u;
    ph.u[p] = (u0 >> 16) | h1;
    float l0 = a0 - u2f(h0), l1 = a1 - u2f(h1);
    pl.u[p] = (f2u(l0) >> 16) | (f2u(l1) & 0xFFFF0000u);
  }
  hi8 = ph.v; lo8 = pl.v;
}

// ---------------------------------------------------------------- zero accum
__global__ void k_zero(float* ss) {
  if (threadIdx.x < 13) ss[threadIdx.x] = 0.f;
}

// ---------------------------------------------------------------- init des to b_proj
__global__ __launch_bounds__(256) void k_init_des(const float* __restrict__ b_proj,
                                                  float* __restrict__ des) {
  int i = blockIdx.x * 256 + threadIdx.x;
  des[i*2]     = b_proj[0];
  des[i*2 + 1] = b_proj[1];
}

// ---------------------------------------------------------------- edge static
__global__ __launch_bounds__(256) void k_edge_static(
    const int* __restrict__ e1, const int* __restrict__ e2,
    const float* __restrict__ nsize, float* __restrict__ rad, float* __restrict__ szf)
{
  int e = blockIdx.x * 256 + threadIdx.x;
  if (e >= E_) return;
  int i1 = e1[e], i2 = e2[e];
  float s1x = nsize[i1*2+0], s1y = nsize[i1*2+1];
  float s2x = nsize[i2*2+0], s2y = nsize[i2*2+1];
  rad[e] = 0.5f * (sqrtf(s1x*s1x + s1y*s1y) + sqrtf(s2x*s2x + s2y*s2y));
  *(float4*)&szf[e*4] = make_float4(s1x, s1y, s2x, s2y);
}

// ---------------------------------------------------------------- transpose W_att1 -> [a][chan]
__global__ __launch_bounds__(256) void k_prep_attT(const float* __restrict__ W_att1,
                                                   float* __restrict__ wT) {
  int i = blockIdx.x * 256 + threadIdx.x;
  int chan = i >> 4, a = i & 15;
  wT[a * 128 + chan] = W_att1[i];
}

// ---------------------------------------------------------------- generic split-bf16 B-fragment prep
__global__ __launch_bounds__(256) void k_prep(
    const float* __restrict__ WA, const float* __restrict__ WB,
    int mode, int split, int wA, int wB, int Ktot, int NT, int nfrag,
    unsigned short* __restrict__ out)
{
  int t = blockIdx.x * 256 + threadIdx.x;
  int fid = t >> 6, L = t & 63;
  if (fid >= nfrag) return;
  int ks = fid / NT, nt = fid % NT;
  int k0 = ks * 32 + (L >> 4) * 8;
  int n  = nt * 16 + (L & 15);
  unsigned int hi[4], lo[4];
#pragma unroll
  for (int p = 0; p < 4; p++) {
    float w0 = 0.f, w1 = 0.f;
    int ka = k0 + 2*p, kb = ka + 1;
    if (mode == 0) {
      if (ka < Ktot) w0 = (ka < split) ? WA[(size_t)ka*wA + n] : WB[(size_t)(ka-split)*wB + n];
      if (kb < Ktot) w1 = (kb < split) ? WA[(size_t)kb*wA + n] : WB[(size_t)(kb-split)*wB + n];
    } else {
      if (ka < Ktot) w0 = (n < split) ? WA[(size_t)ka*wA + n] : WB[(size_t)ka*wB + (n-split)];
      if (kb < Ktot) w1 = (n < split) ? WA[(size_t)kb*wA + n] : WB[(size_t)kb*wB + (n-split)];
    }
    unsigned int u0 = f2u(w0), u1 = f2u(w1);
    unsigned int h0 = u0 & 0xFFFF0000u, h1 = u1 & 0xFFFF0000u;
    hi[p] = (u0 >> 16) | h1;
    float l0 = w0 - u2f(h0), l1 = w1 - u2f(h1);
    lo[p] = (f2u(l0) >> 16) | (f2u(l1) & 0xFFFF0000u);
  }
  size_t base = (size_t)(fid * 2) * 512 + (size_t)L * 8;
  *(uint4*)(out + base)       = make_uint4(hi[0], hi[1], hi[2], hi[3]);
  *(uint4*)(out + base + 512) = make_uint4(lo[0], lo[1], lo[2], lo[3]);
}

// ---------------------------------------------------------------- xz GEMM (once)
__global__ __launch_bounds__(256) void k_xz_mfma(
    const float* __restrict__ hist, const float* __restrict__ z,
    const unsigned short* __restrict__ wB,
    const float* __restrict__ b_gh, const float* __restrict__ b_gih,
    float* __restrict__ gh0, float* __restrict__ gi)
{
  __shared__ __align__(16) float Abuf[64][36];
  const int tid = threadIdx.x;
  const int w = tid >> 6, lane = tid & 63;
  const int m = lane & 15, q = lane >> 4;
  const int n0 = blockIdx.x * 64;
  const int r_ = tid >> 2, c_ = (tid & 3) * 8;
  float4x acc[16];
#pragma unroll
  for (int tl = 0; tl < 16; tl++) acc[tl] = (float4x){0.f,0.f,0.f,0.f};

  for (int ks = 0; ks < 9; ks++) {
    __syncthreads();
    {
      int kk = ks*32 + c_;
      int n = n0 + r_;
      float4 v0, v1;
      if (kk < 256) {
        v0 = *(const float4*)&hist[(size_t)n*256 + kk];
        v1 = *(const float4*)&hist[(size_t)n*256 + kk + 4];
      } else if (kk == 256) {
        v0 = *(const float4*)&z[n*8];
        v1 = *(const float4*)&z[n*8 + 4];
      } else {
        v0 = make_float4(0,0,0,0); v1 = v0;
      }
      *(float4*)&Abuf[r_][c_]     = v0;
      *(float4*)&Abuf[r_][c_ + 4] = v1;
    }
    __syncthreads();
    short8x aHi, aLo;
    split8(&Abuf[w*16 + m][q*8], aHi, aLo);
#pragma unroll
    for (int tl = 0; tl < 16; tl++) {
      int nt = blockIdx.y*16 + tl;
      size_t off = (size_t)((ks*64 + nt)*2) * 512 + (size_t)lane*8;
      short8x bh = *(const short8x*)(wB + off);
      short8x bl = *(const short8x*)(wB + off + 512);
      acc[tl] = __builtin_amdgcn_mfma_f32_16x16x32_bf16(aHi, bl, acc[tl], 0, 0, 0);
      acc[tl] = __builtin_amdgcn_mfma_f32_16x16x32_bf16(aLo, bh, acc[tl], 0, 0, 0);
      acc[tl] = __builtin_amdgcn_mfma_f32_16x16x32_bf16(aHi, bh, acc[tl], 0, 0, 0);
    }
  }
#pragma unroll
  for (int tl = 0; tl < 16; tl++) {
    int col = (blockIdx.y*16 + tl)*16 + m;
    float bias = (col < 256) ? b_gh[col] : b_gih[col - 256];
#pragma unroll
    for (int i = 0; i < 4; i++) {
      int n = n0 + w*16 + q*4 + i;
      float v = acc[tl][i] + bias;
      if (col < 256) gh0[(size_t)n*256 + col] = v;
      else           gi[(size_t)n*768 + col - 256] = v;
    }
  }
}

// ---------------------------------------------------------------- GRU core (shared)
DEVI void gru_core(float (*Abuf)[36], int tid, int n0, int j0,
                   const float* __restrict__ h_in, const unsigned short* __restrict__ wB,
                   const float* __restrict__ b_hh, const float* __restrict__ gi,
                   const float* __restrict__ W_proj, float* __restrict__ des_t,
                   float* __restrict__ h_out)
{
  const int w = tid >> 6, lane = tid & 63;
  const int m = lane & 15, q = lane >> 4;
  const int r_ = tid >> 2, c_ = (tid & 3) * 8;
  float4x acc[12];
#pragma unroll
  for (int tl = 0; tl < 12; tl++) acc[tl] = (float4x){0.f,0.f,0.f,0.f};

  for (int ks = 0; ks < 8; ks++) {
    __syncthreads();
    {
      int kk = ks*32 + c_;
      int n = n0 + r_;
      *(float4*)&Abuf[r_][c_]     = *(const float4*)&h_in[(size_t)n*256 + kk];
      *(float4*)&Abuf[r_][c_ + 4] = *(const float4*)&h_in[(size_t)n*256 + kk + 4];
    }
    __syncthreads();
    short8x aHi, aLo;
    split8(&Abuf[w*16 + m][q*8], aHi, aLo);
#pragma unroll
    for (int tl = 0; tl < 12; tl++) {
      int g = tl >> 2, jt = tl & 3;
      int nt = g*16 + (j0 >> 4) + jt;
      size_t off = (size_t)((ks*48 + nt)*2) * 512 + (size_t)lane*8;
      short8x bh = *(const short8x*)(wB + off);
      short8x bl = *(const short8x*)(wB + off + 512);
      acc[tl] = __builtin_amdgcn_mfma_f32_16x16x32_bf16(aHi, bl, acc[tl], 0, 0, 0);
      acc[tl] = __builtin_amdgcn_mfma_f32_16x16x32_bf16(aLo, bh, acc[tl], 0, 0, 0);
      acc[tl] = __builtin_amdgcn_mfma_f32_16x16x32_bf16(aHi, bh, acc[tl], 0, 0, 0);
    }
  }
  float pd0[4] = {0,0,0,0}, pd1[4] = {0,0,0,0};
#pragma unroll
  for (int jt = 0; jt < 4; jt++) {
    int j = j0 + jt*16 + m;
    float br = b_hh[j], bz = b_hh[256 + j], bn = b_hh[512 + j];
    float wp0 = W_proj[j*2], wp1 = W_proj[j*2 + 1];
#pragma unroll
    for (int i = 0; i < 4; i++) {
      int n = n0 + w*16 + q*4 + i;
      float ir  = gi[(size_t)n*768 + j];
      float iz  = gi[(size_t)n*768 + 256 + j];
      float inn = gi[(size_t)n*768 + 512 + j];
      float hold = h_in[(size_t)n*256 + j];
      float r = sigf(ir + acc[0*4 + jt][i] + br);
      float u = sigf(iz + acc[1*4 + jt][i] + bz);
      float nh = (1.f - u) * tanhf_fast(inn + r * (acc[2*4 + jt][i] + bn)) + u * hold;
      h_out[(size_t)n*256 + j] = nh;
      pd0[i] += nh * wp0;
      pd1[i] += nh * wp1;
    }
  }
#pragma unroll
  for (int off = 1; off < 16; off <<= 1) {
#pragma unroll
    for (int i = 0; i < 4; i++) {
      pd0[i] += __shfl_xor(pd0[i], off);
      pd1[i] += __shfl_xor(pd1[i], off);
    }
  }
  if (m == 0) {
#pragma unroll
    for (int i = 0; i < 4; i++) {
      int n = n0 + w*16 + q*4 + i;
      atomicAdd(&des_t[n*2],     pd0[i]);
      atomicAdd(&des_t[n*2 + 1], pd1[i]);
    }
  }
}

// ---------------------------------------------------------------- standalone GRU step (prologue)
__global__ __launch_bounds__(256) void k_gru_mfma(
    const float* __restrict__ h_in, const unsigned short* __restrict__ wB,
    const float* __restrict__ b_hh, const float* __restrict__ gi,
    const float* __restrict__ W_proj, float* __restrict__ des_t,
    float* __restrict__ h_out)
{
  __shared__ __align__(16) float Abuf[64][36];
  gru_core(Abuf, threadIdx.x, blockIdx.x * 64, blockIdx.y * 64,
           h_in, wB, b_hh, gi, W_proj, des_t, h_out);
}

// ---------------------------------------------------------------- LSTM cell (MFMA), j-tile = 32 for occupancy
__global__ __launch_bounds__(256) void k_lstm_mfma(
    const float* __restrict__ ctxg, const float* __restrict__ h_in,
    const unsigned short* __restrict__ wB,
    const float* __restrict__ b_ih, const float* __restrict__ b_hh,
    float* __restrict__ c_st, float* __restrict__ h_out)
{
  __shared__ __align__(16) float Abuf[64][36];
  const int tid = threadIdx.x;
  const int w = tid >> 6, lane = tid & 63;
  const int m = lane & 15, q = lane >> 4;
  const int n0 = blockIdx.x * 64;
  const int j0 = blockIdx.y * 32;
  const int r_ = tid >> 2, c_ = (tid & 3) * 8;
  float4x acc[8];
#pragma unroll
  for (int tl = 0; tl < 8; tl++) acc[tl] = (float4x){0.f,0.f,0.f,0.f};

  for (int ks = 0; ks < 12; ks++) {
    __syncthreads();
    {
      int kk = ks*32 + c_;
      int n = n0 + r_;
      float4 v0, v1;
      if (kk < 128) {
        v0 = *(const float4*)&ctxg[(size_t)n*128 + kk];
        v1 = *(const float4*)&ctxg[(size_t)n*128 + kk + 4];
      } else {
        v0 = *(const float4*)&h_in[(size_t)n*256 + kk - 128];
        v1 = *(const float4*)&h_in[(size_t)n*256 + kk - 124];
      }
      *(float4*)&Abuf[r_][c_]     = v0;
      *(float4*)&Abuf[r_][c_ + 4] = v1;
    }
    __syncthreads();
    short8x aHi, aLo;
    split8(&Abuf[w*16 + m][q*8], aHi, aLo);
#pragma unroll
    for (int tl = 0; tl < 8; tl++) {
      int g = tl >> 1, jt = tl & 1;
      int nt = g*16 + (j0 >> 4) + jt;
      size_t off = (size_t)((ks*64 + nt)*2) * 512 + (size_t)lane*8;
      short8x bh = *(const short8x*)(wB + off);
      short8x bl = *(const short8x*)(wB + off + 512);
      acc[tl] = __builtin_amdgcn_mfma_f32_16x16x32_bf16(aHi, bl, acc[tl], 0, 0, 0);
      acc[tl] = __builtin_amdgcn_mfma_f32_16x16x32_bf16(aLo, bh, acc[tl], 0, 0, 0);
      acc[tl] = __builtin_amdgcn_mfma_f32_16x16x32_bf16(aHi, bh, acc[tl], 0, 0, 0);
    }
  }
#pragma unroll
  for (int jt = 0; jt < 2; jt++) {
    int j = j0 + jt*16 + m;
    float bi = b_ih[j]       + b_hh[j];
    float bf = b_ih[256 + j] + b_hh[256 + j];
    float bg = b_ih[512 + j] + b_hh[512 + j];
    float bo = b_ih[768 + j] + b_hh[768 + j];
#pragma unroll
    for (int i = 0; i < 4; i++) {
      int n = n0 + w*16 + q*4 + i;
      float g_i = sigf(acc[0*2 + jt][i] + bi);
      float g_f = sigf(acc[1*2 + jt][i] + bf);
      float g_g = tanhf_fast(acc[2*2 + jt][i] + bg);
      float g_o = sigf(acc[3*2 + jt][i] + bo);
      float cv = g_f * c_st[(size_t)n*256 + j] + g_i * g_g;
      c_st[(size_t)n*256 + j] = cv;
      h_out[(size_t)n*256 + j] = g_o * tanhf_fast(cv);
    }
  }
}

// ---------------------------------------------------------------- action MLP: 32 nodes/block, hidden split across wave pairs
__global__ __launch_bounds__(256) void k_action_mfma(
    const float* __restrict__ h, const float* __restrict__ z,
    const float* __restrict__ rel, const float* __restrict__ nwp, const float* __restrict__ nwp2,
    const unsigned short* __restrict__ wB, const float* __restrict__ b_a1,
    const float* __restrict__ W_a2, const float* __restrict__ b_a2,
    float* __restrict__ prev, float* __restrict__ prev_st,
    float* __restrict__ outS, float* __restrict__ outU)
{
  __shared__ __align__(16) float Abuf[32][36];
  __shared__ float sm_p[2][16][2];
  const int tid = threadIdx.x;
  const int w = tid >> 6, lane = tid & 63;
  const int m = lane & 15, q = lane >> 4;
  const int ng = w >> 1, hh = w & 1;
  const int n0 = blockIdx.x * 32;
  const int r_ = tid >> 3, c_ = (tid & 7) * 4;
  float4x acc[8];
#pragma unroll
  for (int j = 0; j < 8; j++) acc[j] = (float4x){0.f,0.f,0.f,0.f};

  for (int ks = 0; ks < 9; ks++) {
    __syncthreads();
    {
      int kk = ks*32 + c_;
      int n = n0 + r_;
      float4 v;
      if (kk < 256)      v = *(const float4*)&h[(size_t)n*256 + kk];
      else if (kk == 256) v = *(const float4*)&z[n*8];
      else if (kk == 260) v = *(const float4*)&z[n*8 + 4];
      else if (kk == 264) v = *(const float4*)&rel[n*4];
      else if (kk == 268) {
        float2 w1 = *(const float2*)&nwp[n*2];
        float2 w2 = *(const float2*)&nwp2[n*2];
        v = make_float4(w1.x, w1.y, w2.x, w2.y);
      } else v = make_float4(0,0,0,0);
      *(float4*)&Abuf[r_][c_] = v;
    }
    __syncthreads();
    short8x aHi, aLo;
    split8(&Abuf[ng*16 + m][q*8], aHi, aLo);
#pragma unroll
    for (int j = 0; j < 8; j++) {
      int tl = hh*8 + j;
      size_t off = (size_t)((ks*16 + tl)*2) * 512 + (size_t)lane*8;
      short8x bh = *(const short8x*)(wB + off);
      short8x bl = *(const short8x*)(wB + off + 512);
      acc[j] = __builtin_amdgcn_mfma_f32_16x16x32_bf16(aHi, bl, acc[j], 0, 0, 0);
      acc[j] = __builtin_amdgcn_mfma_f32_16x16x32_bf16(aLo, bh, acc[j], 0, 0, 0);
      acc[j] = __builtin_amdgcn_mfma_f32_16x16x32_bf16(aHi, bh, acc[j], 0, 0, 0);
    }
  }
  float p0[4] = {0,0,0,0}, p1[4] = {0,0,0,0};
#pragma unroll
  for (int j = 0; j < 8; j++) {
    int col = (hh*8 + j)*16 + m;
    float ba = b_a1[col];
    float2 w2 = *(const float2*)&W_a2[col*2];
#pragma unroll
    for (int i = 0; i < 4; i++) {
      float hv = fmaxf(acc[j][i] + ba, 0.f);
      p0[i] += hv * w2.x;
      p1[i] += hv * w2.y;
    }
  }
#pragma unroll
  for (int off = 1; off < 16; off <<= 1) {
#pragma unroll
    for (int i = 0; i < 4; i++) {
      p0[i] += __shfl_xor(p0[i], off);
      p1[i] += __shfl_xor(p1[i], off);
    }
  }
  if (hh == 1 && m == 0) {
#pragma unroll
    for (int i = 0; i < 4; i++) {
      sm_p[ng][q*4 + i][0] = p0[i];
      sm_p[ng][q*4 + i][1] = p1[i];
    }
  }
  __syncthreads();
  if (hh == 0 && m == 0) {
    float ba0 = b_a2[0], ba1 = b_a2[1];
    const float hd = 0.5f * DT_ * DT_;
#pragma unroll
    for (int i = 0; i < 4; i++) {
      int n = n0 + ng*16 + q*4 + i;
      float ux = tanhf_fast(p0[i] + sm_p[ng][q*4 + i][0] + ba0);
      float uy = tanhf_fast(p1[i] + sm_p[ng][q*4 + i][1] + ba1);
      float4 pv = *(const float4*)&prev[n*4];
      float4 ps = *(const float4*)&prev_st[n*4];
      float4 npv, nps;
      npv.x = pv.x + pv.z*DT_ + ux*hd;
      npv.y = pv.y + pv.w*DT_ + uy*hd;
      npv.z = pv.z + ux*DT_;
      npv.w = pv.w + uy*DT_;
      nps.x = ps.x + ps.z*DT_ + ux*hd;
      nps.y = ps.y + ps.w*DT_ + uy*hd;
      nps.z = ps.z + ux*DT_;
      nps.w = ps.w + uy*DT_;
      *(float4*)&prev[n*4] = npv;
      *(float4*)&prev_st[n*4] = nps;
      *(float4*)&outS[(size_t)n*4] = npv;
      outU[n*2]     = ux;
      outU[n*2 + 1] = uy;
    }
  }
}

// ---------------------------------------------------------------- LSTM h0/c0 + prev copies
__global__ __launch_bounds__(256) void k_init_hc(
    const float* __restrict__ x_last, const float* __restrict__ x_st_last,
    const float* __restrict__ W_h0, const float* __restrict__ b_h0,
    const float* __restrict__ W_c0, const float* __restrict__ b_c0,
    float* __restrict__ h, float* __restrict__ c,
    float* __restrict__ prev, float* __restrict__ prev_st)
{
  const int n = blockIdx.x;
  const int j = threadIdx.x;
  float x0 = x_st_last[n*4], x1 = x_st_last[n*4+1], x2 = x_st_last[n*4+2], x3 = x_st_last[n*4+3];
  h[(size_t)n*256 + j] = b_h0[j] + x0*W_h0[j] + x1*W_h0[256+j] + x2*W_h0[512+j] + x3*W_h0[768+j];
  c[(size_t)n*256 + j] = b_c0[j] + x0*W_c0[j] + x1*W_c0[256+j] + x2*W_c0[512+j] + x3*W_c0[768+j];
  if (j < 4) prev[n*4 + j] = x_last[n*4 + j];
  else if (j < 8) prev_st[n*4 + (j-4)] = x_st_last[n*4 + (j-4)];
}

// ---------------------------------------------------------------- FUSED: edge (blocks 0..1023, 8 nodes/block) | GRU (blocks 1024..1279, 2 tiles/block)
__global__ __launch_bounds__(512, 8) void k_edge_gru(
    const float* __restrict__ prev, const float* __restrict__ prev_st,
    const float* __restrict__ x_st_last,
    const float* __restrict__ szf, const float* __restrict__ rad,
    const int* __restrict__ nobs, const int* __restrict__ e1, const int* __restrict__ e2,
    const float* __restrict__ W_e1, const float* __restrict__ b_e1,
    const unsigned short* __restrict__ wsB, const float* __restrict__ b_e2,
    const float* __restrict__ wattT, const float* __restrict__ W_att2,
    const float* __restrict__ v_att,
    const float* __restrict__ des_p, const float* __restrict__ des_t,
    const float* __restrict__ des_n,
    float* __restrict__ relg, float* __restrict__ nwp, float* __restrict__ nwp2,
    float* __restrict__ ctx, float* __restrict__ ss_t, float* __restrict__ cc,
    const float* __restrict__ g_hin, const unsigned short* __restrict__ wBg,
    const float* __restrict__ b_ghh, const float* __restrict__ gi,
    const float* __restrict__ W_proj, float* __restrict__ des_g,
    float* __restrict__ g_hout, int gru_on)
{
  // LDS: stage[4096] | feats[1024]@4096 | flags[128]@5120 | relv[32]@5248
  //      w1T[2048]@5280 | watt2[64]@7328 | vatt[16]@7392 | red[16]@7408 -> 7424 floats
  __shared__ __align__(16) float smem[7424];
  const int tid = threadIdx.x;

  if (blockIdx.x >= 1024) {
    if (!gru_on) return;
    int half = tid >> 8;
    int st = tid & 255;
    int b = (blockIdx.x - 1024) * 2 + half;
    gru_core((float(*)[36])(smem + half * 2304), st, (b & 127) * 64, (b >> 7) * 64,
             g_hin, wBg, b_ghh, gi, W_proj, des_g, g_hout);
    return;
  }

  float* sm_stage = smem;
  float* sm_feats = smem + 4096;
  float* sm_flags = smem + 5120;
  float* sm_relv  = smem + 5248;
  float* sm_w1T   = smem + 5280;
  float* sm_watt2 = smem + 7328;
  float* sm_vatt  = smem + 7392;
  float* sm_red   = smem + 7408;

  const int n0  = blockIdx.x * 8;
  const int lane = tid & 63;
  const int g    = tid >> 6;
  const int q = lane >> 4, m = lane & 15;

  // ---- P0
  for (int i = tid; i < 2048; i += 512) sm_w1T[i] = wattT[i];

  if (tid < 128) {
    float v = 0.f;
    if (tid < 120) {
      int gg = tid / 15, k = tid % 15;
      int idx = nobs[(n0 + gg) * 15 + k];
      float f[8] = {0,0,0,0,0,0,0,0};
      float fl = 0.f;
      if (idx > 0) {
        int e = idx - 1;
        int i1 = e1[e], i2 = e2[e];
#pragma unroll
        for (int d = 0; d < 4; d++) f[d] = prev[i2*4 + d] - prev[i1*4 + d];
        float4 sz = *(const float4*)&szf[(size_t)e*4];
        f[4] = sz.x; f[5] = sz.y; f[6] = sz.z; f[7] = sz.w;
        fl = 1.f;
        float dist = sqrtf(f[0]*f[0] + f[1]*f[1]);
        v = fmaxf(rad[e] - dist, 0.f);
      }
#pragma unroll
      for (int d = 0; d < 8; d++) sm_feats[(gg*16 + k)*8 + d] = f[d];
      sm_flags[gg*16 + k] = fl;
    } else {
      int gg = tid - 120;
#pragma unroll
      for (int d = 0; d < 8; d++) sm_feats[(gg*16 + 15)*8 + d] = 0.f;
      sm_flags[gg*16 + 15] = 0.f;
    }
#pragma unroll
    for (int off = 32; off; off >>= 1) v += __shfl_down(v, off);
    if (lane == 0) sm_red[8 + (tid >> 6)] = v;
  } else if (tid < 136) {
    int gg = tid - 128;
    int n = n0 + gg;
    float4 ps = *(const float4*)&prev_st[n*4];
    float r0, r1, r2, r3;
    if (des_p) {
      float4 xs = *(const float4*)&x_st_last[n*4];
      r0 = ps.x - xs.x - des_p[n*2];
      r1 = ps.y - xs.y - des_p[n*2 + 1];
      r2 = ps.z - xs.z;
      r3 = ps.w - xs.w;
    } else { r0 = ps.x; r1 = ps.y; r2 = ps.z; r3 = ps.w; }
    sm_relv[gg*4+0] = r0; sm_relv[gg*4+1] = r1; sm_relv[gg*4+2] = r2; sm_relv[gg*4+3] = r3;
    *(float4*)&relg[n*4] = make_float4(r0, r1, r2, r3);
    nwp[n*2]      = des_t[n*2]     - ps.x;
    nwp[n*2 + 1]  = des_t[n*2 + 1] - ps.y;
    nwp2[n*2]     = des_n[n*2]     - ps.x;
    nwp2[n*2 + 1] = des_n[n*2 + 1] - ps.y;
    sm_red[gg] = r0*r0 + r1*r1;
  } else if (tid >= 192 && tid < 208) {
    sm_vatt[tid - 192] = v_att[tid - 192];
  } else if (tid >= 256 && tid < 320) {
    sm_watt2[tid - 256] = W_att2[tid - 256];
  }
  __syncthreads();
  if (tid == 136) atomicAdd(cc, sm_red[8] + sm_red[9]);
  if (tid == 137) atomicAdd(ss_t, sm_red[0] + sm_red[1] + sm_red[2] + sm_red[3]
                                + sm_red[4] + sm_red[5] + sm_red[6] + sm_red[7]);

  // ---- P1+P2 fused over ks: hidden (per-ks VALU) + staged-B MFMA
  float f[8];
  {
    const float4 fa = *(const float4*)&sm_feats[(g*16 + m)*8];
    const float4 fb = *(const float4*)&sm_feats[(g*16 + m)*8 + 4];
    f[0]=fa.x; f[1]=fa.y; f[2]=fa.z; f[3]=fa.w; f[4]=fb.x; f[5]=fb.y; f[6]=fb.z; f[7]=fb.w;
  }
  float4x encR[8];
#pragma unroll
  for (int nt = 0; nt < 8; nt++) encR[nt] = (float4x){0.f,0.f,0.f,0.f};
  const float4* We14 = (const float4*)W_e1;
  const float4* Be14 = (const float4*)b_e1;
  const unsigned short* sb = (const unsigned short*)sm_stage;

  for (int ks = 0; ks < 8; ks++) {
    __syncthreads();
    {
      const uint4* src = (const uint4*)(wsB + (size_t)ks * 8192);
      uint4* dst = (uint4*)sm_stage;
      dst[tid]       = src[tid];
      dst[tid + 512] = src[tid + 512];
    }
    short8x aHi, aLo;
    {
      float h8[8];
      float4 b0 = Be14[8*ks + 2*q];
      float4 b1 = Be14[8*ks + 2*q + 1];
      h8[0]=b0.x; h8[1]=b0.y; h8[2]=b0.z; h8[3]=b0.w; h8[4]=b1.x; h8[5]=b1.y; h8[6]=b1.z; h8[7]=b1.w;
#pragma unroll
      for (int d = 0; d < 8; d++) {
        float4 wa = We14[d*64 + ks*8 + 2*q];
        float4 wb = We14[d*64 + ks*8 + 2*q + 1];
        h8[0] += f[d]*wa.x; h8[1] += f[d]*wa.y; h8[2] += f[d]*wa.z; h8[3] += f[d]*wa.w;
        h8[4] += f[d]*wb.x; h8[5] += f[d]*wb.y; h8[6] += f[d]*wb.z; h8[7] += f[d]*wb.w;
      }
#pragma unroll
      for (int p = 0; p < 8; p++) h8[p] = fmaxf(h8[p], 0.f);
      split8(h8, aHi, aLo);
    }
    __syncthreads();
#pragma unroll
    for (int nt = 0; nt < 8; nt++) {
      short8x bh = *(const short8x*)(sb + nt*1024 + lane*8);
      short8x bl = *(const short8x*)(sb + nt*1024 + 512 + lane*8);
      encR[nt] = __builtin_amdgcn_mfma_f32_16x16x32_bf16(aHi, bl, encR[nt], 0, 0, 0);
      encR[nt] = __builtin_amdgcn_mfma_f32_16x16x32_bf16(aLo, bh, encR[nt], 0, 0, 0);
      encR[nt] = __builtin_amdgcn_mfma_f32_16x16x32_bf16(aHi, bh, encR[nt], 0, 0, 0);
    }
  }
  float4x fl4 = *(const float4x*)&sm_flags[g*16 + q*4];
#pragma unroll
  for (int nt = 0; nt < 8; nt++) {
    float b2 = b_e2[nt*16 + m];
#pragma unroll
    for (int i = 0; i < 4; i++) encR[nt][i] = (encR[nt][i] + b2) * fl4[i];
  }

  // ---- P3: score partials
  float4x part[16];
#pragma unroll
  for (int a = 0; a < 16; a++) part[a] = (float4x){0.f,0.f,0.f,0.f};
#pragma unroll
  for (int a = 0; a < 16; a++) {
#pragma unroll
    for (int nt = 0; nt < 8; nt++) {
      float wv = sm_w1T[a*128 + nt*16 + m];
      part[a] = part[a] + encR[nt] * wv;
    }
  }

  // ---- P4: halving-exchange over m
  const bool s8 = (m & 8) != 0, s4b = (m & 4) != 0, s2b = (m & 2) != 0, s1b = (m & 1) != 0;
  float4x c8[8];
#pragma unroll
  for (int a = 0; a < 8; a++) {
    float4x mi, sd, rc;
#pragma unroll
    for (int e = 0; e < 4; e++) {
      mi[e] = s8 ? part[a+8][e] : part[a][e];
      sd[e] = s8 ? part[a][e] : part[a+8][e];
      rc[e] = __shfl_xor(sd[e], 8);
    }
    c8[a] = mi + rc;
  }
  float4x c4[4];
#pragma unroll
  for (int a = 0; a < 4; a++) {
    float4x mi, sd, rc;
#pragma unroll
    for (int e = 0; e < 4; e++) {
      mi[e] = s4b ? c8[a+4][e] : c8[a][e];
      sd[e] = s4b ? c8[a][e] : c8[a+4][e];
      rc[e] = __shfl_xor(sd[e], 4);
    }
    c4[a] = mi + rc;
  }
  float4x c2[2];
#pragma unroll
  for (int a = 0; a < 2; a++) {
    float4x mi, sd, rc;
#pragma unroll
    for (int e = 0; e < 4; e++) {
      mi[e] = s2b ? c4[a+2][e] : c4[a][e];
      sd[e] = s2b ? c4[a][e] : c4[a+2][e];
      rc[e] = __shfl_xor(sd[e], 2);
    }
    c2[a] = mi + rc;
  }
  float4x c1;
  {
    float4x mi, sd, rc;
#pragma unroll
    for (int e = 0; e < 4; e++) {
      mi[e] = s1b ? c2[1][e] : c2[0][e];
      sd[e] = s1b ? c2[0][e] : c2[1][e];
      rc[e] = __shfl_xor(sd[e], 1);
    }
    c1 = mi + rc;
  }

  // ---- P5: softmax + ctx
  float relw;
  {
    float4 rv = *(const float4*)&sm_relv[g*4];
    relw = rv.x * sm_watt2[m] + rv.y * sm_watt2[16 + m]
         + rv.z * sm_watt2[32 + m] + rv.w * sm_watt2[48 + m];
  }
  float vat = sm_vatt[m];
  float val[4];
#pragma unroll
  for (int i = 0; i < 4; i++) val[i] = tanhf_fast(c1[i] + relw) * vat;
#pragma unroll
  for (int msk = 1; msk < 16; msk <<= 1) {
#pragma unroll
    for (int i = 0; i < 4; i++) val[i] += __shfl_xor(val[i], msk);
  }
  if (q == 3) val[3] = -3.0e38f;
  float mx = fmaxf(fmaxf(val[0], val[1]), fmaxf(val[2], val[3]));
  mx = fmaxf(mx, __shfl_xor(mx, 16));
  mx = fmaxf(mx, __shfl_xor(mx, 32));
  float4x ev;
  float ssum = 0.f;
#pragma unroll
  for (int i = 0; i < 4; i++) { ev[i] = __expf(val[i] - mx); ssum += ev[i]; }
  ssum += __shfl_xor(ssum, 16);
  ssum += __shfl_xor(ssum, 32);
  float inv = 1.f / ssum;
#pragma unroll
  for (int i = 0; i < 4; i++) ev[i] *= inv;

  float cpart[8];
#pragma unroll
  for (int nt = 0; nt < 8; nt++) {
    float cv = ev[0]*encR[nt][0] + ev[1]*encR[nt][1] + ev[2]*encR[nt][2] + ev[3]*encR[nt][3];
    cv += __shfl_xor(cv, 16);
    cv += __shfl_xor(cv, 32);
    cpart[nt] = cv;
  }
  float v0 = (q == 0) ? cpart[0] : (q == 1) ? cpart[2] : (q == 2) ? cpart[4] : cpart[6];
  float v1 = (q == 0) ? cpart[1] : (q == 1) ? cpart[3] : (q == 2) ? cpart[5] : cpart[7];
  size_t cb = (size_t)(n0 + g) * 128 + q*32 + m;
  ctx[cb]      = v0;
  ctx[cb + 16] = v1;
}

// ---------------------------------------------------------------- finalize scalars
__global__ void k_final(const float* __restrict__ ss, float* __restrict__ out) {
  if (threadIdx.x == 0) {
    float t = 0.f;
    for (int i = 0; i < FTS; i++) t += sqrtf(ss[i]);
    out[(size_t)FTS * N_ * 6]     = t / (float)N_;
    out[(size_t)FTS * N_ * 6 + 1] = ss[FTS];
  }
}

// ================================================================ launch
extern "C" void kernel_launch(void* const* d_in, const int* in_sizes, int n_in,
                              void* d_out, int out_size, void* d_ws, size_t ws_size,
                              hipStream_t stream) {
  (void)in_sizes; (void)n_in; (void)out_size;
  const float* x_last    = (const float*)d_in[0];
  const float* x_st_last = (const float*)d_in[1];
  const float* hist_enc  = (const float*)d_in[2];
  const float* z         = (const float*)d_in[3];
  const float* node_size = (const float*)d_in[4];
  const float* W_h0 = (const float*)d_in[5];
  const float* b_h0 = (const float*)d_in[6];
  const float* W_c0 = (const float*)d_in[7];
  const float* b_c0 = (const float*)d_in[8];
  const float* W_gh = (const float*)d_in[9];
  const float* b_gh = (const float*)d_in[10];
  const float* W_gih = (const float*)d_in[11];
  const float* W_ghh = (const float*)d_in[12];
  const float* b_gih = (const float*)d_in[13];
  const float* b_ghh = (const float*)d_in[14];
  const float* W_proj = (const float*)d_in[15];
  const float* b_proj = (const float*)d_in[16];
  const float* W_att1 = (const float*)d_in[17];
  const float* W_att2 = (const float*)d_in[18];
  const float* v_att  = (const float*)d_in[19];
  const float* W_lih = (const float*)d_in[20];
  const float* W_lhh = (const float*)d_in[21];
  const float* b_lih = (const float*)d_in[22];
  const float* b_lhh = (const float*)d_in[23];
  const float* W_e1 = (const float*)d_in[24];
  const float* b_e1 = (const float*)d_in[25];
  const float* W_e2 = (const float*)d_in[26];
  const float* b_e2 = (const float*)d_in[27];
  const float* W_a1 = (const float*)d_in[28];
  const float* b_a1 = (const float*)d_in[29];
  const float* W_a2 = (const float*)d_in[30];
  const float* b_a2 = (const float*)d_in[31];
  const int* e1   = (const int*)d_in[32];
  const int* e2   = (const int*)d_in[33];
  const int* nobs = (const int*)d_in[34];
  float* out = (float*)d_out;

  // workspace carve (floats)
  float* wsf     = (float*)d_ws;
  float* prev    = wsf;
  float* prev_st = wsf + 32768;
  float* des     = wsf + 65536;
  float* ss      = wsf + 262144;
  float* rad     = wsf + 262160;
  float* szf     = wsf + 385040;            // -> end 876560
  float* baseA   = wsf + 876560;            // union region, 5 units of N*256 -> end 11362320
  // serial-phase aliased view
  float* gh0 = baseA;
  float* gh1 = baseA + (size_t)N_ * 256;
  float* gi  = baseA + (size_t)2 * N_ * 256;
  // main phase view
  float* hA   = baseA;
  float* hB   = baseA + (size_t)N_ * 256;
  float* cbuf = baseA + (size_t)2 * N_ * 256;
  float* ctx  = baseA + (size_t)3 * N_ * 256;
  float* rel  = baseA + (size_t)4 * N_ * 256;
  float* nwp  = rel + (size_t)N_ * 4;
  float* nwp2 = nwp + (size_t)N_ * 2;
  // prepped B fragments
  unsigned short* wsBe = (unsigned short*)(wsf + 11362320);
  unsigned short* wsBg = (unsigned short*)(wsf + 11427856);
  unsigned short* wsBl = (unsigned short*)(wsf + 11624464);
  unsigned short* wsBx = (unsigned short*)(wsf + 12017680);
  unsigned short* wsBa = (unsigned short*)(wsf + 12312592);
  float* wattT = wsf + 12386320;                             // -> end 12388368
  // fused-path GRU buffers (disjoint from main-phase aliases)
  float* ext = wsf + 12388368;
  const size_t needF = 12388368ull + 5ull * N_ * 256ull;
  const bool fuse = ws_size >= needF * 4ull;
  float* gh0F = fuse ? ext : gh0;
  float* gh1F = fuse ? (ext + (size_t)N_ * 256) : gh1;
  float* giF  = fuse ? (ext + (size_t)2 * N_ * 256) : gi;

  k_zero<<<1, 64, 0, stream>>>(ss);
  k_edge_static<<<(E_ + 255) / 256, 256, 0, stream>>>(e1, e2, node_size, rad, szf);
  k_init_des<<<FTS * N_ / 256, 256, 0, stream>>>(b_proj, des);
  k_prep_attT<<<8, 256, 0, stream>>>(W_att1, wattT);

  k_prep<<<16,  256, 0, stream>>>(W_e2,  W_e2,  0, 256, 128,  128,  256, 8,  64,  wsBe);
  k_prep<<<96,  256, 0, stream>>>(W_ghh, W_ghh, 0, 256, 768,  768,  256, 48, 384, wsBg);
  k_prep<<<192, 256, 0, stream>>>(W_lih, W_lhh, 0, 128, 1024, 1024, 384, 64, 768, wsBl);
  k_prep<<<144, 256, 0, stream>>>(W_gh,  W_gih, 1, 256, 256,  768,  264, 64, 576, wsBx);
  k_prep<<<36,  256, 0, stream>>>(W_a1,  W_a1,  0, 272, 256,  256,  272, 16, 144, wsBa);

  // guide GRU: prologue steps (2 if fused, all 12 otherwise)
  k_xz_mfma<<<dim3(128, 4), 256, 0, stream>>>(hist_enc, z, wsBx, b_gh, b_gih, gh0F, giF);
  const int pre = fuse ? 2 : FTS;
  float* gcur = gh0F;
  float* gnxt = gh1F;
  for (int t = 0; t < pre; t++) {
    k_gru_mfma<<<dim3(128, 4), 256, 0, stream>>>(gcur, wsBg, b_ghh, giF, W_proj,
                                                 des + (size_t)t * N_ * 2, gnxt);
    float* tmp = gcur; gcur = gnxt; gnxt = tmp;
  }

  // main rollout (gru step t+2 fused into edge dispatch when enabled)
  k_init_hc<<<N_, 256, 0, stream>>>(x_last, x_st_last, W_h0, b_h0, W_c0, b_c0,
                                    hA, cbuf, prev, prev_st);
  float* hcur = hA;
  float* hnxt = hB;
  for (int t = 0; t < FTS; t++) {
    const float* des_t = des + (size_t)t * N_ * 2;
    const float* des_n = des + (size_t)((t + 1 < FTS) ? t + 1 : FTS - 1) * N_ * 2;
    const float* des_p = (t > 0) ? des + (size_t)(t - 1) * N_ * 2 : nullptr;
    const int gs = t + 2;
    const int gru_on = (fuse && gs < FTS) ? 1 : 0;
    const float* gin = (gs & 1) ? gh1F : gh0F;
    float* gout      = (gs & 1) ? gh0F : gh1F;
    float* des_g = des + (size_t)((gs < FTS) ? gs : 0) * N_ * 2;
    k_edge_gru<<<1280, 512, 0, stream>>>(prev, prev_st, x_st_last, szf, rad,
                                         nobs, e1, e2, W_e1, b_e1, wsBe, b_e2,
                                         wattT, W_att2, v_att,
                                         des_p, des_t, des_n,
                                         rel, nwp, nwp2, ctx, ss + t, ss + 12,
                                         gin, wsBg, b_ghh, giF, W_proj, des_g, gout, gru_on);
    k_lstm_mfma<<<dim3(128, 8), 256, 0, stream>>>(ctx, hcur, wsBl, b_lih, b_lhh,
                                                  cbuf, hnxt);
    k_action_mfma<<<256, 256, 0, stream>>>(hnxt, z, rel, nwp, nwp2,
                                           wsBa, b_a1, W_a2, b_a2,
                                           prev, prev_st,
                                           out + (size_t)t * N_ * 4,
                                           out + (size_t)FTS * N_ * 4 + (size_t)t * N_ * 2);
    float* tmp = hcur; hcur = hnxt; hnxt = tmp;
  }
  k_final<<<1, 64, 0, stream>>>(ss, out);
}

// Round 7
// 2679.779 us; speedup vs baseline: 1.4242x; 1.4242x over previous
//
#include <hip/hip_runtime.h>

#define DEVI __device__ __forceinline__

constexpr int N_  = 8192;
constexpr int K_  = 15;
constexpr int E_  = N_ * K_;     // 122880
constexpr int FTS = 12;
constexpr float DT_ = 0.25f;

typedef __attribute__((ext_vector_type(8))) short short8x;
typedef __attribute__((ext_vector_type(4))) float float4x;

union U8 { unsigned int u[4]; short8x v; };

DEVI float sigf(float x) { return 1.0f / (1.0f + __expf(-x)); }
DEVI float tanhf_fast(float x) { float e = __expf(2.f * x); return 1.f - 2.f / (e + 1.f); }
DEVI unsigned int f2u(float x) { union { float f; unsigned int u; } c; c.f = x; return c.u; }
DEVI float u2f(unsigned int x) { union { unsigned int u; float f; } c; c.u = x; return c.f; }

DEVI void split8(const float* __restrict__ s, short8x& hi8, short8x& lo8) {
  U8 ph, pl;
#pragma unroll
  for (int p = 0; p < 4; p++) {
    float a0 = s[2*p], a1 = s[2*p+1];
    unsigned int u0 = f2u(a0), u1 = f2u(a1);
    unsigned int h0 = u0 & 0xFFFF0000u, h1 = u1 & 0xFFFF0000u;
    ph.u[p] = (u0 >> 16) | h1;
    float l0 = a0 - u2f(h0), l1 = a1 - u2f(h1);
    pl.u[p] = (f2u(l0) >> 16) | (f2u(l1) & 0xFFFF0000u);
  }
  hi8 = ph.v; lo8 = pl.v;
}

// ---------------------------------------------------------------- zero accum
__global__ void k_zero(float* ss) {
  if (threadIdx.x < 13) ss[threadIdx.x] = 0.f;
}

// ---------------------------------------------------------------- init des to b_proj
__global__ __launch_bounds__(256) void k_init_des(const float* __restrict__ b_proj,
                                                  float* __restrict__ des) {
  int i = blockIdx.x * 256 + threadIdx.x;
  des[i*2]     = b_proj[0];
  des[i*2 + 1] = b_proj[1];
}

// ---------------------------------------------------------------- edge static
__global__ __launch_bounds__(256) void k_edge_static(
    const int* __restrict__ e1, const int* __restrict__ e2,
    const float* __restrict__ nsize, float* __restrict__ rad, float* __restrict__ szf)
{
  int e = blockIdx.x * 256 + threadIdx.x;
  if (e >= E_) return;
  int i1 = e1[e], i2 = e2[e];
  float s1x = nsize[i1*2+0], s1y = nsize[i1*2+1];
  float s2x = nsize[i2*2+0], s2y = nsize[i2*2+1];
  rad[e] = 0.5f * (sqrtf(s1x*s1x + s1y*s1y) + sqrtf(s2x*s2x + s2y*s2y));
  *(float4*)&szf[e*4] = make_float4(s1x, s1y, s2x, s2y);
}

// ---------------------------------------------------------------- transpose W_att1 -> [a][chan]
__global__ __launch_bounds__(256) void k_prep_attT(const float* __restrict__ W_att1,
                                                   float* __restrict__ wT) {
  int i = blockIdx.x * 256 + threadIdx.x;
  int chan = i >> 4, a = i & 15;
  wT[a * 128 + chan] = W_att1[i];
}

// ---------------------------------------------------------------- generic split-bf16 B-fragment prep
__global__ __launch_bounds__(256) void k_prep(
    const float* __restrict__ WA, const float* __restrict__ WB,
    int mode, int split, int wA, int wB, int Ktot, int NT, int nfrag,
    unsigned short* __restrict__ out)
{
  int t = blockIdx.x * 256 + threadIdx.x;
  int fid = t >> 6, L = t & 63;
  if (fid >= nfrag) return;
  int ks = fid / NT, nt = fid % NT;
  int k0 = ks * 32 + (L >> 4) * 8;
  int n  = nt * 16 + (L & 15);
  unsigned int hi[4], lo[4];
#pragma unroll
  for (int p = 0; p < 4; p++) {
    float w0 = 0.f, w1 = 0.f;
    int ka = k0 + 2*p, kb = ka + 1;
    if (mode == 0) {
      if (ka < Ktot) w0 = (ka < split) ? WA[(size_t)ka*wA + n] : WB[(size_t)(ka-split)*wB + n];
      if (kb < Ktot) w1 = (kb < split) ? WA[(size_t)kb*wA + n] : WB[(size_t)(kb-split)*wB + n];
    } else {
      if (ka < Ktot) w0 = (n < split) ? WA[(size_t)ka*wA + n] : WB[(size_t)ka*wB + (n-split)];
      if (kb < Ktot) w1 = (n < split) ? WA[(size_t)kb*wA + n] : WB[(size_t)kb*wB + (n-split)];
    }
    unsigned int u0 = f2u(w0), u1 = f2u(w1);
    unsigned int h0 = u0 & 0xFFFF0000u, h1 = u1 & 0xFFFF0000u;
    hi[p] = (u0 >> 16) | h1;
    float l0 = w0 - u2f(h0), l1 = w1 - u2f(h1);
    lo[p] = (f2u(l0) >> 16) | (f2u(l1) & 0xFFFF0000u);
  }
  size_t base = (size_t)(fid * 2) * 512 + (size_t)L * 8;
  *(uint4*)(out + base)       = make_uint4(hi[0], hi[1], hi[2], hi[3]);
  *(uint4*)(out + base + 512) = make_uint4(lo[0], lo[1], lo[2], lo[3]);
}

// ---------------------------------------------------------------- xz GEMM (once)
__global__ __launch_bounds__(256) void k_xz_mfma(
    const float* __restrict__ hist, const float* __restrict__ z,
    const unsigned short* __restrict__ wB,
    const float* __restrict__ b_gh, const float* __restrict__ b_gih,
    float* __restrict__ gh0, float* __restrict__ gi)
{
  __shared__ __align__(16) float Abuf[64][36];
  const int tid = threadIdx.x;
  const int w = tid >> 6, lane = tid & 63;
  const int m = lane & 15, q = lane >> 4;
  const int n0 = blockIdx.x * 64;
  const int r_ = tid >> 2, c_ = (tid & 3) * 8;
  float4x acc[16];
#pragma unroll
  for (int tl = 0; tl < 16; tl++) acc[tl] = (float4x){0.f,0.f,0.f,0.f};

  for (int ks = 0; ks < 9; ks++) {
    __syncthreads();
    {
      int kk = ks*32 + c_;
      int n = n0 + r_;
      float4 v0, v1;
      if (kk < 256) {
        v0 = *(const float4*)&hist[(size_t)n*256 + kk];
        v1 = *(const float4*)&hist[(size_t)n*256 + kk + 4];
      } else if (kk == 256) {
        v0 = *(const float4*)&z[n*8];
        v1 = *(const float4*)&z[n*8 + 4];
      } else {
        v0 = make_float4(0,0,0,0); v1 = v0;
      }
      *(float4*)&Abuf[r_][c_]     = v0;
      *(float4*)&Abuf[r_][c_ + 4] = v1;
    }
    __syncthreads();
    short8x aHi, aLo;
    split8(&Abuf[w*16 + m][q*8], aHi, aLo);
#pragma unroll
    for (int tl = 0; tl < 16; tl++) {
      int nt = blockIdx.y*16 + tl;
      size_t off = (size_t)((ks*64 + nt)*2) * 512 + (size_t)lane*8;
      short8x bh = *(const short8x*)(wB + off);
      short8x bl = *(const short8x*)(wB + off + 512);
      acc[tl] = __builtin_amdgcn_mfma_f32_16x16x32_bf16(aHi, bl, acc[tl], 0, 0, 0);
      acc[tl] = __builtin_amdgcn_mfma_f32_16x16x32_bf16(aLo, bh, acc[tl], 0, 0, 0);
      acc[tl] = __builtin_amdgcn_mfma_f32_16x16x32_bf16(aHi, bh, acc[tl], 0, 0, 0);
    }
  }
#pragma unroll
  for (int tl = 0; tl < 16; tl++) {
    int col = (blockIdx.y*16 + tl)*16 + m;
    float bias = (col < 256) ? b_gh[col] : b_gih[col - 256];
#pragma unroll
    for (int i = 0; i < 4; i++) {
      int n = n0 + w*16 + q*4 + i;
      float v = acc[tl][i] + bias;
      if (col < 256) gh0[(size_t)n*256 + col] = v;
      else           gi[(size_t)n*768 + col - 256] = v;
    }
  }
}

// ---------------------------------------------------------------- GRU core (shared)
DEVI void gru_core(float (*Abuf)[36], int tid, int n0, int j0,
                   const float* __restrict__ h_in, const unsigned short* __restrict__ wB,
                   const float* __restrict__ b_hh, const float* __restrict__ gi,
                   const float* __restrict__ W_proj, float* __restrict__ des_t,
                   float* __restrict__ h_out)
{
  const int w = tid >> 6, lane = tid & 63;
  const int m = lane & 15, q = lane >> 4;
  const int r_ = tid >> 2, c_ = (tid & 3) * 8;
  float4x acc[12];
#pragma unroll
  for (int tl = 0; tl < 12; tl++) acc[tl] = (float4x){0.f,0.f,0.f,0.f};

  for (int ks = 0; ks < 8; ks++) {
    __syncthreads();
    {
      int kk = ks*32 + c_;
      int n = n0 + r_;
      *(float4*)&Abuf[r_][c_]     = *(const float4*)&h_in[(size_t)n*256 + kk];
      *(float4*)&Abuf[r_][c_ + 4] = *(const float4*)&h_in[(size_t)n*256 + kk + 4];
    }
    __syncthreads();
    short8x aHi, aLo;
    split8(&Abuf[w*16 + m][q*8], aHi, aLo);
#pragma unroll
    for (int tl = 0; tl < 12; tl++) {
      int g = tl >> 2, jt = tl & 3;
      int nt = g*16 + (j0 >> 4) + jt;
      size_t off = (size_t)((ks*48 + nt)*2) * 512 + (size_t)lane*8;
      short8x bh = *(const short8x*)(wB + off);
      short8x bl = *(const short8x*)(wB + off + 512);
      acc[tl] = __builtin_amdgcn_mfma_f32_16x16x32_bf16(aHi, bl, acc[tl], 0, 0, 0);
      acc[tl] = __builtin_amdgcn_mfma_f32_16x16x32_bf16(aLo, bh, acc[tl], 0, 0, 0);
      acc[tl] = __builtin_amdgcn_mfma_f32_16x16x32_bf16(aHi, bh, acc[tl], 0, 0, 0);
    }
  }
  float pd0[4] = {0,0,0,0}, pd1[4] = {0,0,0,0};
#pragma unroll
  for (int jt = 0; jt < 4; jt++) {
    int j = j0 + jt*16 + m;
    float br = b_hh[j], bz = b_hh[256 + j], bn = b_hh[512 + j];
    float wp0 = W_proj[j*2], wp1 = W_proj[j*2 + 1];
#pragma unroll
    for (int i = 0; i < 4; i++) {
      int n = n0 + w*16 + q*4 + i;
      float ir  = gi[(size_t)n*768 + j];
      float iz  = gi[(size_t)n*768 + 256 + j];
      float inn = gi[(size_t)n*768 + 512 + j];
      float hold = h_in[(size_t)n*256 + j];
      float r = sigf(ir + acc[0*4 + jt][i] + br);
      float u = sigf(iz + acc[1*4 + jt][i] + bz);
      float nh = (1.f - u) * tanhf_fast(inn + r * (acc[2*4 + jt][i] + bn)) + u * hold;
      h_out[(size_t)n*256 + j] = nh;
      pd0[i] += nh * wp0;
      pd1[i] += nh * wp1;
    }
  }
#pragma unroll
  for (int off = 1; off < 16; off <<= 1) {
#pragma unroll
    for (int i = 0; i < 4; i++) {
      pd0[i] += __shfl_xor(pd0[i], off);
      pd1[i] += __shfl_xor(pd1[i], off);
    }
  }
  if (m == 0) {
#pragma unroll
    for (int i = 0; i < 4; i++) {
      int n = n0 + w*16 + q*4 + i;
      atomicAdd(&des_t[n*2],     pd0[i]);
      atomicAdd(&des_t[n*2 + 1], pd1[i]);
    }
  }
}

// ---------------------------------------------------------------- standalone GRU step (prologue)
__global__ __launch_bounds__(256) void k_gru_mfma(
    const float* __restrict__ h_in, const unsigned short* __restrict__ wB,
    const float* __restrict__ b_hh, const float* __restrict__ gi,
    const float* __restrict__ W_proj, float* __restrict__ des_t,
    float* __restrict__ h_out)
{
  __shared__ __align__(16) float Abuf[64][36];
  gru_core(Abuf, threadIdx.x, blockIdx.x * 64, blockIdx.y * 64,
           h_in, wB, b_hh, gi, W_proj, des_t, h_out);
}

// ---------------------------------------------------------------- LSTM cell (MFMA), j-tile = 32
__global__ __launch_bounds__(256) void k_lstm_mfma(
    const float* __restrict__ ctxg, const float* __restrict__ h_in,
    const unsigned short* __restrict__ wB,
    const float* __restrict__ b_ih, const float* __restrict__ b_hh,
    float* __restrict__ c_st, float* __restrict__ h_out)
{
  __shared__ __align__(16) float Abuf[64][36];
  const int tid = threadIdx.x;
  const int w = tid >> 6, lane = tid & 63;
  const int m = lane & 15, q = lane >> 4;
  const int n0 = blockIdx.x * 64;
  const int j0 = blockIdx.y * 32;
  const int r_ = tid >> 2, c_ = (tid & 3) * 8;
  float4x acc[8];
#pragma unroll
  for (int tl = 0; tl < 8; tl++) acc[tl] = (float4x){0.f,0.f,0.f,0.f};

  for (int ks = 0; ks < 12; ks++) {
    __syncthreads();
    {
      int kk = ks*32 + c_;
      int n = n0 + r_;
      float4 v0, v1;
      if (kk < 128) {
        v0 = *(const float4*)&ctxg[(size_t)n*128 + kk];
        v1 = *(const float4*)&ctxg[(size_t)n*128 + kk + 4];
      } else {
        v0 = *(const float4*)&h_in[(size_t)n*256 + kk - 128];
        v1 = *(const float4*)&h_in[(size_t)n*256 + kk - 124];
      }
      *(float4*)&Abuf[r_][c_]     = v0;
      *(float4*)&Abuf[r_][c_ + 4] = v1;
    }
    __syncthreads();
    short8x aHi, aLo;
    split8(&Abuf[w*16 + m][q*8], aHi, aLo);
#pragma unroll
    for (int tl = 0; tl < 8; tl++) {
      int g = tl >> 1, jt = tl & 1;
      int nt = g*16 + (j0 >> 4) + jt;
      size_t off = (size_t)((ks*64 + nt)*2) * 512 + (size_t)lane*8;
      short8x bh = *(const short8x*)(wB + off);
      short8x bl = *(const short8x*)(wB + off + 512);
      acc[tl] = __builtin_amdgcn_mfma_f32_16x16x32_bf16(aHi, bl, acc[tl], 0, 0, 0);
      acc[tl] = __builtin_amdgcn_mfma_f32_16x16x32_bf16(aLo, bh, acc[tl], 0, 0, 0);
      acc[tl] = __builtin_amdgcn_mfma_f32_16x16x32_bf16(aHi, bh, acc[tl], 0, 0, 0);
    }
  }
#pragma unroll
  for (int jt = 0; jt < 2; jt++) {
    int j = j0 + jt*16 + m;
    float bi = b_ih[j]       + b_hh[j];
    float bf = b_ih[256 + j] + b_hh[256 + j];
    float bg = b_ih[512 + j] + b_hh[512 + j];
    float bo = b_ih[768 + j] + b_hh[768 + j];
#pragma unroll
    for (int i = 0; i < 4; i++) {
      int n = n0 + w*16 + q*4 + i;
      float g_i = sigf(acc[0*2 + jt][i] + bi);
      float g_f = sigf(acc[1*2 + jt][i] + bf);
      float g_g = tanhf_fast(acc[2*2 + jt][i] + bg);
      float g_o = sigf(acc[3*2 + jt][i] + bo);
      float cv = g_f * c_st[(size_t)n*256 + j] + g_i * g_g;
      c_st[(size_t)n*256 + j] = cv;
      h_out[(size_t)n*256 + j] = g_o * tanhf_fast(cv);
    }
  }
}

// ---------------------------------------------------------------- action MLP: 32 nodes/block
__global__ __launch_bounds__(256) void k_action_mfma(
    const float* __restrict__ h, const float* __restrict__ z,
    const float* __restrict__ rel, const float* __restrict__ nwp, const float* __restrict__ nwp2,
    const unsigned short* __restrict__ wB, const float* __restrict__ b_a1,
    const float* __restrict__ W_a2, const float* __restrict__ b_a2,
    float* __restrict__ prev, float* __restrict__ prev_st,
    float* __restrict__ outS, float* __restrict__ outU)
{
  __shared__ __align__(16) float Abuf[32][36];
  __shared__ float sm_p[2][16][2];
  const int tid = threadIdx.x;
  const int w = tid >> 6, lane = tid & 63;
  const int m = lane & 15, q = lane >> 4;
  const int ng = w >> 1, hh = w & 1;
  const int n0 = blockIdx.x * 32;
  const int r_ = tid >> 3, c_ = (tid & 7) * 4;
  float4x acc[8];
#pragma unroll
  for (int j = 0; j < 8; j++) acc[j] = (float4x){0.f,0.f,0.f,0.f};

  for (int ks = 0; ks < 9; ks++) {
    __syncthreads();
    {
      int kk = ks*32 + c_;
      int n = n0 + r_;
      float4 v;
      if (kk < 256)      v = *(const float4*)&h[(size_t)n*256 + kk];
      else if (kk == 256) v = *(const float4*)&z[n*8];
      else if (kk == 260) v = *(const float4*)&z[n*8 + 4];
      else if (kk == 264) v = *(const float4*)&rel[n*4];
      else if (kk == 268) {
        float2 w1 = *(const float2*)&nwp[n*2];
        float2 w2 = *(const float2*)&nwp2[n*2];
        v = make_float4(w1.x, w1.y, w2.x, w2.y);
      } else v = make_float4(0,0,0,0);
      *(float4*)&Abuf[r_][c_] = v;
    }
    __syncthreads();
    short8x aHi, aLo;
    split8(&Abuf[ng*16 + m][q*8], aHi, aLo);
#pragma unroll
    for (int j = 0; j < 8; j++) {
      int tl = hh*8 + j;
      size_t off = (size_t)((ks*16 + tl)*2) * 512 + (size_t)lane*8;
      short8x bh = *(const short8x*)(wB + off);
      short8x bl = *(const short8x*)(wB + off + 512);
      acc[j] = __builtin_amdgcn_mfma_f32_16x16x32_bf16(aHi, bl, acc[j], 0, 0, 0);
      acc[j] = __builtin_amdgcn_mfma_f32_16x16x32_bf16(aLo, bh, acc[j], 0, 0, 0);
      acc[j] = __builtin_amdgcn_mfma_f32_16x16x32_bf16(aHi, bh, acc[j], 0, 0, 0);
    }
  }
  float p0[4] = {0,0,0,0}, p1[4] = {0,0,0,0};
#pragma unroll
  for (int j = 0; j < 8; j++) {
    int col = (hh*8 + j)*16 + m;
    float ba = b_a1[col];
    float2 w2 = *(const float2*)&W_a2[col*2];
#pragma unroll
    for (int i = 0; i < 4; i++) {
      float hv = fmaxf(acc[j][i] + ba, 0.f);
      p0[i] += hv * w2.x;
      p1[i] += hv * w2.y;
    }
  }
#pragma unroll
  for (int off = 1; off < 16; off <<= 1) {
#pragma unroll
    for (int i = 0; i < 4; i++) {
      p0[i] += __shfl_xor(p0[i], off);
      p1[i] += __shfl_xor(p1[i], off);
    }
  }
  if (hh == 1 && m == 0) {
#pragma unroll
    for (int i = 0; i < 4; i++) {
      sm_p[ng][q*4 + i][0] = p0[i];
      sm_p[ng][q*4 + i][1] = p1[i];
    }
  }
  __syncthreads();
  if (hh == 0 && m == 0) {
    float ba0 = b_a2[0], ba1 = b_a2[1];
    const float hd = 0.5f * DT_ * DT_;
#pragma unroll
    for (int i = 0; i < 4; i++) {
      int n = n0 + ng*16 + q*4 + i;
      float ux = tanhf_fast(p0[i] + sm_p[ng][q*4 + i][0] + ba0);
      float uy = tanhf_fast(p1[i] + sm_p[ng][q*4 + i][1] + ba1);
      float4 pv = *(const float4*)&prev[n*4];
      float4 ps = *(const float4*)&prev_st[n*4];
      float4 npv, nps;
      npv.x = pv.x + pv.z*DT_ + ux*hd;
      npv.y = pv.y + pv.w*DT_ + uy*hd;
      npv.z = pv.z + ux*DT_;
      npv.w = pv.w + uy*DT_;
      nps.x = ps.x + ps.z*DT_ + ux*hd;
      nps.y = ps.y + ps.w*DT_ + uy*hd;
      nps.z = ps.z + ux*DT_;
      nps.w = ps.w + uy*DT_;
      *(float4*)&prev[n*4] = npv;
      *(float4*)&prev_st[n*4] = nps;
      *(float4*)&outS[(size_t)n*4] = npv;
      outU[n*2]     = ux;
      outU[n*2 + 1] = uy;
    }
  }
}

// ---------------------------------------------------------------- LSTM h0/c0 + prev copies
__global__ __launch_bounds__(256) void k_init_hc(
    const float* __restrict__ x_last, const float* __restrict__ x_st_last,
    const float* __restrict__ W_h0, const float* __restrict__ b_h0,
    const float* __restrict__ W_c0, const float* __restrict__ b_c0,
    float* __restrict__ h, float* __restrict__ c,
    float* __restrict__ prev, float* __restrict__ prev_st)
{
  const int n = blockIdx.x;
  const int j = threadIdx.x;
  float x0 = x_st_last[n*4], x1 = x_st_last[n*4+1], x2 = x_st_last[n*4+2], x3 = x_st_last[n*4+3];
  h[(size_t)n*256 + j] = b_h0[j] + x0*W_h0[j] + x1*W_h0[256+j] + x2*W_h0[512+j] + x3*W_h0[768+j];
  c[(size_t)n*256 + j] = b_c0[j] + x0*W_c0[j] + x1*W_c0[256+j] + x2*W_c0[512+j] + x3*W_c0[768+j];
  if (j < 4) prev[n*4 + j] = x_last[n*4 + j];
  else if (j < 8) prev_st[n*4 + (j-4)] = x_st_last[n*4 + (j-4)];
}

// ---------------------------------------------------------------- FUSED: edge (blocks 0..2047, 4 nodes) | GRU (blocks 2048..2559)
// 256 threads; (256,5): VGPR cap ~102 >= actual ~60 (no spill), LDS 27.6KB*5 = 138KB <= 160KB.
__global__ __launch_bounds__(256, 5) void k_edge_gru(
    const float* __restrict__ prev, const float* __restrict__ prev_st,
    const float* __restrict__ x_st_last,
    const float* __restrict__ szf, const float* __restrict__ rad,
    const int* __restrict__ nobs, const int* __restrict__ e1, const int* __restrict__ e2,
    const float* __restrict__ W_e1, const float* __restrict__ b_e1,
    const unsigned short* __restrict__ wsB, const float* __restrict__ b_e2,
    const float* __restrict__ wattT, const float* __restrict__ W_att2,
    const float* __restrict__ v_att,
    const float* __restrict__ des_p, const float* __restrict__ des_t,
    const float* __restrict__ des_n,
    float* __restrict__ relg, float* __restrict__ nwp, float* __restrict__ nwp2,
    float* __restrict__ ctx, float* __restrict__ ss_t, float* __restrict__ cc,
    const float* __restrict__ g_hin, const unsigned short* __restrict__ wBg,
    const float* __restrict__ b_ghh, const float* __restrict__ gi,
    const float* __restrict__ W_proj, float* __restrict__ des_g,
    float* __restrict__ g_hout, int gru_on)
{
  // LDS: stage[4096] | feats[512]@4096 | flags[64]@4608 | relv[16]@4672
  //      w1T[2048]@4688 | watt2[64]@6736 | vatt[16]@6800 | red[8]@6816  -> 6824 floats
  __shared__ __align__(16) float smem[6824];
  const int tid = threadIdx.x;

  if (blockIdx.x >= 2048) {
    if (!gru_on) return;
    int b = blockIdx.x - 2048;
    gru_core((float(*)[36])smem, tid, (b & 127) * 64, (b >> 7) * 64,
             g_hin, wBg, b_ghh, gi, W_proj, des_g, g_hout);
    return;
  }

  float* sm_stage = smem;
  float* sm_feats = smem + 4096;
  float* sm_flags = smem + 4608;
  float* sm_relv  = smem + 4672;
  float* sm_w1T   = smem + 4688;
  float* sm_watt2 = smem + 6736;
  float* sm_vatt  = smem + 6800;
  float* sm_red   = smem + 6816;

  const int n0  = blockIdx.x * 4;
  const int lane = tid & 63;
  const int g    = tid >> 6;
  const int q = lane >> 4, m = lane & 15;

  // ---- P0
  for (int i = tid; i < 2048; i += 256) sm_w1T[i] = wattT[i];
  if (tid >= 176 && tid < 192) sm_vatt[tid - 176] = v_att[tid - 176];
  if (tid >= 192) sm_watt2[tid - 192] = W_att2[tid - 192];

  if (tid < 64) {
    float v = 0.f;
    if (tid < 60) {
      int gg = tid / 15, k = tid % 15;
      int idx = nobs[(n0 + gg) * 15 + k];
      float f[8] = {0,0,0,0,0,0,0,0};
      float fl = 0.f;
      if (idx > 0) {
        int e = idx - 1;
        int i1 = e1[e], i2 = e2[e];
#pragma unroll
        for (int d = 0; d < 4; d++) f[d] = prev[i2*4 + d] - prev[i1*4 + d];
        float4 sz = *(const float4*)&szf[(size_t)e*4];
        f[4] = sz.x; f[5] = sz.y; f[6] = sz.z; f[7] = sz.w;
        fl = 1.f;
        float dist = sqrtf(f[0]*f[0] + f[1]*f[1]);
        v = fmaxf(rad[e] - dist, 0.f);
      }
#pragma unroll
      for (int d = 0; d < 8; d++) sm_feats[(gg*16 + k)*8 + d] = f[d];
      sm_flags[gg*16 + k] = fl;
    } else {
      int gg = tid - 60;
#pragma unroll
      for (int d = 0; d < 8; d++) sm_feats[(gg*16 + 15)*8 + d] = 0.f;
      sm_flags[gg*16 + 15] = 0.f;
    }
#pragma unroll
    for (int off = 32; off; off >>= 1) v += __shfl_down(v, off);
    if (tid == 0) atomicAdd(cc, v);
  } else if (tid < 68) {
    int gg = tid - 64;
    int n = n0 + gg;
    float4 ps = *(const float4*)&prev_st[n*4];
    float r0, r1, r2, r3;
    if (des_p) {
      float4 xs = *(const float4*)&x_st_last[n*4];
      r0 = ps.x - xs.x - des_p[n*2];
      r1 = ps.y - xs.y - des_p[n*2 + 1];
      r2 = ps.z - xs.z;
      r3 = ps.w - xs.w;
    } else { r0 = ps.x; r1 = ps.y; r2 = ps.z; r3 = ps.w; }
    sm_relv[gg*4+0] = r0; sm_relv[gg*4+1] = r1; sm_relv[gg*4+2] = r2; sm_relv[gg*4+3] = r3;
    *(float4*)&relg[n*4] = make_float4(r0, r1, r2, r3);
    nwp[n*2]      = des_t[n*2]     - ps.x;
    nwp[n*2 + 1]  = des_t[n*2 + 1] - ps.y;
    nwp2[n*2]     = des_n[n*2]     - ps.x;
    nwp2[n*2 + 1] = des_n[n*2 + 1] - ps.y;
    sm_red[gg] = r0*r0 + r1*r1;
  }
  __syncthreads();
  if (tid == 64) atomicAdd(ss_t, sm_red[0] + sm_red[1] + sm_red[2] + sm_red[3]);

  // ---- P1+P2 fused over ks: hidden (per-ks VALU) + staged-B MFMA
  float f[8];
  {
    const float4 fa = *(const float4*)&sm_feats[(g*16 + m)*8];
    const float4 fb = *(const float4*)&sm_feats[(g*16 + m)*8 + 4];
    f[0]=fa.x; f[1]=fa.y; f[2]=fa.z; f[3]=fa.w; f[4]=fb.x; f[5]=fb.y; f[6]=fb.z; f[7]=fb.w;
  }
  float4x encR[8];
#pragma unroll
  for (int nt = 0; nt < 8; nt++) encR[nt] = (float4x){0.f,0.f,0.f,0.f};
  const float4* We14 = (const float4*)W_e1;
  const float4* Be14 = (const float4*)b_e1;
  const unsigned short* sb = (const unsigned short*)sm_stage;

  for (int ks = 0; ks < 8; ks++) {
    __syncthreads();
    {
      const uint4* src = (const uint4*)(wsB + (size_t)ks * 8192);
      uint4* dst = (uint4*)sm_stage;
#pragma unroll
      for (int i2 = 0; i2 < 4; i2++) dst[tid + i2*256] = src[tid + i2*256];
    }
    short8x aHi, aLo;
    {
      float h8[8];
      float4 b0 = Be14[8*ks + 2*q];
      float4 b1 = Be14[8*ks + 2*q + 1];
      h8[0]=b0.x; h8[1]=b0.y; h8[2]=b0.z; h8[3]=b0.w; h8[4]=b1.x; h8[5]=b1.y; h8[6]=b1.z; h8[7]=b1.w;
#pragma unroll
      for (int d = 0; d < 8; d++) {
        float4 wa = We14[d*64 + ks*8 + 2*q];
        float4 wb = We14[d*64 + ks*8 + 2*q + 1];
        h8[0] += f[d]*wa.x; h8[1] += f[d]*wa.y; h8[2] += f[d]*wa.z; h8[3] += f[d]*wa.w;
        h8[4] += f[d]*wb.x; h8[5] += f[d]*wb.y; h8[6] += f[d]*wb.z; h8[7] += f[d]*wb.w;
      }
#pragma unroll
      for (int p = 0; p < 8; p++) h8[p] = fmaxf(h8[p], 0.f);
      split8(h8, aHi, aLo);
    }
    __syncthreads();
#pragma unroll
    for (int nt = 0; nt < 8; nt++) {
      short8x bh = *(const short8x*)(sb + nt*1024 + lane*8);
      short8x bl = *(const short8x*)(sb + nt*1024 + 512 + lane*8);
      encR[nt] = __builtin_amdgcn_mfma_f32_16x16x32_bf16(aHi, bl, encR[nt], 0, 0, 0);
      encR[nt] = __builtin_amdgcn_mfma_f32_16x16x32_bf16(aLo, bh, encR[nt], 0, 0, 0);
      encR[nt] = __builtin_amdgcn_mfma_f32_16x16x32_bf16(aHi, bh, encR[nt], 0, 0, 0);
    }
  }
  float4x fl4 = *(const float4x*)&sm_flags[g*16 + q*4];
#pragma unroll
  for (int nt = 0; nt < 8; nt++) {
    float b2 = b_e2[nt*16 + m];
#pragma unroll
    for (int i = 0; i < 4; i++) encR[nt][i] = (encR[nt][i] + b2) * fl4[i];
  }

  // ---- P3: score partials
  float4x part[16];
#pragma unroll
  for (int a = 0; a < 16; a++) part[a] = (float4x){0.f,0.f,0.f,0.f};
#pragma unroll
  for (int a = 0; a < 16; a++) {
#pragma unroll
    for (int nt = 0; nt < 8; nt++) {
      float wv = sm_w1T[a*128 + nt*16 + m];
      part[a] = part[a] + encR[nt] * wv;
    }
  }

  // ---- P4: halving-exchange over m
  const bool s8 = (m & 8) != 0, s4b = (m & 4) != 0, s2b = (m & 2) != 0, s1b = (m & 1) != 0;
  float4x c8[8];
#pragma unroll
  for (int a = 0; a < 8; a++) {
    float4x mi, sd, rc;
#pragma unroll
    for (int e = 0; e < 4; e++) {
      mi[e] = s8 ? part[a+8][e] : part[a][e];
      sd[e] = s8 ? part[a][e] : part[a+8][e];
      rc[e] = __shfl_xor(sd[e], 8);
    }
    c8[a] = mi + rc;
  }
  float4x c4[4];
#pragma unroll
  for (int a = 0; a < 4; a++) {
    float4x mi, sd, rc;
#pragma unroll
    for (int e = 0; e < 4; e++) {
      mi[e] = s4b ? c8[a+4][e] : c8[a][e];
      sd[e] = s4b ? c8[a][e] : c8[a+4][e];
      rc[e] = __shfl_xor(sd[e], 4);
    }
    c4[a] = mi + rc;
  }
  float4x c2[2];
#pragma unroll
  for (int a = 0; a < 2; a++) {
    float4x mi, sd, rc;
#pragma unroll
    for (int e = 0; e < 4; e++) {
      mi[e] = s2b ? c4[a+2][e] : c4[a][e];
      sd[e] = s2b ? c4[a][e] : c4[a+2][e];
      rc[e] = __shfl_xor(sd[e], 2);
    }
    c2[a] = mi + rc;
  }
  float4x c1;
  {
    float4x mi, sd, rc;
#pragma unroll
    for (int e = 0; e < 4; e++) {
      mi[e] = s1b ? c2[1][e] : c2[0][e];
      sd[e] = s1b ? c2[0][e] : c2[1][e];
      rc[e] = __shfl_xor(sd[e], 1);
    }
    c1 = mi + rc;
  }

  // ---- P5: softmax + ctx
  float relw;
  {
    float4 rv = *(const float4*)&sm_relv[g*4];
    relw = rv.x * sm_watt2[m] + rv.y * sm_watt2[16 + m]
         + rv.z * sm_watt2[32 + m] + rv.w * sm_watt2[48 + m];
  }
  float vat = sm_vatt[m];
  float val[4];
#pragma unroll
  for (int i = 0; i < 4; i++) val[i] = tanhf_fast(c1[i] + relw) * vat;
#pragma unroll
  for (int msk = 1; msk < 16; msk <<= 1) {
#pragma unroll
    for (int i = 0; i < 4; i++) val[i] += __shfl_xor(val[i], msk);
  }
  if (q == 3) val[3] = -3.0e38f;
  float mx = fmaxf(fmaxf(val[0], val[1]), fmaxf(val[2], val[3]));
  mx = fmaxf(mx, __shfl_xor(mx, 16));
  mx = fmaxf(mx, __shfl_xor(mx, 32));
  float4x ev;
  float ssum = 0.f;
#pragma unroll
  for (int i = 0; i < 4; i++) { ev[i] = __expf(val[i] - mx); ssum += ev[i]; }
  ssum += __shfl_xor(ssum, 16);
  ssum += __shfl_xor(ssum, 32);
  float inv = 1.f / ssum;
#pragma unroll
  for (int i = 0; i < 4; i++) ev[i] *= inv;

  float cpart[8];
#pragma unroll
  for (int nt = 0; nt < 8; nt++) {
    float cv = ev[0]*encR[nt][0] + ev[1]*encR[nt][1] + ev[2]*encR[nt][2] + ev[3]*encR[nt][3];
    cv += __shfl_xor(cv, 16);
    cv += __shfl_xor(cv, 32);
    cpart[nt] = cv;
  }
  float v0 = (q == 0) ? cpart[0] : (q == 1) ? cpart[2] : (q == 2) ? cpart[4] : cpart[6];
  float v1 = (q == 0) ? cpart[1] : (q == 1) ? cpart[3] : (q == 2) ? cpart[5] : cpart[7];
  size_t cb = (size_t)(n0 + g) * 128 + q*32 + m;
  ctx[cb]      = v0;
  ctx[cb + 16] = v1;
}

// ---------------------------------------------------------------- finalize scalars
__global__ void k_final(const float* __restrict__ ss, float* __restrict__ out) {
  if (threadIdx.x == 0) {
    float t = 0.f;
    for (int i = 0; i < FTS; i++) t += sqrtf(ss[i]);
    out[(size_t)FTS * N_ * 6]     = t / (float)N_;
    out[(size_t)FTS * N_ * 6 + 1] = ss[FTS];
  }
}

// ================================================================ launch
extern "C" void kernel_launch(void* const* d_in, const int* in_sizes, int n_in,
                              void* d_out, int out_size, void* d_ws, size_t ws_size,
                              hipStream_t stream) {
  (void)in_sizes; (void)n_in; (void)out_size;
  const float* x_last    = (const float*)d_in[0];
  const float* x_st_last = (const float*)d_in[1];
  const float* hist_enc  = (const float*)d_in[2];
  const float* z         = (const float*)d_in[3];
  const float* node_size = (const float*)d_in[4];
  const float* W_h0 = (const float*)d_in[5];
  const float* b_h0 = (const float*)d_in[6];
  const float* W_c0 = (const float*)d_in[7];
  const float* b_c0 = (const float*)d_in[8];
  const float* W_gh = (const float*)d_in[9];
  const float* b_gh = (const float*)d_in[10];
  const float* W_gih = (const float*)d_in[11];
  const float* W_ghh = (const float*)d_in[12];
  const float* b_gih = (const float*)d_in[13];
  const float* b_ghh = (const float*)d_in[14];
  const float* W_proj = (const float*)d_in[15];
  const float* b_proj = (const float*)d_in[16];
  const float* W_att1 = (const float*)d_in[17];
  const float* W_att2 = (const float*)d_in[18];
  const float* v_att  = (const float*)d_in[19];
  const float* W_lih = (const float*)d_in[20];
  const float* W_lhh = (const float*)d_in[21];
  const float* b_lih = (const float*)d_in[22];
  const float* b_lhh = (const float*)d_in[23];
  const float* W_e1 = (const float*)d_in[24];
  const float* b_e1 = (const float*)d_in[25];
  const float* W_e2 = (const float*)d_in[26];
  const float* b_e2 = (const float*)d_in[27];
  const float* W_a1 = (const float*)d_in[28];
  const float* b_a1 = (const float*)d_in[29];
  const float* W_a2 = (const float*)d_in[30];
  const float* b_a2 = (const float*)d_in[31];
  const int* e1   = (const int*)d_in[32];
  const int* e2   = (const int*)d_in[33];
  const int* nobs = (const int*)d_in[34];
  float* out = (float*)d_out;

  // workspace carve (floats)
  float* wsf     = (float*)d_ws;
  float* prev    = wsf;
  float* prev_st = wsf + 32768;
  float* des     = wsf + 65536;
  float* ss      = wsf + 262144;
  float* rad     = wsf + 262160;
  float* szf     = wsf + 385040;            // -> end 876560
  float* baseA   = wsf + 876560;            // union region, 5 units of N*256 -> end 11362320
  // serial-phase aliased view
  float* gh0 = baseA;
  float* gh1 = baseA + (size_t)N_ * 256;
  float* gi  = baseA + (size_t)2 * N_ * 256;
  // main phase view
  float* hA   = baseA;
  float* hB   = baseA + (size_t)N_ * 256;
  float* cbuf = baseA + (size_t)2 * N_ * 256;
  float* ctx  = baseA + (size_t)3 * N_ * 256;
  float* rel  = baseA + (size_t)4 * N_ * 256;
  float* nwp  = rel + (size_t)N_ * 4;
  float* nwp2 = nwp + (size_t)N_ * 2;
  // prepped B fragments
  unsigned short* wsBe = (unsigned short*)(wsf + 11362320);
  unsigned short* wsBg = (unsigned short*)(wsf + 11427856);
  unsigned short* wsBl = (unsigned short*)(wsf + 11624464);
  unsigned short* wsBx = (unsigned short*)(wsf + 12017680);
  unsigned short* wsBa = (unsigned short*)(wsf + 12312592);
  float* wattT = wsf + 12386320;                             // -> end 12388368
  // fused-path GRU buffers (disjoint from main-phase aliases)
  float* ext = wsf + 12388368;
  const size_t needF = 12388368ull + 5ull * N_ * 256ull;
  const bool fuse = ws_size >= needF * 4ull;
  float* gh0F = fuse ? ext : gh0;
  float* gh1F = fuse ? (ext + (size_t)N_ * 256) : gh1;
  float* giF  = fuse ? (ext + (size_t)2 * N_ * 256) : gi;

  k_zero<<<1, 64, 0, stream>>>(ss);
  k_edge_static<<<(E_ + 255) / 256, 256, 0, stream>>>(e1, e2, node_size, rad, szf);
  k_init_des<<<FTS * N_ / 256, 256, 0, stream>>>(b_proj, des);
  k_prep_attT<<<8, 256, 0, stream>>>(W_att1, wattT);

  k_prep<<<16,  256, 0, stream>>>(W_e2,  W_e2,  0, 256, 128,  128,  256, 8,  64,  wsBe);
  k_prep<<<96,  256, 0, stream>>>(W_ghh, W_ghh, 0, 256, 768,  768,  256, 48, 384, wsBg);
  k_prep<<<192, 256, 0, stream>>>(W_lih, W_lhh, 0, 128, 1024, 1024, 384, 64, 768, wsBl);
  k_prep<<<144, 256, 0, stream>>>(W_gh,  W_gih, 1, 256, 256,  768,  264, 64, 576, wsBx);
  k_prep<<<36,  256, 0, stream>>>(W_a1,  W_a1,  0, 272, 256,  256,  272, 16, 144, wsBa);

  // guide GRU: prologue steps (2 if fused, all 12 otherwise)
  k_xz_mfma<<<dim3(128, 4), 256, 0, stream>>>(hist_enc, z, wsBx, b_gh, b_gih, gh0F, giF);
  const int pre = fuse ? 2 : FTS;
  float* gcur = gh0F;
  float* gnxt = gh1F;
  for (int t = 0; t < pre; t++) {
    k_gru_mfma<<<dim3(128, 4), 256, 0, stream>>>(gcur, wsBg, b_ghh, giF, W_proj,
                                                 des + (size_t)t * N_ * 2, gnxt);
    float* tmp = gcur; gcur = gnxt; gnxt = tmp;
  }

  // main rollout (gru step t+2 fused into edge dispatch when enabled)
  k_init_hc<<<N_, 256, 0, stream>>>(x_last, x_st_last, W_h0, b_h0, W_c0, b_c0,
                                    hA, cbuf, prev, prev_st);
  float* hcur = hA;
  float* hnxt = hB;
  for (int t = 0; t < FTS; t++) {
    const float* des_t = des + (size_t)t * N_ * 2;
    const float* des_n = des + (size_t)((t + 1 < FTS) ? t + 1 : FTS - 1) * N_ * 2;
    const float* des_p = (t > 0) ? des + (size_t)(t - 1) * N_ * 2 : nullptr;
    const int gs = t + 2;
    const int gru_on = (fuse && gs < FTS) ? 1 : 0;
    const float* gin = (gs & 1) ? gh1F : gh0F;
    float* gout      = (gs & 1) ? gh0F : gh1F;
    float* des_g = des + (size_t)((gs < FTS) ? gs : 0) * N_ * 2;
    k_edge_gru<<<2560, 256, 0, stream>>>(prev, prev_st, x_st_last, szf, rad,
                                         nobs, e1, e2, W_e1, b_e1, wsBe, b_e2,
                                         wattT, W_att2, v_att,
                                         des_p, des_t, des_n,
                                         rel, nwp, nwp2, ctx, ss + t, ss + 12,
                                         gin, wsBg, b_ghh, giF, W_proj, des_g, gout, gru_on);
    k_lstm_mfma<<<dim3(128, 8), 256, 0, stream>>>(ctx, hcur, wsBl, b_lih, b_lhh,
                                                  cbuf, hnxt);
    k_action_mfma<<<256, 256, 0, stream>>>(hnxt, z, rel, nwp, nwp2,
                                           wsBa, b_a1, W_a2, b_a2,
                                           prev, prev_st,
                                           out + (size_t)t * N_ * 4,
                                           out + (size_t)FTS * N_ * 4 + (size_t)t * N_ * 2);
    float* tmp = hcur; hcur = hnxt; hnxt = tmp;
  }
  k_final<<<1, 64, 0, stream>>>(ss, out);
}

// Round 8
// 2438.880 us; speedup vs baseline: 1.5648x; 1.0988x over previous
//
#include <hip/hip_runtime.h>

#define DEVI __device__ __forceinline__

constexpr int N_  = 8192;
constexpr int K_  = 15;
constexpr int E_  = N_ * K_;     // 122880
constexpr int FTS = 12;
constexpr float DT_ = 0.25f;

typedef __attribute__((ext_vector_type(8))) short short8x;
typedef __attribute__((ext_vector_type(4))) float float4x;

union U8 { unsigned int u[4]; short8x v; };

DEVI float sigf(float x) { return 1.0f / (1.0f + __expf(-x)); }
DEVI float tanhf_fast(float x) { float e = __expf(2.f * x); return 1.f - 2.f / (e + 1.f); }
DEVI unsigned int f2u(float x) { union { float f; unsigned int u; } c; c.f = x; return c.u; }
DEVI float u2f(unsigned int x) { union { unsigned int u; float f; } c; c.u = x; return c.f; }

DEVI void split8(const float* __restrict__ s, short8x& hi8, short8x& lo8) {
  U8 ph, pl;
#pragma unroll
  for (int p = 0; p < 4; p++) {
    float a0 = s[2*p], a1 = s[2*p+1];
    unsigned int u0 = f2u(a0), u1 = f2u(a1);
    unsigned int h0 = u0 & 0xFFFF0000u, h1 = u1 & 0xFFFF0000u;
    ph.u[p] = (u0 >> 16) | h1;
    float l0 = a0 - u2f(h0), l1 = a1 - u2f(h1);
    pl.u[p] = (f2u(l0) >> 16) | (f2u(l1) & 0xFFFF0000u);
  }
  hi8 = ph.v; lo8 = pl.v;
}

// ---------------------------------------------------------------- zero accum
__global__ void k_zero(float* ss) {
  if (threadIdx.x < 13) ss[threadIdx.x] = 0.f;
}

// ---------------------------------------------------------------- init des to b_proj
__global__ __launch_bounds__(256) void k_init_des(const float* __restrict__ b_proj,
                                                  float* __restrict__ des) {
  int i = blockIdx.x * 256 + threadIdx.x;
  des[i*2]     = b_proj[0];
  des[i*2 + 1] = b_proj[1];
}

// ---------------------------------------------------------------- edge static
__global__ __launch_bounds__(256) void k_edge_static(
    const int* __restrict__ e1, const int* __restrict__ e2,
    const float* __restrict__ nsize, float* __restrict__ rad, float* __restrict__ szf)
{
  int e = blockIdx.x * 256 + threadIdx.x;
  if (e >= E_) return;
  int i1 = e1[e], i2 = e2[e];
  float s1x = nsize[i1*2+0], s1y = nsize[i1*2+1];
  float s2x = nsize[i2*2+0], s2y = nsize[i2*2+1];
  rad[e] = 0.5f * (sqrtf(s1x*s1x + s1y*s1y) + sqrtf(s2x*s2x + s2y*s2y));
  *(float4*)&szf[e*4] = make_float4(s1x, s1y, s2x, s2y);
}

// ---------------------------------------------------------------- transpose W_att1 -> [a][chan]
__global__ __launch_bounds__(256) void k_prep_attT(const float* __restrict__ W_att1,
                                                   float* __restrict__ wT) {
  int i = blockIdx.x * 256 + threadIdx.x;
  int chan = i >> 4, a = i & 15;
  wT[a * 128 + chan] = W_att1[i];
}

// ---------------------------------------------------------------- hi-only bf16 B-fragments for edge W_e2
// contiguous: out[fid*512 + L*8], fid = ks*8+nt  (64 frags, 32768 ushorts)
__global__ __launch_bounds__(256) void k_prep_hi(
    const float* __restrict__ W, unsigned short* __restrict__ out)
{
  int t = blockIdx.x * 256 + threadIdx.x;   // < 4096
  int fid = t >> 6, L = t & 63;
  int ks = fid >> 3, nt = fid & 7;
  int k0 = ks * 32 + (L >> 4) * 8;
  int n  = nt * 16 + (L & 15);
  unsigned int hi[4];
#pragma unroll
  for (int p = 0; p < 4; p++) {
    float w0 = W[(size_t)(k0 + 2*p) * 128 + n];
    float w1 = W[(size_t)(k0 + 2*p + 1) * 128 + n];
    hi[p] = (f2u(w0) >> 16) | (f2u(w1) & 0xFFFF0000u);
  }
  *(uint4*)(out + (size_t)fid * 512 + (size_t)L * 8) = make_uint4(hi[0], hi[1], hi[2], hi[3]);
}

// ---------------------------------------------------------------- generic split-bf16 B-fragment prep
__global__ __launch_bounds__(256) void k_prep(
    const float* __restrict__ WA, const float* __restrict__ WB,
    int mode, int split, int wA, int wB, int Ktot, int NT, int nfrag,
    unsigned short* __restrict__ out)
{
  int t = blockIdx.x * 256 + threadIdx.x;
  int fid = t >> 6, L = t & 63;
  if (fid >= nfrag) return;
  int ks = fid / NT, nt = fid % NT;
  int k0 = ks * 32 + (L >> 4) * 8;
  int n  = nt * 16 + (L & 15);
  unsigned int hi[4], lo[4];
#pragma unroll
  for (int p = 0; p < 4; p++) {
    float w0 = 0.f, w1 = 0.f;
    int ka = k0 + 2*p, kb = ka + 1;
    if (mode == 0) {
      if (ka < Ktot) w0 = (ka < split) ? WA[(size_t)ka*wA + n] : WB[(size_t)(ka-split)*wB + n];
      if (kb < Ktot) w1 = (kb < split) ? WA[(size_t)kb*wA + n] : WB[(size_t)(kb-split)*wB + n];
    } else {
      if (ka < Ktot) w0 = (n < split) ? WA[(size_t)ka*wA + n] : WB[(size_t)ka*wB + (n-split)];
      if (kb < Ktot) w1 = (n < split) ? WA[(size_t)kb*wA + n] : WB[(size_t)kb*wB + (n-split)];
    }
    unsigned int u0 = f2u(w0), u1 = f2u(w1);
    unsigned int h0 = u0 & 0xFFFF0000u, h1 = u1 & 0xFFFF0000u;
    hi[p] = (u0 >> 16) | h1;
    float l0 = w0 - u2f(h0), l1 = w1 - u2f(h1);
    lo[p] = (f2u(l0) >> 16) | (f2u(l1) & 0xFFFF0000u);
  }
  size_t base = (size_t)(fid * 2) * 512 + (size_t)L * 8;
  *(uint4*)(out + base)       = make_uint4(hi[0], hi[1], hi[2], hi[3]);
  *(uint4*)(out + base + 512) = make_uint4(lo[0], lo[1], lo[2], lo[3]);
}

// ---------------------------------------------------------------- xz GEMM (once)
__global__ __launch_bounds__(256) void k_xz_mfma(
    const float* __restrict__ hist, const float* __restrict__ z,
    const unsigned short* __restrict__ wB,
    const float* __restrict__ b_gh, const float* __restrict__ b_gih,
    float* __restrict__ gh0, float* __restrict__ gi)
{
  __shared__ __align__(16) float Abuf[64][36];
  const int tid = threadIdx.x;
  const int w = tid >> 6, lane = tid & 63;
  const int m = lane & 15, q = lane >> 4;
  const int n0 = blockIdx.x * 64;
  const int r_ = tid >> 2, c_ = (tid & 3) * 8;
  float4x acc[16];
#pragma unroll
  for (int tl = 0; tl < 16; tl++) acc[tl] = (float4x){0.f,0.f,0.f,0.f};

  for (int ks = 0; ks < 9; ks++) {
    __syncthreads();
    {
      int kk = ks*32 + c_;
      int n = n0 + r_;
      float4 v0, v1;
      if (kk < 256) {
        v0 = *(const float4*)&hist[(size_t)n*256 + kk];
        v1 = *(const float4*)&hist[(size_t)n*256 + kk + 4];
      } else if (kk == 256) {
        v0 = *(const float4*)&z[n*8];
        v1 = *(const float4*)&z[n*8 + 4];
      } else {
        v0 = make_float4(0,0,0,0); v1 = v0;
      }
      *(float4*)&Abuf[r_][c_]     = v0;
      *(float4*)&Abuf[r_][c_ + 4] = v1;
    }
    __syncthreads();
    short8x aHi, aLo;
    split8(&Abuf[w*16 + m][q*8], aHi, aLo);
#pragma unroll
    for (int tl = 0; tl < 16; tl++) {
      int nt = blockIdx.y*16 + tl;
      size_t off = (size_t)((ks*64 + nt)*2) * 512 + (size_t)lane*8;
      short8x bh = *(const short8x*)(wB + off);
      short8x bl = *(const short8x*)(wB + off + 512);
      acc[tl] = __builtin_amdgcn_mfma_f32_16x16x32_bf16(aHi, bl, acc[tl], 0, 0, 0);
      acc[tl] = __builtin_amdgcn_mfma_f32_16x16x32_bf16(aLo, bh, acc[tl], 0, 0, 0);
      acc[tl] = __builtin_amdgcn_mfma_f32_16x16x32_bf16(aHi, bh, acc[tl], 0, 0, 0);
    }
  }
#pragma unroll
  for (int tl = 0; tl < 16; tl++) {
    int col = (blockIdx.y*16 + tl)*16 + m;
    float bias = (col < 256) ? b_gh[col] : b_gih[col - 256];
#pragma unroll
    for (int i = 0; i < 4; i++) {
      int n = n0 + w*16 + q*4 + i;
      float v = acc[tl][i] + bias;
      if (col < 256) gh0[(size_t)n*256 + col] = v;
      else           gi[(size_t)n*768 + col - 256] = v;
    }
  }
}

// ---------------------------------------------------------------- GRU core (shared)
DEVI void gru_core(float (*Abuf)[36], int tid, int n0, int j0,
                   const float* __restrict__ h_in, const unsigned short* __restrict__ wB,
                   const float* __restrict__ b_hh, const float* __restrict__ gi,
                   const float* __restrict__ W_proj, float* __restrict__ des_t,
                   float* __restrict__ h_out)
{
  const int w = tid >> 6, lane = tid & 63;
  const int m = lane & 15, q = lane >> 4;
  const int r_ = tid >> 2, c_ = (tid & 3) * 8;
  float4x acc[12];
#pragma unroll
  for (int tl = 0; tl < 12; tl++) acc[tl] = (float4x){0.f,0.f,0.f,0.f};

  for (int ks = 0; ks < 8; ks++) {
    __syncthreads();
    {
      int kk = ks*32 + c_;
      int n = n0 + r_;
      *(float4*)&Abuf[r_][c_]     = *(const float4*)&h_in[(size_t)n*256 + kk];
      *(float4*)&Abuf[r_][c_ + 4] = *(const float4*)&h_in[(size_t)n*256 + kk + 4];
    }
    __syncthreads();
    short8x aHi, aLo;
    split8(&Abuf[w*16 + m][q*8], aHi, aLo);
#pragma unroll
    for (int tl = 0; tl < 12; tl++) {
      int g = tl >> 2, jt = tl & 3;
      int nt = g*16 + (j0 >> 4) + jt;
      size_t off = (size_t)((ks*48 + nt)*2) * 512 + (size_t)lane*8;
      short8x bh = *(const short8x*)(wB + off);
      short8x bl = *(const short8x*)(wB + off + 512);
      acc[tl] = __builtin_amdgcn_mfma_f32_16x16x32_bf16(aHi, bl, acc[tl], 0, 0, 0);
      acc[tl] = __builtin_amdgcn_mfma_f32_16x16x32_bf16(aLo, bh, acc[tl], 0, 0, 0);
      acc[tl] = __builtin_amdgcn_mfma_f32_16x16x32_bf16(aHi, bh, acc[tl], 0, 0, 0);
    }
  }
  float pd0[4] = {0,0,0,0}, pd1[4] = {0,0,0,0};
#pragma unroll
  for (int jt = 0; jt < 4; jt++) {
    int j = j0 + jt*16 + m;
    float br = b_hh[j], bz = b_hh[256 + j], bn = b_hh[512 + j];
    float wp0 = W_proj[j*2], wp1 = W_proj[j*2 + 1];
#pragma unroll
    for (int i = 0; i < 4; i++) {
      int n = n0 + w*16 + q*4 + i;
      float ir  = gi[(size_t)n*768 + j];
      float iz  = gi[(size_t)n*768 + 256 + j];
      float inn = gi[(size_t)n*768 + 512 + j];
      float hold = h_in[(size_t)n*256 + j];
      float r = sigf(ir + acc[0*4 + jt][i] + br);
      float u = sigf(iz + acc[1*4 + jt][i] + bz);
      float nh = (1.f - u) * tanhf_fast(inn + r * (acc[2*4 + jt][i] + bn)) + u * hold;
      h_out[(size_t)n*256 + j] = nh;
      pd0[i] += nh * wp0;
      pd1[i] += nh * wp1;
    }
  }
#pragma unroll
  for (int off = 1; off < 16; off <<= 1) {
#pragma unroll
    for (int i = 0; i < 4; i++) {
      pd0[i] += __shfl_xor(pd0[i], off);
      pd1[i] += __shfl_xor(pd1[i], off);
    }
  }
  if (m == 0) {
#pragma unroll
    for (int i = 0; i < 4; i++) {
      int n = n0 + w*16 + q*4 + i;
      atomicAdd(&des_t[n*2],     pd0[i]);
      atomicAdd(&des_t[n*2 + 1], pd1[i]);
    }
  }
}

// ---------------------------------------------------------------- standalone GRU step (prologue)
__global__ __launch_bounds__(256) void k_gru_mfma(
    const float* __restrict__ h_in, const unsigned short* __restrict__ wB,
    const float* __restrict__ b_hh, const float* __restrict__ gi,
    const float* __restrict__ W_proj, float* __restrict__ des_t,
    float* __restrict__ h_out)
{
  __shared__ __align__(16) float Abuf[64][36];
  gru_core(Abuf, threadIdx.x, blockIdx.x * 64, blockIdx.y * 64,
           h_in, wB, b_hh, gi, W_proj, des_t, h_out);
}

// ---------------------------------------------------------------- LSTM cell (MFMA), j-tile = 32
__global__ __launch_bounds__(256) void k_lstm_mfma(
    const float* __restrict__ ctxg, const float* __restrict__ h_in,
    const unsigned short* __restrict__ wB,
    const float* __restrict__ b_ih, const float* __restrict__ b_hh,
    float* __restrict__ c_st, float* __restrict__ h_out)
{
  __shared__ __align__(16) float Abuf[64][36];
  const int tid = threadIdx.x;
  const int w = tid >> 6, lane = tid & 63;
  const int m = lane & 15, q = lane >> 4;
  const int n0 = blockIdx.x * 64;
  const int j0 = blockIdx.y * 32;
  const int r_ = tid >> 2, c_ = (tid & 3) * 8;
  float4x acc[8];
#pragma unroll
  for (int tl = 0; tl < 8; tl++) acc[tl] = (float4x){0.f,0.f,0.f,0.f};

  for (int ks = 0; ks < 12; ks++) {
    __syncthreads();
    {
      int kk = ks*32 + c_;
      int n = n0 + r_;
      float4 v0, v1;
      if (kk < 128) {
        v0 = *(const float4*)&ctxg[(size_t)n*128 + kk];
        v1 = *(const float4*)&ctxg[(size_t)n*128 + kk + 4];
      } else {
        v0 = *(const float4*)&h_in[(size_t)n*256 + kk - 128];
        v1 = *(const float4*)&h_in[(size_t)n*256 + kk - 124];
      }
      *(float4*)&Abuf[r_][c_]     = v0;
      *(float4*)&Abuf[r_][c_ + 4] = v1;
    }
    __syncthreads();
    short8x aHi, aLo;
    split8(&Abuf[w*16 + m][q*8], aHi, aLo);
#pragma unroll
    for (int tl = 0; tl < 8; tl++) {
      int g = tl >> 1, jt = tl & 1;
      int nt = g*16 + (j0 >> 4) + jt;
      size_t off = (size_t)((ks*64 + nt)*2) * 512 + (size_t)lane*8;
      short8x bh = *(const short8x*)(wB + off);
      short8x bl = *(const short8x*)(wB + off + 512);
      acc[tl] = __builtin_amdgcn_mfma_f32_16x16x32_bf16(aHi, bl, acc[tl], 0, 0, 0);
      acc[tl] = __builtin_amdgcn_mfma_f32_16x16x32_bf16(aLo, bh, acc[tl], 0, 0, 0);
      acc[tl] = __builtin_amdgcn_mfma_f32_16x16x32_bf16(aHi, bh, acc[tl], 0, 0, 0);
    }
  }
#pragma unroll
  for (int jt = 0; jt < 2; jt++) {
    int j = j0 + jt*16 + m;
    float bi = b_ih[j]       + b_hh[j];
    float bf = b_ih[256 + j] + b_hh[256 + j];
    float bg = b_ih[512 + j] + b_hh[512 + j];
    float bo = b_ih[768 + j] + b_hh[768 + j];
#pragma unroll
    for (int i = 0; i < 4; i++) {
      int n = n0 + w*16 + q*4 + i;
      float g_i = sigf(acc[0*2 + jt][i] + bi);
      float g_f = sigf(acc[1*2 + jt][i] + bf);
      float g_g = tanhf_fast(acc[2*2 + jt][i] + bg);
      float g_o = sigf(acc[3*2 + jt][i] + bo);
      float cv = g_f * c_st[(size_t)n*256 + j] + g_i * g_g;
      c_st[(size_t)n*256 + j] = cv;
      h_out[(size_t)n*256 + j] = g_o * tanhf_fast(cv);
    }
  }
}

// ---------------------------------------------------------------- action MLP: 32 nodes/block
__global__ __launch_bounds__(256) void k_action_mfma(
    const float* __restrict__ h, const float* __restrict__ z,
    const float* __restrict__ rel, const float* __restrict__ nwp, const float* __restrict__ nwp2,
    const unsigned short* __restrict__ wB, const float* __restrict__ b_a1,
    const float* __restrict__ W_a2, const float* __restrict__ b_a2,
    float* __restrict__ prev, float* __restrict__ prev_st,
    float* __restrict__ outS, float* __restrict__ outU)
{
  __shared__ __align__(16) float Abuf[32][36];
  __shared__ float sm_p[2][16][2];
  const int tid = threadIdx.x;
  const int w = tid >> 6, lane = tid & 63;
  const int m = lane & 15, q = lane >> 4;
  const int ng = w >> 1, hh = w & 1;
  const int n0 = blockIdx.x * 32;
  const int r_ = tid >> 3, c_ = (tid & 7) * 4;
  float4x acc[8];
#pragma unroll
  for (int j = 0; j < 8; j++) acc[j] = (float4x){0.f,0.f,0.f,0.f};

  for (int ks = 0; ks < 9; ks++) {
    __syncthreads();
    {
      int kk = ks*32 + c_;
      int n = n0 + r_;
      float4 v;
      if (kk < 256)      v = *(const float4*)&h[(size_t)n*256 + kk];
      else if (kk == 256) v = *(const float4*)&z[n*8];
      else if (kk == 260) v = *(const float4*)&z[n*8 + 4];
      else if (kk == 264) v = *(const float4*)&rel[n*4];
      else if (kk == 268) {
        float2 w1 = *(const float2*)&nwp[n*2];
        float2 w2 = *(const float2*)&nwp2[n*2];
        v = make_float4(w1.x, w1.y, w2.x, w2.y);
      } else v = make_float4(0,0,0,0);
      *(float4*)&Abuf[r_][c_] = v;
    }
    __syncthreads();
    short8x aHi, aLo;
    split8(&Abuf[ng*16 + m][q*8], aHi, aLo);
#pragma unroll
    for (int j = 0; j < 8; j++) {
      int tl = hh*8 + j;
      size_t off = (size_t)((ks*16 + tl)*2) * 512 + (size_t)lane*8;
      short8x bh = *(const short8x*)(wB + off);
      short8x bl = *(const short8x*)(wB + off + 512);
      acc[j] = __builtin_amdgcn_mfma_f32_16x16x32_bf16(aHi, bl, acc[j], 0, 0, 0);
      acc[j] = __builtin_amdgcn_mfma_f32_16x16x32_bf16(aLo, bh, acc[j], 0, 0, 0);
      acc[j] = __builtin_amdgcn_mfma_f32_16x16x32_bf16(aHi, bh, acc[j], 0, 0, 0);
    }
  }
  float p0[4] = {0,0,0,0}, p1[4] = {0,0,0,0};
#pragma unroll
  for (int j = 0; j < 8; j++) {
    int col = (hh*8 + j)*16 + m;
    float ba = b_a1[col];
    float2 w2 = *(const float2*)&W_a2[col*2];
#pragma unroll
    for (int i = 0; i < 4; i++) {
      float hv = fmaxf(acc[j][i] + ba, 0.f);
      p0[i] += hv * w2.x;
      p1[i] += hv * w2.y;
    }
  }
#pragma unroll
  for (int off = 1; off < 16; off <<= 1) {
#pragma unroll
    for (int i = 0; i < 4; i++) {
      p0[i] += __shfl_xor(p0[i], off);
      p1[i] += __shfl_xor(p1[i], off);
    }
  }
  if (hh == 1 && m == 0) {
#pragma unroll
    for (int i = 0; i < 4; i++) {
      sm_p[ng][q*4 + i][0] = p0[i];
      sm_p[ng][q*4 + i][1] = p1[i];
    }
  }
  __syncthreads();
  if (hh == 0 && m == 0) {
    float ba0 = b_a2[0], ba1 = b_a2[1];
    const float hd = 0.5f * DT_ * DT_;
#pragma unroll
    for (int i = 0; i < 4; i++) {
      int n = n0 + ng*16 + q*4 + i;
      float ux = tanhf_fast(p0[i] + sm_p[ng][q*4 + i][0] + ba0);
      float uy = tanhf_fast(p1[i] + sm_p[ng][q*4 + i][1] + ba1);
      float4 pv = *(const float4*)&prev[n*4];
      float4 ps = *(const float4*)&prev_st[n*4];
      float4 npv, nps;
      npv.x = pv.x + pv.z*DT_ + ux*hd;
      npv.y = pv.y + pv.w*DT_ + uy*hd;
      npv.z = pv.z + ux*DT_;
      npv.w = pv.w + uy*DT_;
      nps.x = ps.x + ps.z*DT_ + ux*hd;
      nps.y = ps.y + ps.w*DT_ + uy*hd;
      nps.z = ps.z + ux*DT_;
      nps.w = ps.w + uy*DT_;
      *(float4*)&prev[n*4] = npv;
      *(float4*)&prev_st[n*4] = nps;
      *(float4*)&outS[(size_t)n*4] = npv;
      outU[n*2]     = ux;
      outU[n*2 + 1] = uy;
    }
  }
}

// ---------------------------------------------------------------- LSTM h0/c0 + prev copies
__global__ __launch_bounds__(256) void k_init_hc(
    const float* __restrict__ x_last, const float* __restrict__ x_st_last,
    const float* __restrict__ W_h0, const float* __restrict__ b_h0,
    const float* __restrict__ W_c0, const float* __restrict__ b_c0,
    float* __restrict__ h, float* __restrict__ c,
    float* __restrict__ prev, float* __restrict__ prev_st)
{
  const int n = blockIdx.x;
  const int j = threadIdx.x;
  float x0 = x_st_last[n*4], x1 = x_st_last[n*4+1], x2 = x_st_last[n*4+2], x3 = x_st_last[n*4+3];
  h[(size_t)n*256 + j] = b_h0[j] + x0*W_h0[j] + x1*W_h0[256+j] + x2*W_h0[512+j] + x3*W_h0[768+j];
  c[(size_t)n*256 + j] = b_c0[j] + x0*W_c0[j] + x1*W_c0[256+j] + x2*W_c0[512+j] + x3*W_c0[768+j];
  if (j < 4) prev[n*4 + j] = x_last[n*4 + j];
  else if (j < 8) prev_st[n*4 + (j-4)] = x_st_last[n*4 + (j-4)];
}

// ---------------------------------------------------------------- FUSED: edge (blocks 0..2047, 4 nodes) | GRU (blocks 2048..2559)
// (256,4): proven no-spill point (VGPR cap 128). B = hi-only bf16, A = split hi/lo (2 MFMA),
// double-buffered 8KB LDS staging, 1 barrier/ks.
__global__ __launch_bounds__(256, 4) void k_edge_gru(
    const float* __restrict__ prev, const float* __restrict__ prev_st,
    const float* __restrict__ x_st_last,
    const float* __restrict__ szf, const float* __restrict__ rad,
    const int* __restrict__ nobs, const int* __restrict__ e1, const int* __restrict__ e2,
    const float* __restrict__ W_e1, const float* __restrict__ b_e1,
    const unsigned short* __restrict__ wsB, const float* __restrict__ b_e2,
    const float* __restrict__ wattT, const float* __restrict__ W_att2,
    const float* __restrict__ v_att,
    const float* __restrict__ des_p, const float* __restrict__ des_t,
    const float* __restrict__ des_n,
    float* __restrict__ relg, float* __restrict__ nwp, float* __restrict__ nwp2,
    float* __restrict__ ctx, float* __restrict__ ss_t, float* __restrict__ cc,
    const float* __restrict__ g_hin, const unsigned short* __restrict__ wBg,
    const float* __restrict__ b_ghh, const float* __restrict__ gi,
    const float* __restrict__ W_proj, float* __restrict__ des_g,
    float* __restrict__ g_hout, int gru_on)
{
  // LDS: stage 2x8KB [4096 fl] | feats[512]@4096 | flags[64]@4608 | relv[16]@4672
  //      w1T[2048]@4688 | watt2[64]@6736 | vatt[16]@6800 | red[8]@6816 -> 6824 floats
  __shared__ __align__(16) float smem[6824];
  const int tid = threadIdx.x;

  if (blockIdx.x >= 2048) {
    if (!gru_on) return;
    int b = blockIdx.x - 2048;
    gru_core((float(*)[36])smem, tid, (b & 127) * 64, (b >> 7) * 64,
             g_hin, wBg, b_ghh, gi, W_proj, des_g, g_hout);
    return;
  }

  float* sm_stage = smem;
  float* sm_feats = smem + 4096;
  float* sm_flags = smem + 4608;
  float* sm_relv  = smem + 4672;
  float* sm_w1T   = smem + 4688;
  float* sm_watt2 = smem + 6736;
  float* sm_vatt  = smem + 6800;
  float* sm_red   = smem + 6816;

  const int n0  = blockIdx.x * 4;
  const int lane = tid & 63;
  const int g    = tid >> 6;
  const int q = lane >> 4, m = lane & 15;

  // ---- P0
  for (int i = tid; i < 2048; i += 256) sm_w1T[i] = wattT[i];
  if (tid >= 176 && tid < 192) sm_vatt[tid - 176] = v_att[tid - 176];
  if (tid >= 192) sm_watt2[tid - 192] = W_att2[tid - 192];

  if (tid < 64) {
    float v = 0.f;
    if (tid < 60) {
      int gg = tid / 15, k = tid % 15;
      int idx = nobs[(n0 + gg) * 15 + k];
      float f[8] = {0,0,0,0,0,0,0,0};
      float fl = 0.f;
      if (idx > 0) {
        int e = idx - 1;
        int i1 = e1[e], i2 = e2[e];
#pragma unroll
        for (int d = 0; d < 4; d++) f[d] = prev[i2*4 + d] - prev[i1*4 + d];
        float4 sz = *(const float4*)&szf[(size_t)e*4];
        f[4] = sz.x; f[5] = sz.y; f[6] = sz.z; f[7] = sz.w;
        fl = 1.f;
        float dist = sqrtf(f[0]*f[0] + f[1]*f[1]);
        v = fmaxf(rad[e] - dist, 0.f);
      }
#pragma unroll
      for (int d = 0; d < 8; d++) sm_feats[(gg*16 + k)*8 + d] = f[d];
      sm_flags[gg*16 + k] = fl;
    } else {
      int gg = tid - 60;
#pragma unroll
      for (int d = 0; d < 8; d++) sm_feats[(gg*16 + 15)*8 + d] = 0.f;
      sm_flags[gg*16 + 15] = 0.f;
    }
#pragma unroll
    for (int off = 32; off; off >>= 1) v += __shfl_down(v, off);
    if (tid == 0) atomicAdd(cc, v);
  } else if (tid < 68) {
    int gg = tid - 64;
    int n = n0 + gg;
    float4 ps = *(const float4*)&prev_st[n*4];
    float r0, r1, r2, r3;
    if (des_p) {
      float4 xs = *(const float4*)&x_st_last[n*4];
      r0 = ps.x - xs.x - des_p[n*2];
      r1 = ps.y - xs.y - des_p[n*2 + 1];
      r2 = ps.z - xs.z;
      r3 = ps.w - xs.w;
    } else { r0 = ps.x; r1 = ps.y; r2 = ps.z; r3 = ps.w; }
    sm_relv[gg*4+0] = r0; sm_relv[gg*4+1] = r1; sm_relv[gg*4+2] = r2; sm_relv[gg*4+3] = r3;
    *(float4*)&relg[n*4] = make_float4(r0, r1, r2, r3);
    nwp[n*2]      = des_t[n*2]     - ps.x;
    nwp[n*2 + 1]  = des_t[n*2 + 1] - ps.y;
    nwp2[n*2]     = des_n[n*2]     - ps.x;
    nwp2[n*2 + 1] = des_n[n*2 + 1] - ps.y;
    sm_red[gg] = r0*r0 + r1*r1;
  }
  // initial stage of ks=0 (hi-only, 8KB) into buf0
  {
    const uint4* src = (const uint4*)wsB;
    uint4* dst = (uint4*)sm_stage;
    dst[tid]       = src[tid];
    dst[tid + 256] = src[tid + 256];
  }
  __syncthreads();
  if (tid == 64) atomicAdd(ss_t, sm_red[0] + sm_red[1] + sm_red[2] + sm_red[3]);

  // ---- P1+P2 pipelined over ks: prefetch(ks+1)->regs, P1 VALU, MFMA from buf[ks&1], write buf[(ks+1)&1], barrier
  float f[8];
  {
    const float4 fa = *(const float4*)&sm_feats[(g*16 + m)*8];
    const float4 fb = *(const float4*)&sm_feats[(g*16 + m)*8 + 4];
    f[0]=fa.x; f[1]=fa.y; f[2]=fa.z; f[3]=fa.w; f[4]=fb.x; f[5]=fb.y; f[6]=fb.z; f[7]=fb.w;
  }
  float4x encR[8];
#pragma unroll
  for (int nt = 0; nt < 8; nt++) encR[nt] = (float4x){0.f,0.f,0.f,0.f};
  const float4* We14 = (const float4*)W_e1;
  const float4* Be14 = (const float4*)b_e1;

  for (int ks = 0; ks < 8; ks++) {
    uint4 r0, r1;
    if (ks < 7) {
      const uint4* src = (const uint4*)wsB + (ks + 1) * 512;
      r0 = src[tid];
      r1 = src[tid + 256];
    }
    short8x aHi, aLo;
    {
      float h8[8];
      float4 b0 = Be14[8*ks + 2*q];
      float4 b1 = Be14[8*ks + 2*q + 1];
      h8[0]=b0.x; h8[1]=b0.y; h8[2]=b0.z; h8[3]=b0.w; h8[4]=b1.x; h8[5]=b1.y; h8[6]=b1.z; h8[7]=b1.w;
#pragma unroll
      for (int d = 0; d < 8; d++) {
        float4 wa = We14[d*64 + ks*8 + 2*q];
        float4 wb = We14[d*64 + ks*8 + 2*q + 1];
        h8[0] += f[d]*wa.x; h8[1] += f[d]*wa.y; h8[2] += f[d]*wa.z; h8[3] += f[d]*wa.w;
        h8[4] += f[d]*wb.x; h8[5] += f[d]*wb.y; h8[6] += f[d]*wb.z; h8[7] += f[d]*wb.w;
      }
#pragma unroll
      for (int p = 0; p < 8; p++) h8[p] = fmaxf(h8[p], 0.f);
      split8(h8, aHi, aLo);
    }
    const unsigned short* sb = (const unsigned short*)sm_stage + (ks & 1) * 4096;
#pragma unroll
    for (int nt = 0; nt < 8; nt++) {
      short8x bh = *(const short8x*)(sb + nt*512 + lane*8);
      encR[nt] = __builtin_amdgcn_mfma_f32_16x16x32_bf16(aLo, bh, encR[nt], 0, 0, 0);
      encR[nt] = __builtin_amdgcn_mfma_f32_16x16x32_bf16(aHi, bh, encR[nt], 0, 0, 0);
    }
    if (ks < 7) {
      uint4* dst = (uint4*)sm_stage + ((ks + 1) & 1) * 512;
      dst[tid]       = r0;
      dst[tid + 256] = r1;
      __syncthreads();
    }
  }
  float4x fl4 = *(const float4x*)&sm_flags[g*16 + q*4];
#pragma unroll
  for (int nt = 0; nt < 8; nt++) {
    float b2 = b_e2[nt*16 + m];
#pragma unroll
    for (int i = 0; i < 4; i++) encR[nt][i] = (encR[nt][i] + b2) * fl4[i];
  }

  // ---- P3: score partials
  float4x part[16];
#pragma unroll
  for (int a = 0; a < 16; a++) part[a] = (float4x){0.f,0.f,0.f,0.f};
#pragma unroll
  for (int a = 0; a < 16; a++) {
#pragma unroll
    for (int nt = 0; nt < 8; nt++) {
      float wv = sm_w1T[a*128 + nt*16 + m];
      part[a] = part[a] + encR[nt] * wv;
    }
  }

  // ---- P4: halving-exchange over m
  const bool s8 = (m & 8) != 0, s4b = (m & 4) != 0, s2b = (m & 2) != 0, s1b = (m & 1) != 0;
  float4x c8[8];
#pragma unroll
  for (int a = 0; a < 8; a++) {
    float4x mi, sd, rc;
#pragma unroll
    for (int e = 0; e < 4; e++) {
      mi[e] = s8 ? part[a+8][e] : part[a][e];
      sd[e] = s8 ? part[a][e] : part[a+8][e];
      rc[e] = __shfl_xor(sd[e], 8);
    }
    c8[a] = mi + rc;
  }
  float4x c4[4];
#pragma unroll
  for (int a = 0; a < 4; a++) {
    float4x mi, sd, rc;
#pragma unroll
    for (int e = 0; e < 4; e++) {
      mi[e] = s4b ? c8[a+4][e] : c8[a][e];
      sd[e] = s4b ? c8[a][e] : c8[a+4][e];
      rc[e] = __shfl_xor(sd[e], 4);
    }
    c4[a] = mi + rc;
  }
  float4x c2[2];
#pragma unroll
  for (int a = 0; a < 2; a++) {
    float4x mi, sd, rc;
#pragma unroll
    for (int e = 0; e < 4; e++) {
      mi[e] = s2b ? c4[a+2][e] : c4[a][e];
      sd[e] = s2b ? c4[a][e] : c4[a+2][e];
      rc[e] = __shfl_xor(sd[e], 2);
    }
    c2[a] = mi + rc;
  }
  float4x c1;
  {
    float4x mi, sd, rc;
#pragma unroll
    for (int e = 0; e < 4; e++) {
      mi[e] = s1b ? c2[1][e] : c2[0][e];
      sd[e] = s1b ? c2[0][e] : c2[1][e];
      rc[e] = __shfl_xor(sd[e], 1);
    }
    c1 = mi + rc;
  }

  // ---- P5: softmax + ctx
  float relw;
  {
    float4 rv = *(const float4*)&sm_relv[g*4];
    relw = rv.x * sm_watt2[m] + rv.y * sm_watt2[16 + m]
         + rv.z * sm_watt2[32 + m] + rv.w * sm_watt2[48 + m];
  }
  float vat = sm_vatt[m];
  float val[4];
#pragma unroll
  for (int i = 0; i < 4; i++) val[i] = tanhf_fast(c1[i] + relw) * vat;
#pragma unroll
  for (int msk = 1; msk < 16; msk <<= 1) {
#pragma unroll
    for (int i = 0; i < 4; i++) val[i] += __shfl_xor(val[i], msk);
  }
  if (q == 3) val[3] = -3.0e38f;
  float mx = fmaxf(fmaxf(val[0], val[1]), fmaxf(val[2], val[3]));
  mx = fmaxf(mx, __shfl_xor(mx, 16));
  mx = fmaxf(mx, __shfl_xor(mx, 32));
  float4x ev;
  float ssum = 0.f;
#pragma unroll
  for (int i = 0; i < 4; i++) { ev[i] = __expf(val[i] - mx); ssum += ev[i]; }
  ssum += __shfl_xor(ssum, 16);
  ssum += __shfl_xor(ssum, 32);
  float inv = 1.f / ssum;
#pragma unroll
  for (int i = 0; i < 4; i++) ev[i] *= inv;

  float cpart[8];
#pragma unroll
  for (int nt = 0; nt < 8; nt++) {
    float cv = ev[0]*encR[nt][0] + ev[1]*encR[nt][1] + ev[2]*encR[nt][2] + ev[3]*encR[nt][3];
    cv += __shfl_xor(cv, 16);
    cv += __shfl_xor(cv, 32);
    cpart[nt] = cv;
  }
  float v0 = (q == 0) ? cpart[0] : (q == 1) ? cpart[2] : (q == 2) ? cpart[4] : cpart[6];
  float v1 = (q == 0) ? cpart[1] : (q == 1) ? cpart[3] : (q == 2) ? cpart[5] : cpart[7];
  size_t cb = (size_t)(n0 + g) * 128 + q*32 + m;
  ctx[cb]      = v0;
  ctx[cb + 16] = v1;
}

// ---------------------------------------------------------------- finalize scalars
__global__ void k_final(const float* __restrict__ ss, float* __restrict__ out) {
  if (threadIdx.x == 0) {
    float t = 0.f;
    for (int i = 0; i < FTS; i++) t += sqrtf(ss[i]);
    out[(size_t)FTS * N_ * 6]     = t / (float)N_;
    out[(size_t)FTS * N_ * 6 + 1] = ss[FTS];
  }
}

// ================================================================ launch
extern "C" void kernel_launch(void* const* d_in, const int* in_sizes, int n_in,
                              void* d_out, int out_size, void* d_ws, size_t ws_size,
                              hipStream_t stream) {
  (void)in_sizes; (void)n_in; (void)out_size;
  const float* x_last    = (const float*)d_in[0];
  const float* x_st_last = (const float*)d_in[1];
  const float* hist_enc  = (const float*)d_in[2];
  const float* z         = (const float*)d_in[3];
  const float* node_size = (const float*)d_in[4];
  const float* W_h0 = (const float*)d_in[5];
  const float* b_h0 = (const float*)d_in[6];
  const float* W_c0 = (const float*)d_in[7];
  const float* b_c0 = (const float*)d_in[8];
  const float* W_gh = (const float*)d_in[9];
  const float* b_gh = (const float*)d_in[10];
  const float* W_gih = (const float*)d_in[11];
  const float* W_ghh = (const float*)d_in[12];
  const float* b_gih = (const float*)d_in[13];
  const float* b_ghh = (const float*)d_in[14];
  const float* W_proj = (const float*)d_in[15];
  const float* b_proj = (const float*)d_in[16];
  const float* W_att1 = (const float*)d_in[17];
  const float* W_att2 = (const float*)d_in[18];
  const float* v_att  = (const float*)d_in[19];
  const float* W_lih = (const float*)d_in[20];
  const float* W_lhh = (const float*)d_in[21];
  const float* b_lih = (const float*)d_in[22];
  const float* b_lhh = (const float*)d_in[23];
  const float* W_e1 = (const float*)d_in[24];
  const float* b_e1 = (const float*)d_in[25];
  const float* W_e2 = (const float*)d_in[26];
  const float* b_e2 = (const float*)d_in[27];
  const float* W_a1 = (const float*)d_in[28];
  const float* b_a1 = (const float*)d_in[29];
  const float* W_a2 = (const float*)d_in[30];
  const float* b_a2 = (const float*)d_in[31];
  const int* e1   = (const int*)d_in[32];
  const int* e2   = (const int*)d_in[33];
  const int* nobs = (const int*)d_in[34];
  float* out = (float*)d_out;

  // workspace carve (floats)
  float* wsf     = (float*)d_ws;
  float* prev    = wsf;
  float* prev_st = wsf + 32768;
  float* des     = wsf + 65536;
  float* ss      = wsf + 262144;
  float* rad     = wsf + 262160;
  float* szf     = wsf + 385040;            // -> end 876560
  float* baseA   = wsf + 876560;            // union region, 5 units of N*256 -> end 11362320
  // serial-phase aliased view
  float* gh0 = baseA;
  float* gh1 = baseA + (size_t)N_ * 256;
  float* gi  = baseA + (size_t)2 * N_ * 256;
  // main phase view
  float* hA   = baseA;
  float* hB   = baseA + (size_t)N_ * 256;
  float* cbuf = baseA + (size_t)2 * N_ * 256;
  float* ctx  = baseA + (size_t)3 * N_ * 256;
  float* rel  = baseA + (size_t)4 * N_ * 256;
  float* nwp  = rel + (size_t)N_ * 4;
  float* nwp2 = nwp + (size_t)N_ * 2;
  // prepped B fragments
  unsigned short* wsBe = (unsigned short*)(wsf + 11362320);   // hi-only edge frags (32768 ush)
  unsigned short* wsBg = (unsigned short*)(wsf + 11427856);
  unsigned short* wsBl = (unsigned short*)(wsf + 11624464);
  unsigned short* wsBx = (unsigned short*)(wsf + 12017680);
  unsigned short* wsBa = (unsigned short*)(wsf + 12312592);
  float* wattT = wsf + 12386320;                              // -> end 12388368
  // fused-path GRU buffers (disjoint from main-phase aliases)
  float* ext = wsf + 12388368;
  const size_t needF = 12388368ull + 5ull * N_ * 256ull;
  const bool fuse = ws_size >= needF * 4ull;
  float* gh0F = fuse ? ext : gh0;
  float* gh1F = fuse ? (ext + (size_t)N_ * 256) : gh1;
  float* giF  = fuse ? (ext + (size_t)2 * N_ * 256) : gi;

  k_zero<<<1, 64, 0, stream>>>(ss);
  k_edge_static<<<(E_ + 255) / 256, 256, 0, stream>>>(e1, e2, node_size, rad, szf);
  k_init_des<<<FTS * N_ / 256, 256, 0, stream>>>(b_proj, des);
  k_prep_attT<<<8, 256, 0, stream>>>(W_att1, wattT);

  k_prep_hi<<<16, 256, 0, stream>>>(W_e2, wsBe);
  k_prep<<<96,  256, 0, stream>>>(W_ghh, W_ghh, 0, 256, 768,  768,  256, 48, 384, wsBg);
  k_prep<<<192, 256, 0, stream>>>(W_lih, W_lhh, 0, 128, 1024, 1024, 384, 64, 768, wsBl);
  k_prep<<<144, 256, 0, stream>>>(W_gh,  W_gih, 1, 256, 256,  768,  264, 64, 576, wsBx);
  k_prep<<<36,  256, 0, stream>>>(W_a1,  W_a1,  0, 272, 256,  256,  272, 16, 144, wsBa);

  // guide GRU: prologue steps (2 if fused, all 12 otherwise)
  k_xz_mfma<<<dim3(128, 4), 256, 0, stream>>>(hist_enc, z, wsBx, b_gh, b_gih, gh0F, giF);
  const int pre = fuse ? 2 : FTS;
  float* gcur = gh0F;
  float* gnxt = gh1F;
  for (int t = 0; t < pre; t++) {
    k_gru_mfma<<<dim3(128, 4), 256, 0, stream>>>(gcur, wsBg, b_ghh, giF, W_proj,
                                                 des + (size_t)t * N_ * 2, gnxt);
    float* tmp = gcur; gcur = gnxt; gnxt = tmp;
  }

  // main rollout (gru step t+2 fused into edge dispatch when enabled)
  k_init_hc<<<N_, 256, 0, stream>>>(x_last, x_st_last, W_h0, b_h0, W_c0, b_c0,
                                    hA, cbuf, prev, prev_st);
  float* hcur = hA;
  float* hnxt = hB;
  for (int t = 0; t < FTS; t++) {
    const float* des_t = des + (size_t)t * N_ * 2;
    const float* des_n = des + (size_t)((t + 1 < FTS) ? t + 1 : FTS - 1) * N_ * 2;
    const float* des_p = (t > 0) ? des + (size_t)(t - 1) * N_ * 2 : nullptr;
    const int gs = t + 2;
    const int gru_on = (fuse && gs < FTS) ? 1 : 0;
    const float* gin = (gs & 1) ? gh1F : gh0F;
    float* gout      = (gs & 1) ? gh0F : gh1F;
    float* des_g = des + (size_t)((gs < FTS) ? gs : 0) * N_ * 2;
    k_edge_gru<<<2560, 256, 0, stream>>>(prev, prev_st, x_st_last, szf, rad,
                                         nobs, e1, e2, W_e1, b_e1, wsBe, b_e2,
                                         wattT, W_att2, v_att,
                                         des_p, des_t, des_n,
                                         rel, nwp, nwp2, ctx, ss + t, ss + 12,
                                         gin, wsBg, b_ghh, giF, W_proj, des_g, gout, gru_on);
    k_lstm_mfma<<<dim3(128, 8), 256, 0, stream>>>(ctx, hcur, wsBl, b_lih, b_lhh,
                                                  cbuf, hnxt);
    k_action_mfma<<<256, 256, 0, stream>>>(hnxt, z, rel, nwp, nwp2,
                                           wsBa, b_a1, W_a2, b_a2,
                                           prev, prev_st,
                                           out + (size_t)t * N_ * 4,
                                           out + (size_t)FTS * N_ * 4 + (size_t)t * N_ * 2);
    float* tmp = hcur; hcur = hnxt; hnxt = tmp;
  }
  k_final<<<1, 64, 0, stream>>>(ss, out);
}

// Round 9
// 1846.333 us; speedup vs baseline: 2.0671x; 1.3209x over previous
//
#include <hip/hip_runtime.h>

#define DEVI __device__ __forceinline__

constexpr int N_  = 8192;
constexpr int K_  = 15;
constexpr int E_  = N_ * K_;     // 122880
constexpr int FTS = 12;
constexpr float DT_ = 0.25f;

typedef __attribute__((ext_vector_type(8))) short short8x;
typedef __attribute__((ext_vector_type(4))) float float4x;

union U8 { unsigned int u[4]; short8x v; };

DEVI float sigf(float x) { return 1.0f / (1.0f + __expf(-x)); }
DEVI float tanhf_fast(float x) { float e = __expf(2.f * x); return 1.f - 2.f / (e + 1.f); }
DEVI unsigned int f2u(float x) { union { float f; unsigned int u; } c; c.f = x; return c.u; }
DEVI float u2f(unsigned int x) { union { unsigned int u; float f; } c; c.u = x; return c.f; }

DEVI void split8(const float* __restrict__ s, short8x& hi8, short8x& lo8) {
  U8 ph, pl;
#pragma unroll
  for (int p = 0; p < 4; p++) {
    float a0 = s[2*p], a1 = s[2*p+1];
    unsigned int u0 = f2u(a0), u1 = f2u(a1);
    unsigned int h0 = u0 & 0xFFFF0000u, h1 = u1 & 0xFFFF0000u;
    ph.u[p] = (u0 >> 16) | h1;
    float l0 = a0 - u2f(h0), l1 = a1 - u2f(h1);
    pl.u[p] = (f2u(l0) >> 16) | (f2u(l1) & 0xFFFF0000u);
  }
  hi8 = ph.v; lo8 = pl.v;
}

// ---------------------------------------------------------------- zero accum
__global__ void k_zero(float* ss) {
  if (threadIdx.x < 13) ss[threadIdx.x] = 0.f;
}

// ---------------------------------------------------------------- init des to b_proj
__global__ __launch_bounds__(256) void k_init_des(const float* __restrict__ b_proj,
                                                  float* __restrict__ des) {
  int i = blockIdx.x * 256 + threadIdx.x;
  des[i*2]     = b_proj[0];
  des[i*2 + 1] = b_proj[1];
}

// ---------------------------------------------------------------- edge static
__global__ __launch_bounds__(256) void k_edge_static(
    const int* __restrict__ e1, const int* __restrict__ e2,
    const float* __restrict__ nsize, float* __restrict__ rad, float* __restrict__ szf)
{
  int e = blockIdx.x * 256 + threadIdx.x;
  if (e >= E_) return;
  int i1 = e1[e], i2 = e2[e];
  float s1x = nsize[i1*2+0], s1y = nsize[i1*2+1];
  float s2x = nsize[i2*2+0], s2y = nsize[i2*2+1];
  rad[e] = 0.5f * (sqrtf(s1x*s1x + s1y*s1y) + sqrtf(s2x*s2x + s2y*s2y));
  *(float4*)&szf[e*4] = make_float4(s1x, s1y, s2x, s2y);
}

// ---------------------------------------------------------------- transpose W_att1 -> [a][chan]
__global__ __launch_bounds__(256) void k_prep_attT(const float* __restrict__ W_att1,
                                                   float* __restrict__ wT) {
  int i = blockIdx.x * 256 + threadIdx.x;
  int chan = i >> 4, a = i & 15;
  wT[a * 128 + chan] = W_att1[i];
}

// ---------------------------------------------------------------- hi-only bf16 B-fragments for edge W_e2
__global__ __launch_bounds__(256) void k_prep_hi(
    const float* __restrict__ W, unsigned short* __restrict__ out)
{
  int t = blockIdx.x * 256 + threadIdx.x;   // < 4096
  int fid = t >> 6, L = t & 63;
  int ks = fid >> 3, nt = fid & 7;
  int k0 = ks * 32 + (L >> 4) * 8;
  int n  = nt * 16 + (L & 15);
  unsigned int hi[4];
#pragma unroll
  for (int p = 0; p < 4; p++) {
    float w0 = W[(size_t)(k0 + 2*p) * 128 + n];
    float w1 = W[(size_t)(k0 + 2*p + 1) * 128 + n];
    hi[p] = (f2u(w0) >> 16) | (f2u(w1) & 0xFFFF0000u);
  }
  *(uint4*)(out + (size_t)fid * 512 + (size_t)L * 8) = make_uint4(hi[0], hi[1], hi[2], hi[3]);
}

// ---------------------------------------------------------------- generic hi-only bf16 B-fragment prep
// frag fid = ks*NT + nt; lane L: k0=32ks+(L>>4)*8, n=16nt+(L&15); out[fid*512 + L*8]
__global__ __launch_bounds__(256) void k_prep1(
    const float* __restrict__ WA, const float* __restrict__ WB,
    int mode, int split, int wA, int wB, int Ktot, int NT, int nfrag,
    unsigned short* __restrict__ out)
{
  int t = blockIdx.x * 256 + threadIdx.x;
  int fid = t >> 6, L = t & 63;
  if (fid >= nfrag) return;
  int ks = fid / NT, nt = fid % NT;
  int k0 = ks * 32 + (L >> 4) * 8;
  int n  = nt * 16 + (L & 15);
  unsigned int hi[4];
#pragma unroll
  for (int p = 0; p < 4; p++) {
    float w0 = 0.f, w1 = 0.f;
    int ka = k0 + 2*p, kb = ka + 1;
    if (mode == 0) {
      if (ka < Ktot) w0 = (ka < split) ? WA[(size_t)ka*wA + n] : WB[(size_t)(ka-split)*wB + n];
      if (kb < Ktot) w1 = (kb < split) ? WA[(size_t)kb*wA + n] : WB[(size_t)(kb-split)*wB + n];
    } else {
      if (ka < Ktot) w0 = (n < split) ? WA[(size_t)ka*wA + n] : WB[(size_t)ka*wB + (n-split)];
      if (kb < Ktot) w1 = (n < split) ? WA[(size_t)kb*wA + n] : WB[(size_t)kb*wB + (n-split)];
    }
    hi[p] = (f2u(w0) >> 16) | (f2u(w1) & 0xFFFF0000u);
  }
  *(uint4*)(out + (size_t)fid * 512 + (size_t)L * 8) = make_uint4(hi[0], hi[1], hi[2], hi[3]);
}

// ---------------------------------------------------------------- xz GEMM (once), B hi-only
__global__ __launch_bounds__(256) void k_xz_mfma(
    const float* __restrict__ hist, const float* __restrict__ z,
    const unsigned short* __restrict__ wB,
    const float* __restrict__ b_gh, const float* __restrict__ b_gih,
    float* __restrict__ gh0, float* __restrict__ gi)
{
  __shared__ __align__(16) float Abuf[64][36];
  const int tid = threadIdx.x;
  const int w = tid >> 6, lane = tid & 63;
  const int m = lane & 15, q = lane >> 4;
  const int n0 = blockIdx.x * 64;
  const int r_ = tid >> 2, c_ = (tid & 3) * 8;
  float4x acc[16];
#pragma unroll
  for (int tl = 0; tl < 16; tl++) acc[tl] = (float4x){0.f,0.f,0.f,0.f};

  for (int ks = 0; ks < 9; ks++) {
    __syncthreads();
    {
      int kk = ks*32 + c_;
      int n = n0 + r_;
      float4 v0, v1;
      if (kk < 256) {
        v0 = *(const float4*)&hist[(size_t)n*256 + kk];
        v1 = *(const float4*)&hist[(size_t)n*256 + kk + 4];
      } else if (kk == 256) {
        v0 = *(const float4*)&z[n*8];
        v1 = *(const float4*)&z[n*8 + 4];
      } else {
        v0 = make_float4(0,0,0,0); v1 = v0;
      }
      *(float4*)&Abuf[r_][c_]     = v0;
      *(float4*)&Abuf[r_][c_ + 4] = v1;
    }
    __syncthreads();
    short8x aHi, aLo;
    split8(&Abuf[w*16 + m][q*8], aHi, aLo);
#pragma unroll
    for (int tl = 0; tl < 16; tl++) {
      int nt = blockIdx.y*16 + tl;
      size_t off = (size_t)(ks*64 + nt) * 512 + (size_t)lane*8;
      short8x bh = *(const short8x*)(wB + off);
      acc[tl] = __builtin_amdgcn_mfma_f32_16x16x32_bf16(aLo, bh, acc[tl], 0, 0, 0);
      acc[tl] = __builtin_amdgcn_mfma_f32_16x16x32_bf16(aHi, bh, acc[tl], 0, 0, 0);
    }
  }
#pragma unroll
  for (int tl = 0; tl < 16; tl++) {
    int col = (blockIdx.y*16 + tl)*16 + m;
    float bias = (col < 256) ? b_gh[col] : b_gih[col - 256];
#pragma unroll
    for (int i = 0; i < 4; i++) {
      int n = n0 + w*16 + q*4 + i;
      float v = acc[tl][i] + bias;
      if (col < 256) gh0[(size_t)n*256 + col] = v;
      else           gi[(size_t)n*768 + col - 256] = v;
    }
  }
}

// ---------------------------------------------------------------- GRU core (shared), B hi-only
DEVI void gru_core(float (*Abuf)[36], int tid, int n0, int j0,
                   const float* __restrict__ h_in, const unsigned short* __restrict__ wB,
                   const float* __restrict__ b_hh, const float* __restrict__ gi,
                   const float* __restrict__ W_proj, float* __restrict__ des_t,
                   float* __restrict__ h_out)
{
  const int w = tid >> 6, lane = tid & 63;
  const int m = lane & 15, q = lane >> 4;
  const int r_ = tid >> 2, c_ = (tid & 3) * 8;
  float4x acc[12];
#pragma unroll
  for (int tl = 0; tl < 12; tl++) acc[tl] = (float4x){0.f,0.f,0.f,0.f};

  for (int ks = 0; ks < 8; ks++) {
    __syncthreads();
    {
      int kk = ks*32 + c_;
      int n = n0 + r_;
      *(float4*)&Abuf[r_][c_]     = *(const float4*)&h_in[(size_t)n*256 + kk];
      *(float4*)&Abuf[r_][c_ + 4] = *(const float4*)&h_in[(size_t)n*256 + kk + 4];
    }
    __syncthreads();
    short8x aHi, aLo;
    split8(&Abuf[w*16 + m][q*8], aHi, aLo);
#pragma unroll
    for (int tl = 0; tl < 12; tl++) {
      int g = tl >> 2, jt = tl & 3;
      int nt = g*16 + (j0 >> 4) + jt;
      size_t off = (size_t)(ks*48 + nt) * 512 + (size_t)lane*8;
      short8x bh = *(const short8x*)(wB + off);
      acc[tl] = __builtin_amdgcn_mfma_f32_16x16x32_bf16(aLo, bh, acc[tl], 0, 0, 0);
      acc[tl] = __builtin_amdgcn_mfma_f32_16x16x32_bf16(aHi, bh, acc[tl], 0, 0, 0);
    }
  }
  float pd0[4] = {0,0,0,0}, pd1[4] = {0,0,0,0};
#pragma unroll
  for (int jt = 0; jt < 4; jt++) {
    int j = j0 + jt*16 + m;
    float br = b_hh[j], bz = b_hh[256 + j], bn = b_hh[512 + j];
    float wp0 = W_proj[j*2], wp1 = W_proj[j*2 + 1];
#pragma unroll
    for (int i = 0; i < 4; i++) {
      int n = n0 + w*16 + q*4 + i;
      float ir  = gi[(size_t)n*768 + j];
      float iz  = gi[(size_t)n*768 + 256 + j];
      float inn = gi[(size_t)n*768 + 512 + j];
      float hold = h_in[(size_t)n*256 + j];
      float r = sigf(ir + acc[0*4 + jt][i] + br);
      float u = sigf(iz + acc[1*4 + jt][i] + bz);
      float nh = (1.f - u) * tanhf_fast(inn + r * (acc[2*4 + jt][i] + bn)) + u * hold;
      h_out[(size_t)n*256 + j] = nh;
      pd0[i] += nh * wp0;
      pd1[i] += nh * wp1;
    }
  }
#pragma unroll
  for (int off = 1; off < 16; off <<= 1) {
#pragma unroll
    for (int i = 0; i < 4; i++) {
      pd0[i] += __shfl_xor(pd0[i], off);
      pd1[i] += __shfl_xor(pd1[i], off);
    }
  }
  if (m == 0) {
#pragma unroll
    for (int i = 0; i < 4; i++) {
      int n = n0 + w*16 + q*4 + i;
      atomicAdd(&des_t[n*2],     pd0[i]);
      atomicAdd(&des_t[n*2 + 1], pd1[i]);
    }
  }
}

// ---------------------------------------------------------------- standalone GRU step (prologue)
__global__ __launch_bounds__(256) void k_gru_mfma(
    const float* __restrict__ h_in, const unsigned short* __restrict__ wB,
    const float* __restrict__ b_hh, const float* __restrict__ gi,
    const float* __restrict__ W_proj, float* __restrict__ des_t,
    float* __restrict__ h_out)
{
  __shared__ __align__(16) float Abuf[64][36];
  gru_core(Abuf, threadIdx.x, blockIdx.x * 64, blockIdx.y * 64,
           h_in, wB, b_hh, gi, W_proj, des_t, h_out);
}

// ---------------------------------------------------------------- LSTM cell (MFMA), j-tile = 32, B hi-only
__global__ __launch_bounds__(256) void k_lstm_mfma(
    const float* __restrict__ ctxg, const float* __restrict__ h_in,
    const unsigned short* __restrict__ wB,
    const float* __restrict__ b_ih, const float* __restrict__ b_hh,
    float* __restrict__ c_st, float* __restrict__ h_out)
{
  __shared__ __align__(16) float Abuf[64][36];
  const int tid = threadIdx.x;
  const int w = tid >> 6, lane = tid & 63;
  const int m = lane & 15, q = lane >> 4;
  const int n0 = blockIdx.x * 64;
  const int j0 = blockIdx.y * 32;
  const int r_ = tid >> 2, c_ = (tid & 3) * 8;
  float4x acc[8];
#pragma unroll
  for (int tl = 0; tl < 8; tl++) acc[tl] = (float4x){0.f,0.f,0.f,0.f};

  for (int ks = 0; ks < 12; ks++) {
    __syncthreads();
    {
      int kk = ks*32 + c_;
      int n = n0 + r_;
      float4 v0, v1;
      if (kk < 128) {
        v0 = *(const float4*)&ctxg[(size_t)n*128 + kk];
        v1 = *(const float4*)&ctxg[(size_t)n*128 + kk + 4];
      } else {
        v0 = *(const float4*)&h_in[(size_t)n*256 + kk - 128];
        v1 = *(const float4*)&h_in[(size_t)n*256 + kk - 124];
      }
      *(float4*)&Abuf[r_][c_]     = v0;
      *(float4*)&Abuf[r_][c_ + 4] = v1;
    }
    __syncthreads();
    short8x aHi, aLo;
    split8(&Abuf[w*16 + m][q*8], aHi, aLo);
#pragma unroll
    for (int tl = 0; tl < 8; tl++) {
      int g = tl >> 1, jt = tl & 1;
      int nt = g*16 + (j0 >> 4) + jt;
      size_t off = (size_t)(ks*64 + nt) * 512 + (size_t)lane*8;
      short8x bh = *(const short8x*)(wB + off);
      acc[tl] = __builtin_amdgcn_mfma_f32_16x16x32_bf16(aLo, bh, acc[tl], 0, 0, 0);
      acc[tl] = __builtin_amdgcn_mfma_f32_16x16x32_bf16(aHi, bh, acc[tl], 0, 0, 0);
    }
  }
#pragma unroll
  for (int jt = 0; jt < 2; jt++) {
    int j = j0 + jt*16 + m;
    float bi = b_ih[j]       + b_hh[j];
    float bf = b_ih[256 + j] + b_hh[256 + j];
    float bg = b_ih[512 + j] + b_hh[512 + j];
    float bo = b_ih[768 + j] + b_hh[768 + j];
#pragma unroll
    for (int i = 0; i < 4; i++) {
      int n = n0 + w*16 + q*4 + i;
      float g_i = sigf(acc[0*2 + jt][i] + bi);
      float g_f = sigf(acc[1*2 + jt][i] + bf);
      float g_g = tanhf_fast(acc[2*2 + jt][i] + bg);
      float g_o = sigf(acc[3*2 + jt][i] + bo);
      float cv = g_f * c_st[(size_t)n*256 + j] + g_i * g_g;
      c_st[(size_t)n*256 + j] = cv;
      h_out[(size_t)n*256 + j] = g_o * tanhf_fast(cv);
    }
  }
}

// ---------------------------------------------------------------- action MLP: 32 nodes/block, B hi-only
__global__ __launch_bounds__(256) void k_action_mfma(
    const float* __restrict__ h, const float* __restrict__ z,
    const float* __restrict__ rel, const float* __restrict__ nwp, const float* __restrict__ nwp2,
    const unsigned short* __restrict__ wB, const float* __restrict__ b_a1,
    const float* __restrict__ W_a2, const float* __restrict__ b_a2,
    float* __restrict__ prev, float* __restrict__ prev_st,
    float* __restrict__ outS, float* __restrict__ outU)
{
  __shared__ __align__(16) float Abuf[32][36];
  __shared__ float sm_p[2][16][2];
  const int tid = threadIdx.x;
  const int w = tid >> 6, lane = tid & 63;
  const int m = lane & 15, q = lane >> 4;
  const int ng = w >> 1, hh = w & 1;
  const int n0 = blockIdx.x * 32;
  const int r_ = tid >> 3, c_ = (tid & 7) * 4;
  float4x acc[8];
#pragma unroll
  for (int j = 0; j < 8; j++) acc[j] = (float4x){0.f,0.f,0.f,0.f};

  for (int ks = 0; ks < 9; ks++) {
    __syncthreads();
    {
      int kk = ks*32 + c_;
      int n = n0 + r_;
      float4 v;
      if (kk < 256)      v = *(const float4*)&h[(size_t)n*256 + kk];
      else if (kk == 256) v = *(const float4*)&z[n*8];
      else if (kk == 260) v = *(const float4*)&z[n*8 + 4];
      else if (kk == 264) v = *(const float4*)&rel[n*4];
      else if (kk == 268) {
        float2 w1 = *(const float2*)&nwp[n*2];
        float2 w2 = *(const float2*)&nwp2[n*2];
        v = make_float4(w1.x, w1.y, w2.x, w2.y);
      } else v = make_float4(0,0,0,0);
      *(float4*)&Abuf[r_][c_] = v;
    }
    __syncthreads();
    short8x aHi, aLo;
    split8(&Abuf[ng*16 + m][q*8], aHi, aLo);
#pragma unroll
    for (int j = 0; j < 8; j++) {
      int tl = hh*8 + j;
      size_t off = (size_t)(ks*16 + tl) * 512 + (size_t)lane*8;
      short8x bh = *(const short8x*)(wB + off);
      acc[j] = __builtin_amdgcn_mfma_f32_16x16x32_bf16(aLo, bh, acc[j], 0, 0, 0);
      acc[j] = __builtin_amdgcn_mfma_f32_16x16x32_bf16(aHi, bh, acc[j], 0, 0, 0);
    }
  }
  float p0[4] = {0,0,0,0}, p1[4] = {0,0,0,0};
#pragma unroll
  for (int j = 0; j < 8; j++) {
    int col = (hh*8 + j)*16 + m;
    float ba = b_a1[col];
    float2 w2 = *(const float2*)&W_a2[col*2];
#pragma unroll
    for (int i = 0; i < 4; i++) {
      float hv = fmaxf(acc[j][i] + ba, 0.f);
      p0[i] += hv * w2.x;
      p1[i] += hv * w2.y;
    }
  }
#pragma unroll
  for (int off = 1; off < 16; off <<= 1) {
#pragma unroll
    for (int i = 0; i < 4; i++) {
      p0[i] += __shfl_xor(p0[i], off);
      p1[i] += __shfl_xor(p1[i], off);
    }
  }
  if (hh == 1 && m == 0) {
#pragma unroll
    for (int i = 0; i < 4; i++) {
      sm_p[ng][q*4 + i][0] = p0[i];
      sm_p[ng][q*4 + i][1] = p1[i];
    }
  }
  __syncthreads();
  if (hh == 0 && m == 0) {
    float ba0 = b_a2[0], ba1 = b_a2[1];
    const float hd = 0.5f * DT_ * DT_;
#pragma unroll
    for (int i = 0; i < 4; i++) {
      int n = n0 + ng*16 + q*4 + i;
      float ux = tanhf_fast(p0[i] + sm_p[ng][q*4 + i][0] + ba0);
      float uy = tanhf_fast(p1[i] + sm_p[ng][q*4 + i][1] + ba1);
      float4 pv = *(const float4*)&prev[n*4];
      float4 ps = *(const float4*)&prev_st[n*4];
      float4 npv, nps;
      npv.x = pv.x + pv.z*DT_ + ux*hd;
      npv.y = pv.y + pv.w*DT_ + uy*hd;
      npv.z = pv.z + ux*DT_;
      npv.w = pv.w + uy*DT_;
      nps.x = ps.x + ps.z*DT_ + ux*hd;
      nps.y = ps.y + ps.w*DT_ + uy*hd;
      nps.z = ps.z + ux*DT_;
      nps.w = ps.w + uy*DT_;
      *(float4*)&prev[n*4] = npv;
      *(float4*)&prev_st[n*4] = nps;
      *(float4*)&outS[(size_t)n*4] = npv;
      outU[n*2]     = ux;
      outU[n*2 + 1] = uy;
    }
  }
}

// ---------------------------------------------------------------- LSTM h0/c0 + prev copies
__global__ __launch_bounds__(256) void k_init_hc(
    const float* __restrict__ x_last, const float* __restrict__ x_st_last,
    const float* __restrict__ W_h0, const float* __restrict__ b_h0,
    const float* __restrict__ W_c0, const float* __restrict__ b_c0,
    float* __restrict__ h, float* __restrict__ c,
    float* __restrict__ prev, float* __restrict__ prev_st)
{
  const int n = blockIdx.x;
  const int j = threadIdx.x;
  float x0 = x_st_last[n*4], x1 = x_st_last[n*4+1], x2 = x_st_last[n*4+2], x3 = x_st_last[n*4+3];
  h[(size_t)n*256 + j] = b_h0[j] + x0*W_h0[j] + x1*W_h0[256+j] + x2*W_h0[512+j] + x3*W_h0[768+j];
  c[(size_t)n*256 + j] = b_c0[j] + x0*W_c0[j] + x1*W_c0[256+j] + x2*W_c0[512+j] + x3*W_c0[768+j];
  if (j < 4) prev[n*4 + j] = x_last[n*4 + j];
  else if (j < 8) prev_st[n*4 + (j-4)] = x_st_last[n*4 + (j-4)];
}

// ---------------------------------------------------------------- FUSED: edge (blocks 0..2047, 4 nodes) | GRU (blocks 2048..2559)
// (256,4): proven no-spill. B hi-only, A split hi/lo, dbuf 8KB staging, 1 barrier/ks.
__global__ __launch_bounds__(256, 4) void k_edge_gru(
    const float* __restrict__ prev, const float* __restrict__ prev_st,
    const float* __restrict__ x_st_last,
    const float* __restrict__ szf, const float* __restrict__ rad,
    const int* __restrict__ nobs, const int* __restrict__ e1, const int* __restrict__ e2,
    const float* __restrict__ W_e1, const float* __restrict__ b_e1,
    const unsigned short* __restrict__ wsB, const float* __restrict__ b_e2,
    const float* __restrict__ wattT, const float* __restrict__ W_att2,
    const float* __restrict__ v_att,
    const float* __restrict__ des_p, const float* __restrict__ des_t,
    const float* __restrict__ des_n,
    float* __restrict__ relg, float* __restrict__ nwp, float* __restrict__ nwp2,
    float* __restrict__ ctx, float* __restrict__ ss_t, float* __restrict__ cc,
    const float* __restrict__ g_hin, const unsigned short* __restrict__ wBg,
    const float* __restrict__ b_ghh, const float* __restrict__ gi,
    const float* __restrict__ W_proj, float* __restrict__ des_g,
    float* __restrict__ g_hout, int gru_on)
{
  __shared__ __align__(16) float smem[6824];
  const int tid = threadIdx.x;

  if (blockIdx.x >= 2048) {
    if (!gru_on) return;
    int b = blockIdx.x - 2048;
    gru_core((float(*)[36])smem, tid, (b & 127) * 64, (b >> 7) * 64,
             g_hin, wBg, b_ghh, gi, W_proj, des_g, g_hout);
    return;
  }

  float* sm_stage = smem;
  float* sm_feats = smem + 4096;
  float* sm_flags = smem + 4608;
  float* sm_relv  = smem + 4672;
  float* sm_w1T   = smem + 4688;
  float* sm_watt2 = smem + 6736;
  float* sm_vatt  = smem + 6800;
  float* sm_red   = smem + 6816;

  const int n0  = blockIdx.x * 4;
  const int lane = tid & 63;
  const int g    = tid >> 6;
  const int q = lane >> 4, m = lane & 15;

  // ---- P0
  for (int i = tid; i < 2048; i += 256) sm_w1T[i] = wattT[i];
  if (tid >= 176 && tid < 192) sm_vatt[tid - 176] = v_att[tid - 176];
  if (tid >= 192) sm_watt2[tid - 192] = W_att2[tid - 192];

  if (tid < 64) {
    float v = 0.f;
    if (tid < 60) {
      int gg = tid / 15, k = tid % 15;
      int idx = nobs[(n0 + gg) * 15 + k];
      float f[8] = {0,0,0,0,0,0,0,0};
      float fl = 0.f;
      if (idx > 0) {
        int e = idx - 1;
        int i1 = e1[e], i2 = e2[e];
#pragma unroll
        for (int d = 0; d < 4; d++) f[d] = prev[i2*4 + d] - prev[i1*4 + d];
        float4 sz = *(const float4*)&szf[(size_t)e*4];
        f[4] = sz.x; f[5] = sz.y; f[6] = sz.z; f[7] = sz.w;
        fl = 1.f;
        float dist = sqrtf(f[0]*f[0] + f[1]*f[1]);
        v = fmaxf(rad[e] - dist, 0.f);
      }
#pragma unroll
      for (int d = 0; d < 8; d++) sm_feats[(gg*16 + k)*8 + d] = f[d];
      sm_flags[gg*16 + k] = fl;
    } else {
      int gg = tid - 60;
#pragma unroll
      for (int d = 0; d < 8; d++) sm_feats[(gg*16 + 15)*8 + d] = 0.f;
      sm_flags[gg*16 + 15] = 0.f;
    }
#pragma unroll
    for (int off = 32; off; off >>= 1) v += __shfl_down(v, off);
    if (tid == 0) atomicAdd(cc, v);
  } else if (tid < 68) {
    int gg = tid - 64;
    int n = n0 + gg;
    float4 ps = *(const float4*)&prev_st[n*4];
    float r0, r1, r2, r3;
    if (des_p) {
      float4 xs = *(const float4*)&x_st_last[n*4];
      r0 = ps.x - xs.x - des_p[n*2];
      r1 = ps.y - xs.y - des_p[n*2 + 1];
      r2 = ps.z - xs.z;
      r3 = ps.w - xs.w;
    } else { r0 = ps.x; r1 = ps.y; r2 = ps.z; r3 = ps.w; }
    sm_relv[gg*4+0] = r0; sm_relv[gg*4+1] = r1; sm_relv[gg*4+2] = r2; sm_relv[gg*4+3] = r3;
    *(float4*)&relg[n*4] = make_float4(r0, r1, r2, r3);
    nwp[n*2]      = des_t[n*2]     - ps.x;
    nwp[n*2 + 1]  = des_t[n*2 + 1] - ps.y;
    nwp2[n*2]     = des_n[n*2]     - ps.x;
    nwp2[n*2 + 1] = des_n[n*2 + 1] - ps.y;
    sm_red[gg] = r0*r0 + r1*r1;
  }
  // initial stage of ks=0 (hi-only, 8KB) into buf0
  {
    const uint4* src = (const uint4*)wsB;
    uint4* dst = (uint4*)sm_stage;
    dst[tid]       = src[tid];
    dst[tid + 256] = src[tid + 256];
  }
  __syncthreads();
  if (tid == 64) atomicAdd(ss_t, sm_red[0] + sm_red[1] + sm_red[2] + sm_red[3]);

  // ---- P1+P2 pipelined over ks
  float f[8];
  {
    const float4 fa = *(const float4*)&sm_feats[(g*16 + m)*8];
    const float4 fb = *(const float4*)&sm_feats[(g*16 + m)*8 + 4];
    f[0]=fa.x; f[1]=fa.y; f[2]=fa.z; f[3]=fa.w; f[4]=fb.x; f[5]=fb.y; f[6]=fb.z; f[7]=fb.w;
  }
  float4x encR[8];
#pragma unroll
  for (int nt = 0; nt < 8; nt++) encR[nt] = (float4x){0.f,0.f,0.f,0.f};
  const float4* We14 = (const float4*)W_e1;
  const float4* Be14 = (const float4*)b_e1;

  for (int ks = 0; ks < 8; ks++) {
    uint4 r0, r1;
    if (ks < 7) {
      const uint4* src = (const uint4*)wsB + (ks + 1) * 512;
      r0 = src[tid];
      r1 = src[tid + 256];
    }
    short8x aHi, aLo;
    {
      float h8[8];
      float4 b0 = Be14[8*ks + 2*q];
      float4 b1 = Be14[8*ks + 2*q + 1];
      h8[0]=b0.x; h8[1]=b0.y; h8[2]=b0.z; h8[3]=b0.w; h8[4]=b1.x; h8[5]=b1.y; h8[6]=b1.z; h8[7]=b1.w;
#pragma unroll
      for (int d = 0; d < 8; d++) {
        float4 wa = We14[d*64 + ks*8 + 2*q];
        float4 wb = We14[d*64 + ks*8 + 2*q + 1];
        h8[0] += f[d]*wa.x; h8[1] += f[d]*wa.y; h8[2] += f[d]*wa.z; h8[3] += f[d]*wa.w;
        h8[4] += f[d]*wb.x; h8[5] += f[d]*wb.y; h8[6] += f[d]*wb.z; h8[7] += f[d]*wb.w;
      }
#pragma unroll
      for (int p = 0; p < 8; p++) h8[p] = fmaxf(h8[p], 0.f);
      split8(h8, aHi, aLo);
    }
    const unsigned short* sb = (const unsigned short*)sm_stage + (ks & 1) * 4096;
#pragma unroll
    for (int nt = 0; nt < 8; nt++) {
      short8x bh = *(const short8x*)(sb + nt*512 + lane*8);
      encR[nt] = __builtin_amdgcn_mfma_f32_16x16x32_bf16(aLo, bh, encR[nt], 0, 0, 0);
      encR[nt] = __builtin_amdgcn_mfma_f32_16x16x32_bf16(aHi, bh, encR[nt], 0, 0, 0);
    }
    if (ks < 7) {
      uint4* dst = (uint4*)sm_stage + ((ks + 1) & 1) * 512;
      dst[tid]       = r0;
      dst[tid + 256] = r1;
      __syncthreads();
    }
  }
  float4x fl4 = *(const float4x*)&sm_flags[g*16 + q*4];
#pragma unroll
  for (int nt = 0; nt < 8; nt++) {
    float b2 = b_e2[nt*16 + m];
#pragma unroll
    for (int i = 0; i < 4; i++) encR[nt][i] = (encR[nt][i] + b2) * fl4[i];
  }

  // ---- P3: score partials
  float4x part[16];
#pragma unroll
  for (int a = 0; a < 16; a++) part[a] = (float4x){0.f,0.f,0.f,0.f};
#pragma unroll
  for (int a = 0; a < 16; a++) {
#pragma unroll
    for (int nt = 0; nt < 8; nt++) {
      float wv = sm_w1T[a*128 + nt*16 + m];
      part[a] = part[a] + encR[nt] * wv;
    }
  }

  // ---- P4: halving-exchange over m
  const bool s8 = (m & 8) != 0, s4b = (m & 4) != 0, s2b = (m & 2) != 0, s1b = (m & 1) != 0;
  float4x c8[8];
#pragma unroll
  for (int a = 0; a < 8; a++) {
    float4x mi, sd, rc;
#pragma unroll
    for (int e = 0; e < 4; e++) {
      mi[e] = s8 ? part[a+8][e] : part[a][e];
      sd[e] = s8 ? part[a][e] : part[a+8][e];
      rc[e] = __shfl_xor(sd[e], 8);
    }
    c8[a] = mi + rc;
  }
  float4x c4[4];
#pragma unroll
  for (int a = 0; a < 4; a++) {
    float4x mi, sd, rc;
#pragma unroll
    for (int e = 0; e < 4; e++) {
      mi[e] = s4b ? c8[a+4][e] : c8[a][e];
      sd[e] = s4b ? c8[a][e] : c8[a+4][e];
      rc[e] = __shfl_xor(sd[e], 4);
    }
    c4[a] = mi + rc;
  }
  float4x c2[2];
#pragma unroll
  for (int a = 0; a < 2; a++) {
    float4x mi, sd, rc;
#pragma unroll
    for (int e = 0; e < 4; e++) {
      mi[e] = s2b ? c4[a+2][e] : c4[a][e];
      sd[e] = s2b ? c4[a][e] : c4[a+2][e];
      rc[e] = __shfl_xor(sd[e], 2);
    }
    c2[a] = mi + rc;
  }
  float4x c1;
  {
    float4x mi, sd, rc;
#pragma unroll
    for (int e = 0; e < 4; e++) {
      mi[e] = s1b ? c2[1][e] : c2[0][e];
      sd[e] = s1b ? c2[0][e] : c2[1][e];
      rc[e] = __shfl_xor(sd[e], 1);
    }
    c1 = mi + rc;
  }

  // ---- P5: softmax + ctx
  float relw;
  {
    float4 rv = *(const float4*)&sm_relv[g*4];
    relw = rv.x * sm_watt2[m] + rv.y * sm_watt2[16 + m]
         + rv.z * sm_watt2[32 + m] + rv.w * sm_watt2[48 + m];
  }
  float vat = sm_vatt[m];
  float val[4];
#pragma unroll
  for (int i = 0; i < 4; i++) val[i] = tanhf_fast(c1[i] + relw) * vat;
#pragma unroll
  for (int msk = 1; msk < 16; msk <<= 1) {
#pragma unroll
    for (int i = 0; i < 4; i++) val[i] += __shfl_xor(val[i], msk);
  }
  if (q == 3) val[3] = -3.0e38f;
  float mx = fmaxf(fmaxf(val[0], val[1]), fmaxf(val[2], val[3]));
  mx = fmaxf(mx, __shfl_xor(mx, 16));
  mx = fmaxf(mx, __shfl_xor(mx, 32));
  float4x ev;
  float ssum = 0.f;
#pragma unroll
  for (int i = 0; i < 4; i++) { ev[i] = __expf(val[i] - mx); ssum += ev[i]; }
  ssum += __shfl_xor(ssum, 16);
  ssum += __shfl_xor(ssum, 32);
  float inv = 1.f / ssum;
#pragma unroll
  for (int i = 0; i < 4; i++) ev[i] *= inv;

  float cpart[8];
#pragma unroll
  for (int nt = 0; nt < 8; nt++) {
    float cv = ev[0]*encR[nt][0] + ev[1]*encR[nt][1] + ev[2]*encR[nt][2] + ev[3]*encR[nt][3];
    cv += __shfl_xor(cv, 16);
    cv += __shfl_xor(cv, 32);
    cpart[nt] = cv;
  }
  float v0 = (q == 0) ? cpart[0] : (q == 1) ? cpart[2] : (q == 2) ? cpart[4] : cpart[6];
  float v1 = (q == 0) ? cpart[1] : (q == 1) ? cpart[3] : (q == 2) ? cpart[5] : cpart[7];
  size_t cb = (size_t)(n0 + g) * 128 + q*32 + m;
  ctx[cb]      = v0;
  ctx[cb + 16] = v1;
}

// ---------------------------------------------------------------- finalize scalars
__global__ void k_final(const float* __restrict__ ss, float* __restrict__ out) {
  if (threadIdx.x == 0) {
    float t = 0.f;
    for (int i = 0; i < FTS; i++) t += sqrtf(ss[i]);
    out[(size_t)FTS * N_ * 6]     = t / (float)N_;
    out[(size_t)FTS * N_ * 6 + 1] = ss[FTS];
  }
}

// ================================================================ launch
extern "C" void kernel_launch(void* const* d_in, const int* in_sizes, int n_in,
                              void* d_out, int out_size, void* d_ws, size_t ws_size,
                              hipStream_t stream) {
  (void)in_sizes; (void)n_in; (void)out_size;
  const float* x_last    = (const float*)d_in[0];
  const float* x_st_last = (const float*)d_in[1];
  const float* hist_enc  = (const float*)d_in[2];
  const float* z         = (const float*)d_in[3];
  const float* node_size = (const float*)d_in[4];
  const float* W_h0 = (const float*)d_in[5];
  const float* b_h0 = (const float*)d_in[6];
  const float* W_c0 = (const float*)d_in[7];
  const float* b_c0 = (const float*)d_in[8];
  const float* W_gh = (const float*)d_in[9];
  const float* b_gh = (const float*)d_in[10];
  const float* W_gih = (const float*)d_in[11];
  const float* W_ghh = (const float*)d_in[12];
  const float* b_gih = (const float*)d_in[13];
  const float* b_ghh = (const float*)d_in[14];
  const float* W_proj = (const float*)d_in[15];
  const float* b_proj = (const float*)d_in[16];
  const float* W_att1 = (const float*)d_in[17];
  const float* W_att2 = (const float*)d_in[18];
  const float* v_att  = (const float*)d_in[19];
  const float* W_lih = (const float*)d_in[20];
  const float* W_lhh = (const float*)d_in[21];
  const float* b_lih = (const float*)d_in[22];
  const float* b_lhh = (const float*)d_in[23];
  const float* W_e1 = (const float*)d_in[24];
  const float* b_e1 = (const float*)d_in[25];
  const float* W_e2 = (const float*)d_in[26];
  const float* b_e2 = (const float*)d_in[27];
  const float* W_a1 = (const float*)d_in[28];
  const float* b_a1 = (const float*)d_in[29];
  const float* W_a2 = (const float*)d_in[30];
  const float* b_a2 = (const float*)d_in[31];
  const int* e1   = (const int*)d_in[32];
  const int* e2   = (const int*)d_in[33];
  const int* nobs = (const int*)d_in[34];
  float* out = (float*)d_out;

  // workspace carve (floats)
  float* wsf     = (float*)d_ws;
  float* prev    = wsf;
  float* prev_st = wsf + 32768;
  float* des     = wsf + 65536;
  float* ss      = wsf + 262144;
  float* rad     = wsf + 262160;
  float* szf     = wsf + 385040;            // -> end 876560
  float* baseA   = wsf + 876560;            // union region, 5 units of N*256 -> end 11362320
  // serial-phase aliased view
  float* gh0 = baseA;
  float* gh1 = baseA + (size_t)N_ * 256;
  float* gi  = baseA + (size_t)2 * N_ * 256;
  // main phase view
  float* hA   = baseA;
  float* hB   = baseA + (size_t)N_ * 256;
  float* cbuf = baseA + (size_t)2 * N_ * 256;
  float* ctx  = baseA + (size_t)3 * N_ * 256;
  float* rel  = baseA + (size_t)4 * N_ * 256;
  float* nwp  = rel + (size_t)N_ * 4;
  float* nwp2 = nwp + (size_t)N_ * 2;
  // prepped B fragments (hi-only now; buffers shrink in place, offsets unchanged)
  unsigned short* wsBe = (unsigned short*)(wsf + 11362320);
  unsigned short* wsBg = (unsigned short*)(wsf + 11427856);
  unsigned short* wsBl = (unsigned short*)(wsf + 11624464);
  unsigned short* wsBx = (unsigned short*)(wsf + 12017680);
  unsigned short* wsBa = (unsigned short*)(wsf + 12312592);
  float* wattT = wsf + 12386320;                              // -> end 12388368
  // fused-path GRU buffers (disjoint from main-phase aliases)
  float* ext = wsf + 12388368;
  const size_t needF = 12388368ull + 5ull * N_ * 256ull;
  const bool fuse = ws_size >= needF * 4ull;
  float* gh0F = fuse ? ext : gh0;
  float* gh1F = fuse ? (ext + (size_t)N_ * 256) : gh1;
  float* giF  = fuse ? (ext + (size_t)2 * N_ * 256) : gi;

  k_zero<<<1, 64, 0, stream>>>(ss);
  k_edge_static<<<(E_ + 255) / 256, 256, 0, stream>>>(e1, e2, node_size, rad, szf);
  k_init_des<<<FTS * N_ / 256, 256, 0, stream>>>(b_proj, des);
  k_prep_attT<<<8, 256, 0, stream>>>(W_att1, wattT);

  k_prep_hi<<<16, 256, 0, stream>>>(W_e2, wsBe);
  k_prep1<<<96,  256, 0, stream>>>(W_ghh, W_ghh, 0, 256, 768,  768,  256, 48, 384, wsBg);
  k_prep1<<<192, 256, 0, stream>>>(W_lih, W_lhh, 0, 128, 1024, 1024, 384, 64, 768, wsBl);
  k_prep1<<<144, 256, 0, stream>>>(W_gh,  W_gih, 1, 256, 256,  768,  264, 64, 576, wsBx);
  k_prep1<<<36,  256, 0, stream>>>(W_a1,  W_a1,  0, 272, 256,  256,  272, 16, 144, wsBa);

  // guide GRU: prologue steps (2 if fused, all 12 otherwise)
  k_xz_mfma<<<dim3(128, 4), 256, 0, stream>>>(hist_enc, z, wsBx, b_gh, b_gih, gh0F, giF);
  const int pre = fuse ? 2 : FTS;
  float* gcur = gh0F;
  float* gnxt = gh1F;
  for (int t = 0; t < pre; t++) {
    k_gru_mfma<<<dim3(128, 4), 256, 0, stream>>>(gcur, wsBg, b_ghh, giF, W_proj,
                                                 des + (size_t)t * N_ * 2, gnxt);
    float* tmp = gcur; gcur = gnxt; gnxt = tmp;
  }

  // main rollout (gru step t+2 fused into edge dispatch when enabled)
  k_init_hc<<<N_, 256, 0, stream>>>(x_last, x_st_last, W_h0, b_h0, W_c0, b_c0,
                                    hA, cbuf, prev, prev_st);
  float* hcur = hA;
  float* hnxt = hB;
  for (int t = 0; t < FTS; t++) {
    const float* des_t = des + (size_t)t * N_ * 2;
    const float* des_n = des + (size_t)((t + 1 < FTS) ? t + 1 : FTS - 1) * N_ * 2;
    const float* des_p = (t > 0) ? des + (size_t)(t - 1) * N_ * 2 : nullptr;
    const int gs = t + 2;
    const int gru_on = (fuse && gs < FTS) ? 1 : 0;
    const float* gin = (gs & 1) ? gh1F : gh0F;
    float* gout      = (gs & 1) ? gh0F : gh1F;
    float* des_g = des + (size_t)((gs < FTS) ? gs : 0) * N_ * 2;
    k_edge_gru<<<2560, 256, 0, stream>>>(prev, prev_st, x_st_last, szf, rad,
                                         nobs, e1, e2, W_e1, b_e1, wsBe, b_e2,
                                         wattT, W_att2, v_att,
                                         des_p, des_t, des_n,
                                         rel, nwp, nwp2, ctx, ss + t, ss + 12,
                                         gin, wsBg, b_ghh, giF, W_proj, des_g, gout, gru_on);
    k_lstm_mfma<<<dim3(128, 8), 256, 0, stream>>>(ctx, hcur, wsBl, b_lih, b_lhh,
                                                  cbuf, hnxt);
    k_action_mfma<<<256, 256, 0, stream>>>(hnxt, z, rel, nwp, nwp2,
                                           wsBa, b_a1, W_a2, b_a2,
                                           prev, prev_st,
                                           out + (size_t)t * N_ * 4,
                                           out + (size_t)FTS * N_ * 4 + (size_t)t * N_ * 2);
    float* tmp = hcur; hcur = hnxt; hnxt = tmp;
  }
  k_final<<<1, 64, 0, stream>>>(ss, out);
}

// Round 10
// 1795.292 us; speedup vs baseline: 2.1258x; 1.0284x over previous
//
#include <hip/hip_runtime.h>

#define DEVI __device__ __forceinline__

constexpr int N_  = 8192;
constexpr int K_  = 15;
constexpr int E_  = N_ * K_;     // 122880
constexpr int FTS = 12;
constexpr float DT_ = 0.25f;

typedef __attribute__((ext_vector_type(8))) short short8x;
typedef __attribute__((ext_vector_type(4))) float float4x;

union U8 { unsigned int u[4]; short8x v; };

DEVI float sigf(float x) { return 1.0f / (1.0f + __expf(-x)); }
DEVI float tanhf_fast(float x) { float e = __expf(2.f * x); return 1.f - 2.f / (e + 1.f); }
DEVI unsigned int f2u(float x) { union { float f; unsigned int u; } c; c.f = x; return c.u; }
DEVI float u2f(unsigned int x) { union { unsigned int u; float f; } c; c.u = x; return c.f; }

DEVI void split8(const float* __restrict__ s, short8x& hi8, short8x& lo8) {
  U8 ph, pl;
#pragma unroll
  for (int p = 0; p < 4; p++) {
    float a0 = s[2*p], a1 = s[2*p+1];
    unsigned int u0 = f2u(a0), u1 = f2u(a1);
    unsigned int h0 = u0 & 0xFFFF0000u, h1 = u1 & 0xFFFF0000u;
    ph.u[p] = (u0 >> 16) | h1;
    float l0 = a0 - u2f(h0), l1 = a1 - u2f(h1);
    pl.u[p] = (f2u(l0) >> 16) | (f2u(l1) & 0xFFFF0000u);
  }
  hi8 = ph.v; lo8 = pl.v;
}

// ---------------------------------------------------------------- zero accum
__global__ void k_zero(float* ss) {
  if (threadIdx.x < 13) ss[threadIdx.x] = 0.f;
}

// ---------------------------------------------------------------- init des to b_proj
__global__ __launch_bounds__(256) void k_init_des(const float* __restrict__ b_proj,
                                                  float* __restrict__ des) {
  int i = blockIdx.x * 256 + threadIdx.x;
  des[i*2]     = b_proj[0];
  des[i*2 + 1] = b_proj[1];
}

// ---------------------------------------------------------------- edge static
__global__ __launch_bounds__(256) void k_edge_static(
    const int* __restrict__ e1, const int* __restrict__ e2,
    const float* __restrict__ nsize, float* __restrict__ rad, float* __restrict__ szf)
{
  int e = blockIdx.x * 256 + threadIdx.x;
  if (e >= E_) return;
  int i1 = e1[e], i2 = e2[e];
  float s1x = nsize[i1*2+0], s1y = nsize[i1*2+1];
  float s2x = nsize[i2*2+0], s2y = nsize[i2*2+1];
  rad[e] = 0.5f * (sqrtf(s1x*s1x + s1y*s1y) + sqrtf(s2x*s2x + s2y*s2y));
  *(float4*)&szf[e*4] = make_float4(s1x, s1y, s2x, s2y);
}

// ---------------------------------------------------------------- hi-only bf16 B-fragments for edge W_e2
__global__ __launch_bounds__(256) void k_prep_hi(
    const float* __restrict__ W, unsigned short* __restrict__ out)
{
  int t = blockIdx.x * 256 + threadIdx.x;   // < 4096
  int fid = t >> 6, L = t & 63;
  int ks = fid >> 3, nt = fid & 7;
  int k0 = ks * 32 + (L >> 4) * 8;
  int n  = nt * 16 + (L & 15);
  unsigned int hi[4];
#pragma unroll
  for (int p = 0; p < 4; p++) {
    float w0 = W[(size_t)(k0 + 2*p) * 128 + n];
    float w1 = W[(size_t)(k0 + 2*p + 1) * 128 + n];
    hi[p] = (f2u(w0) >> 16) | (f2u(w1) & 0xFFFF0000u);
  }
  *(uint4*)(out + (size_t)fid * 512 + (size_t)L * 8) = make_uint4(hi[0], hi[1], hi[2], hi[3]);
}

// ---------------------------------------------------------------- generic hi-only bf16 B-fragment prep
__global__ __launch_bounds__(256) void k_prep1(
    const float* __restrict__ WA, const float* __restrict__ WB,
    int mode, int split, int wA, int wB, int Ktot, int NT, int nfrag,
    unsigned short* __restrict__ out)
{
  int t = blockIdx.x * 256 + threadIdx.x;
  int fid = t >> 6, L = t & 63;
  if (fid >= nfrag) return;
  int ks = fid / NT, nt = fid % NT;
  int k0 = ks * 32 + (L >> 4) * 8;
  int n  = nt * 16 + (L & 15);
  unsigned int hi[4];
#pragma unroll
  for (int p = 0; p < 4; p++) {
    float w0 = 0.f, w1 = 0.f;
    int ka = k0 + 2*p, kb = ka + 1;
    if (mode == 0) {
      if (ka < Ktot) w0 = (ka < split) ? WA[(size_t)ka*wA + n] : WB[(size_t)(ka-split)*wB + n];
      if (kb < Ktot) w1 = (kb < split) ? WA[(size_t)kb*wA + n] : WB[(size_t)(kb-split)*wB + n];
    } else {
      if (ka < Ktot) w0 = (n < split) ? WA[(size_t)ka*wA + n] : WB[(size_t)ka*wB + (n-split)];
      if (kb < Ktot) w1 = (n < split) ? WA[(size_t)kb*wA + n] : WB[(size_t)kb*wB + (n-split)];
    }
    hi[p] = (f2u(w0) >> 16) | (f2u(w1) & 0xFFFF0000u);
  }
  *(uint4*)(out + (size_t)fid * 512 + (size_t)L * 8) = make_uint4(hi[0], hi[1], hi[2], hi[3]);
}

// ---------------------------------------------------------------- xz GEMM (once), B hi-only
__global__ __launch_bounds__(256) void k_xz_mfma(
    const float* __restrict__ hist, const float* __restrict__ z,
    const unsigned short* __restrict__ wB,
    const float* __restrict__ b_gh, const float* __restrict__ b_gih,
    float* __restrict__ gh0, float* __restrict__ gi)
{
  __shared__ __align__(16) float Abuf[64][36];
  const int tid = threadIdx.x;
  const int w = tid >> 6, lane = tid & 63;
  const int m = lane & 15, q = lane >> 4;
  const int n0 = blockIdx.x * 64;
  const int r_ = tid >> 2, c_ = (tid & 3) * 8;
  float4x acc[16];
#pragma unroll
  for (int tl = 0; tl < 16; tl++) acc[tl] = (float4x){0.f,0.f,0.f,0.f};

  for (int ks = 0; ks < 9; ks++) {
    __syncthreads();
    {
      int kk = ks*32 + c_;
      int n = n0 + r_;
      float4 v0, v1;
      if (kk < 256) {
        v0 = *(const float4*)&hist[(size_t)n*256 + kk];
        v1 = *(const float4*)&hist[(size_t)n*256 + kk + 4];
      } else if (kk == 256) {
        v0 = *(const float4*)&z[n*8];
        v1 = *(const float4*)&z[n*8 + 4];
      } else {
        v0 = make_float4(0,0,0,0); v1 = v0;
      }
      *(float4*)&Abuf[r_][c_]     = v0;
      *(float4*)&Abuf[r_][c_ + 4] = v1;
    }
    __syncthreads();
    short8x aHi, aLo;
    split8(&Abuf[w*16 + m][q*8], aHi, aLo);
#pragma unroll
    for (int tl = 0; tl < 16; tl++) {
      int nt = blockIdx.y*16 + tl;
      size_t off = (size_t)(ks*64 + nt) * 512 + (size_t)lane*8;
      short8x bh = *(const short8x*)(wB + off);
      acc[tl] = __builtin_amdgcn_mfma_f32_16x16x32_bf16(aLo, bh, acc[tl], 0, 0, 0);
      acc[tl] = __builtin_amdgcn_mfma_f32_16x16x32_bf16(aHi, bh, acc[tl], 0, 0, 0);
    }
  }
#pragma unroll
  for (int tl = 0; tl < 16; tl++) {
    int col = (blockIdx.y*16 + tl)*16 + m;
    float bias = (col < 256) ? b_gh[col] : b_gih[col - 256];
#pragma unroll
    for (int i = 0; i < 4; i++) {
      int n = n0 + w*16 + q*4 + i;
      float v = acc[tl][i] + bias;
      if (col < 256) gh0[(size_t)n*256 + col] = v;
      else           gi[(size_t)n*768 + col - 256] = v;
    }
  }
}

// ---------------------------------------------------------------- GRU core (shared), B hi-only
DEVI void gru_core(float (*Abuf)[36], int tid, int n0, int j0,
                   const float* __restrict__ h_in, const unsigned short* __restrict__ wB,
                   const float* __restrict__ b_hh, const float* __restrict__ gi,
                   const float* __restrict__ W_proj, float* __restrict__ des_t,
                   float* __restrict__ h_out)
{
  const int w = tid >> 6, lane = tid & 63;
  const int m = lane & 15, q = lane >> 4;
  const int r_ = tid >> 2, c_ = (tid & 3) * 8;
  float4x acc[12];
#pragma unroll
  for (int tl = 0; tl < 12; tl++) acc[tl] = (float4x){0.f,0.f,0.f,0.f};

  for (int ks = 0; ks < 8; ks++) {
    __syncthreads();
    {
      int kk = ks*32 + c_;
      int n = n0 + r_;
      *(float4*)&Abuf[r_][c_]     = *(const float4*)&h_in[(size_t)n*256 + kk];
      *(float4*)&Abuf[r_][c_ + 4] = *(const float4*)&h_in[(size_t)n*256 + kk + 4];
    }
    __syncthreads();
    short8x aHi, aLo;
    split8(&Abuf[w*16 + m][q*8], aHi, aLo);
#pragma unroll
    for (int tl = 0; tl < 12; tl++) {
      int g = tl >> 2, jt = tl & 3;
      int nt = g*16 + (j0 >> 4) + jt;
      size_t off = (size_t)(ks*48 + nt) * 512 + (size_t)lane*8;
      short8x bh = *(const short8x*)(wB + off);
      acc[tl] = __builtin_amdgcn_mfma_f32_16x16x32_bf16(aLo, bh, acc[tl], 0, 0, 0);
      acc[tl] = __builtin_amdgcn_mfma_f32_16x16x32_bf16(aHi, bh, acc[tl], 0, 0, 0);
    }
  }
  float pd0[4] = {0,0,0,0}, pd1[4] = {0,0,0,0};
#pragma unroll
  for (int jt = 0; jt < 4; jt++) {
    int j = j0 + jt*16 + m;
    float br = b_hh[j], bz = b_hh[256 + j], bn = b_hh[512 + j];
    float wp0 = W_proj[j*2], wp1 = W_proj[j*2 + 1];
#pragma unroll
    for (int i = 0; i < 4; i++) {
      int n = n0 + w*16 + q*4 + i;
      float ir  = gi[(size_t)n*768 + j];
      float iz  = gi[(size_t)n*768 + 256 + j];
      float inn = gi[(size_t)n*768 + 512 + j];
      float hold = h_in[(size_t)n*256 + j];
      float r = sigf(ir + acc[0*4 + jt][i] + br);
      float u = sigf(iz + acc[1*4 + jt][i] + bz);
      float nh = (1.f - u) * tanhf_fast(inn + r * (acc[2*4 + jt][i] + bn)) + u * hold;
      h_out[(size_t)n*256 + j] = nh;
      pd0[i] += nh * wp0;
      pd1[i] += nh * wp1;
    }
  }
#pragma unroll
  for (int off = 1; off < 16; off <<= 1) {
#pragma unroll
    for (int i = 0; i < 4; i++) {
      pd0[i] += __shfl_xor(pd0[i], off);
      pd1[i] += __shfl_xor(pd1[i], off);
    }
  }
  if (m == 0) {
#pragma unroll
    for (int i = 0; i < 4; i++) {
      int n = n0 + w*16 + q*4 + i;
      atomicAdd(&des_t[n*2],     pd0[i]);
      atomicAdd(&des_t[n*2 + 1], pd1[i]);
    }
  }
}

// ---------------------------------------------------------------- standalone GRU step (prologue)
__global__ __launch_bounds__(256) void k_gru_mfma(
    const float* __restrict__ h_in, const unsigned short* __restrict__ wB,
    const float* __restrict__ b_hh, const float* __restrict__ gi,
    const float* __restrict__ W_proj, float* __restrict__ des_t,
    float* __restrict__ h_out)
{
  __shared__ __align__(16) float Abuf[64][36];
  gru_core(Abuf, threadIdx.x, blockIdx.x * 64, blockIdx.y * 64,
           h_in, wB, b_hh, gi, W_proj, des_t, h_out);
}

// ---------------------------------------------------------------- LSTM cell (MFMA), j-tile = 32, B hi-only
__global__ __launch_bounds__(256) void k_lstm_mfma(
    const float* __restrict__ ctxg, const float* __restrict__ h_in,
    const unsigned short* __restrict__ wB,
    const float* __restrict__ b_ih, const float* __restrict__ b_hh,
    float* __restrict__ c_st, float* __restrict__ h_out)
{
  __shared__ __align__(16) float Abuf[64][36];
  const int tid = threadIdx.x;
  const int w = tid >> 6, lane = tid & 63;
  const int m = lane & 15, q = lane >> 4;
  const int n0 = blockIdx.x * 64;
  const int j0 = blockIdx.y * 32;
  const int r_ = tid >> 2, c_ = (tid & 3) * 8;
  float4x acc[8];
#pragma unroll
  for (int tl = 0; tl < 8; tl++) acc[tl] = (float4x){0.f,0.f,0.f,0.f};

  for (int ks = 0; ks < 12; ks++) {
    __syncthreads();
    {
      int kk = ks*32 + c_;
      int n = n0 + r_;
      float4 v0, v1;
      if (kk < 128) {
        v0 = *(const float4*)&ctxg[(size_t)n*128 + kk];
        v1 = *(const float4*)&ctxg[(size_t)n*128 + kk + 4];
      } else {
        v0 = *(const float4*)&h_in[(size_t)n*256 + kk - 128];
        v1 = *(const float4*)&h_in[(size_t)n*256 + kk - 124];
      }
      *(float4*)&Abuf[r_][c_]     = v0;
      *(float4*)&Abuf[r_][c_ + 4] = v1;
    }
    __syncthreads();
    short8x aHi, aLo;
    split8(&Abuf[w*16 + m][q*8], aHi, aLo);
#pragma unroll
    for (int tl = 0; tl < 8; tl++) {
      int g = tl >> 1, jt = tl & 1;
      int nt = g*16 + (j0 >> 4) + jt;
      size_t off = (size_t)(ks*64 + nt) * 512 + (size_t)lane*8;
      short8x bh = *(const short8x*)(wB + off);
      acc[tl] = __builtin_amdgcn_mfma_f32_16x16x32_bf16(aLo, bh, acc[tl], 0, 0, 0);
      acc[tl] = __builtin_amdgcn_mfma_f32_16x16x32_bf16(aHi, bh, acc[tl], 0, 0, 0);
    }
  }
#pragma unroll
  for (int jt = 0; jt < 2; jt++) {
    int j = j0 + jt*16 + m;
    float bi = b_ih[j]       + b_hh[j];
    float bf = b_ih[256 + j] + b_hh[256 + j];
    float bg = b_ih[512 + j] + b_hh[512 + j];
    float bo = b_ih[768 + j] + b_hh[768 + j];
#pragma unroll
    for (int i = 0; i < 4; i++) {
      int n = n0 + w*16 + q*4 + i;
      float g_i = sigf(acc[0*2 + jt][i] + bi);
      float g_f = sigf(acc[1*2 + jt][i] + bf);
      float g_g = tanhf_fast(acc[2*2 + jt][i] + bg);
      float g_o = sigf(acc[3*2 + jt][i] + bo);
      float cv = g_f * c_st[(size_t)n*256 + j] + g_i * g_g;
      c_st[(size_t)n*256 + j] = cv;
      h_out[(size_t)n*256 + j] = g_o * tanhf_fast(cv);
    }
  }
}

// ---------------------------------------------------------------- action MLP: 32 nodes/block, B hi-only
__global__ __launch_bounds__(256) void k_action_mfma(
    const float* __restrict__ h, const float* __restrict__ z,
    const float* __restrict__ rel, const float* __restrict__ nwp, const float* __restrict__ nwp2,
    const unsigned short* __restrict__ wB, const float* __restrict__ b_a1,
    const float* __restrict__ W_a2, const float* __restrict__ b_a2,
    float* __restrict__ prev, float* __restrict__ prev_st,
    float* __restrict__ outS, float* __restrict__ outU)
{
  __shared__ __align__(16) float Abuf[32][36];
  __shared__ float sm_p[2][16][2];
  const int tid = threadIdx.x;
  const int w = tid >> 6, lane = tid & 63;
  const int m = lane & 15, q = lane >> 4;
  const int ng = w >> 1, hh = w & 1;
  const int n0 = blockIdx.x * 32;
  const int r_ = tid >> 3, c_ = (tid & 7) * 4;
  float4x acc[8];
#pragma unroll
  for (int j = 0; j < 8; j++) acc[j] = (float4x){0.f,0.f,0.f,0.f};

  for (int ks = 0; ks < 9; ks++) {
    __syncthreads();
    {
      int kk = ks*32 + c_;
      int n = n0 + r_;
      float4 v;
      if (kk < 256)      v = *(const float4*)&h[(size_t)n*256 + kk];
      else if (kk == 256) v = *(const float4*)&z[n*8];
      else if (kk == 260) v = *(const float4*)&z[n*8 + 4];
      else if (kk == 264) v = *(const float4*)&rel[n*4];
      else if (kk == 268) {
        float2 w1 = *(const float2*)&nwp[n*2];
        float2 w2 = *(const float2*)&nwp2[n*2];
        v = make_float4(w1.x, w1.y, w2.x, w2.y);
      } else v = make_float4(0,0,0,0);
      *(float4*)&Abuf[r_][c_] = v;
    }
    __syncthreads();
    short8x aHi, aLo;
    split8(&Abuf[ng*16 + m][q*8], aHi, aLo);
#pragma unroll
    for (int j = 0; j < 8; j++) {
      int tl = hh*8 + j;
      size_t off = (size_t)(ks*16 + tl) * 512 + (size_t)lane*8;
      short8x bh = *(const short8x*)(wB + off);
      acc[j] = __builtin_amdgcn_mfma_f32_16x16x32_bf16(aLo, bh, acc[j], 0, 0, 0);
      acc[j] = __builtin_amdgcn_mfma_f32_16x16x32_bf16(aHi, bh, acc[j], 0, 0, 0);
    }
  }
  float p0[4] = {0,0,0,0}, p1[4] = {0,0,0,0};
#pragma unroll
  for (int j = 0; j < 8; j++) {
    int col = (hh*8 + j)*16 + m;
    float ba = b_a1[col];
    float2 w2 = *(const float2*)&W_a2[col*2];
#pragma unroll
    for (int i = 0; i < 4; i++) {
      float hv = fmaxf(acc[j][i] + ba, 0.f);
      p0[i] += hv * w2.x;
      p1[i] += hv * w2.y;
    }
  }
#pragma unroll
  for (int off = 1; off < 16; off <<= 1) {
#pragma unroll
    for (int i = 0; i < 4; i++) {
      p0[i] += __shfl_xor(p0[i], off);
      p1[i] += __shfl_xor(p1[i], off);
    }
  }
  if (hh == 1 && m == 0) {
#pragma unroll
    for (int i = 0; i < 4; i++) {
      sm_p[ng][q*4 + i][0] = p0[i];
      sm_p[ng][q*4 + i][1] = p1[i];
    }
  }
  __syncthreads();
  if (hh == 0 && m == 0) {
    float ba0 = b_a2[0], ba1 = b_a2[1];
    const float hd = 0.5f * DT_ * DT_;
#pragma unroll
    for (int i = 0; i < 4; i++) {
      int n = n0 + ng*16 + q*4 + i;
      float ux = tanhf_fast(p0[i] + sm_p[ng][q*4 + i][0] + ba0);
      float uy = tanhf_fast(p1[i] + sm_p[ng][q*4 + i][1] + ba1);
      float4 pv = *(const float4*)&prev[n*4];
      float4 ps = *(const float4*)&prev_st[n*4];
      float4 npv, nps;
      npv.x = pv.x + pv.z*DT_ + ux*hd;
      npv.y = pv.y + pv.w*DT_ + uy*hd;
      npv.z = pv.z + ux*DT_;
      npv.w = pv.w + uy*DT_;
      nps.x = ps.x + ps.z*DT_ + ux*hd;
      nps.y = ps.y + ps.w*DT_ + uy*hd;
      nps.z = ps.z + ux*DT_;
      nps.w = ps.w + uy*DT_;
      *(float4*)&prev[n*4] = npv;
      *(float4*)&prev_st[n*4] = nps;
      *(float4*)&outS[(size_t)n*4] = npv;
      outU[n*2]     = ux;
      outU[n*2 + 1] = uy;
    }
  }
}

// ---------------------------------------------------------------- LSTM h0/c0 + prev copies
__global__ __launch_bounds__(256) void k_init_hc(
    const float* __restrict__ x_last, const float* __restrict__ x_st_last,
    const float* __restrict__ W_h0, const float* __restrict__ b_h0,
    const float* __restrict__ W_c0, const float* __restrict__ b_c0,
    float* __restrict__ h, float* __restrict__ c,
    float* __restrict__ prev, float* __restrict__ prev_st)
{
  const int n = blockIdx.x;
  const int j = threadIdx.x;
  float x0 = x_st_last[n*4], x1 = x_st_last[n*4+1], x2 = x_st_last[n*4+2], x3 = x_st_last[n*4+3];
  h[(size_t)n*256 + j] = b_h0[j] + x0*W_h0[j] + x1*W_h0[256+j] + x2*W_h0[512+j] + x3*W_h0[768+j];
  c[(size_t)n*256 + j] = b_c0[j] + x0*W_c0[j] + x1*W_c0[256+j] + x2*W_c0[512+j] + x3*W_c0[768+j];
  if (j < 4) prev[n*4 + j] = x_last[n*4 + j];
  else if (j < 8) prev_st[n*4 + (j-4)] = x_st_last[n*4 + (j-4)];
}

// ---------------------------------------------------------------- FUSED: edge (blocks 0..2047, 4 nodes) | GRU (blocks 2048..2559)
// (256,4) proven no-spill. B hi-only everywhere. Scores via MFMA (in-wave LDS transpose); P4 deleted.
__global__ __launch_bounds__(256, 4) void k_edge_gru(
    const float* __restrict__ prev, const float* __restrict__ prev_st,
    const float* __restrict__ x_st_last,
    const float* __restrict__ szf, const float* __restrict__ rad,
    const int* __restrict__ nobs, const int* __restrict__ e1, const int* __restrict__ e2,
    const float* __restrict__ W_e1, const float* __restrict__ b_e1,
    const unsigned short* __restrict__ wsB, const float* __restrict__ b_e2,
    const unsigned short* __restrict__ wattA, const float* __restrict__ W_att2,
    const float* __restrict__ v_att,
    const float* __restrict__ des_p, const float* __restrict__ des_t,
    const float* __restrict__ des_n,
    float* __restrict__ relg, float* __restrict__ nwp, float* __restrict__ nwp2,
    float* __restrict__ ctx, float* __restrict__ ss_t, float* __restrict__ cc,
    const float* __restrict__ g_hin, const unsigned short* __restrict__ wBg,
    const float* __restrict__ b_ghh, const float* __restrict__ gi,
    const float* __restrict__ W_proj, float* __restrict__ des_g,
    float* __restrict__ g_hout, int gru_on)
{
  // LDS (floats): stage 2x2048 @0 (also reused per-wave 16x36 transpose regions)
  //   feats[512]@4096 | flags[64]@4608 | relv[16]@4672 | watt2[64]@4688 | vatt[16]@4752 | red[8]@4768 -> 4776
  __shared__ __align__(16) float smem[4776];
  const int tid = threadIdx.x;

  if (blockIdx.x >= 2048) {
    if (!gru_on) return;
    int b = blockIdx.x - 2048;
    gru_core((float(*)[36])smem, tid, (b & 127) * 64, (b >> 7) * 64,
             g_hin, wBg, b_ghh, gi, W_proj, des_g, g_hout);
    return;
  }

  float* sm_stage = smem;
  float* sm_feats = smem + 4096;
  float* sm_flags = smem + 4608;
  float* sm_relv  = smem + 4672;
  float* sm_watt2 = smem + 4688;
  float* sm_vatt  = smem + 4752;
  float* sm_red   = smem + 4768;

  const int n0  = blockIdx.x * 4;
  const int lane = tid & 63;
  const int g    = tid >> 6;
  const int q = lane >> 4, m = lane & 15;

  // ---- P0
  if (tid >= 176 && tid < 192) sm_vatt[tid - 176] = v_att[tid - 176];
  if (tid >= 192) sm_watt2[tid - 192] = W_att2[tid - 192];

  if (tid < 64) {
    float v = 0.f;
    if (tid < 60) {
      int gg = tid / 15, k = tid % 15;
      int idx = nobs[(n0 + gg) * 15 + k];
      float f[8] = {0,0,0,0,0,0,0,0};
      float fl = 0.f;
      if (idx > 0) {
        int e = idx - 1;
        int i1 = e1[e], i2 = e2[e];
#pragma unroll
        for (int d = 0; d < 4; d++) f[d] = prev[i2*4 + d] - prev[i1*4 + d];
        float4 sz = *(const float4*)&szf[(size_t)e*4];
        f[4] = sz.x; f[5] = sz.y; f[6] = sz.z; f[7] = sz.w;
        fl = 1.f;
        float dist = sqrtf(f[0]*f[0] + f[1]*f[1]);
        v = fmaxf(rad[e] - dist, 0.f);
      }
#pragma unroll
      for (int d = 0; d < 8; d++) sm_feats[(gg*16 + k)*8 + d] = f[d];
      sm_flags[gg*16 + k] = fl;
    } else {
      int gg = tid - 60;
#pragma unroll
      for (int d = 0; d < 8; d++) sm_feats[(gg*16 + 15)*8 + d] = 0.f;
      sm_flags[gg*16 + 15] = 0.f;
    }
#pragma unroll
    for (int off = 32; off; off >>= 1) v += __shfl_down(v, off);
    if (tid == 0) atomicAdd(cc, v);
  } else if (tid < 68) {
    int gg = tid - 64;
    int n = n0 + gg;
    float4 ps = *(const float4*)&prev_st[n*4];
    float r0, r1, r2, r3;
    if (des_p) {
      float4 xs = *(const float4*)&x_st_last[n*4];
      r0 = ps.x - xs.x - des_p[n*2];
      r1 = ps.y - xs.y - des_p[n*2 + 1];
      r2 = ps.z - xs.z;
      r3 = ps.w - xs.w;
    } else { r0 = ps.x; r1 = ps.y; r2 = ps.z; r3 = ps.w; }
    sm_relv[gg*4+0] = r0; sm_relv[gg*4+1] = r1; sm_relv[gg*4+2] = r2; sm_relv[gg*4+3] = r3;
    *(float4*)&relg[n*4] = make_float4(r0, r1, r2, r3);
    nwp[n*2]      = des_t[n*2]     - ps.x;
    nwp[n*2 + 1]  = des_t[n*2 + 1] - ps.y;
    nwp2[n*2]     = des_n[n*2]     - ps.x;
    nwp2[n*2 + 1] = des_n[n*2 + 1] - ps.y;
    sm_red[gg] = r0*r0 + r1*r1;
  }
  // initial stage of ks=0 (hi-only, 8KB) into buf0
  {
    const uint4* src = (const uint4*)wsB;
    uint4* dst = (uint4*)sm_stage;
    dst[tid]       = src[tid];
    dst[tid + 256] = src[tid + 256];
  }
  __syncthreads();
  if (tid == 64) atomicAdd(ss_t, sm_red[0] + sm_red[1] + sm_red[2] + sm_red[3]);

  // ---- P1+P2 pipelined over ks
  float f[8];
  {
    const float4 fa = *(const float4*)&sm_feats[(g*16 + m)*8];
    const float4 fb = *(const float4*)&sm_feats[(g*16 + m)*8 + 4];
    f[0]=fa.x; f[1]=fa.y; f[2]=fa.z; f[3]=fa.w; f[4]=fb.x; f[5]=fb.y; f[6]=fb.z; f[7]=fb.w;
  }
  float4x encR[8];
#pragma unroll
  for (int nt = 0; nt < 8; nt++) encR[nt] = (float4x){0.f,0.f,0.f,0.f};
  const float4* We14 = (const float4*)W_e1;
  const float4* Be14 = (const float4*)b_e1;

  for (int ks = 0; ks < 8; ks++) {
    uint4 r0, r1;
    if (ks < 7) {
      const uint4* src = (const uint4*)wsB + (ks + 1) * 512;
      r0 = src[tid];
      r1 = src[tid + 256];
    }
    short8x aHi, aLo;
    {
      float h8[8];
      float4 b0 = Be14[8*ks + 2*q];
      float4 b1 = Be14[8*ks + 2*q + 1];
      h8[0]=b0.x; h8[1]=b0.y; h8[2]=b0.z; h8[3]=b0.w; h8[4]=b1.x; h8[5]=b1.y; h8[6]=b1.z; h8[7]=b1.w;
#pragma unroll
      for (int d = 0; d < 8; d++) {
        float4 wa = We14[d*64 + ks*8 + 2*q];
        float4 wb = We14[d*64 + ks*8 + 2*q + 1];
        h8[0] += f[d]*wa.x; h8[1] += f[d]*wa.y; h8[2] += f[d]*wa.z; h8[3] += f[d]*wa.w;
        h8[4] += f[d]*wb.x; h8[5] += f[d]*wb.y; h8[6] += f[d]*wb.z; h8[7] += f[d]*wb.w;
      }
#pragma unroll
      for (int p = 0; p < 8; p++) h8[p] = fmaxf(h8[p], 0.f);
      split8(h8, aHi, aLo);
    }
    const unsigned short* sb = (const unsigned short*)sm_stage + (ks & 1) * 4096;
#pragma unroll
    for (int nt = 0; nt < 8; nt++) {
      short8x bh = *(const short8x*)(sb + nt*512 + lane*8);
      encR[nt] = __builtin_amdgcn_mfma_f32_16x16x32_bf16(aLo, bh, encR[nt], 0, 0, 0);
      encR[nt] = __builtin_amdgcn_mfma_f32_16x16x32_bf16(aHi, bh, encR[nt], 0, 0, 0);
    }
    if (ks < 7) {
      uint4* dst = (uint4*)sm_stage + ((ks + 1) & 1) * 512;
      dst[tid]       = r0;
      dst[tid + 256] = r1;
      __syncthreads();
    }
  }
  float4x fl4 = *(const float4x*)&sm_flags[g*16 + q*4];
#pragma unroll
  for (int nt = 0; nt < 8; nt++) {
    float b2 = b_e2[nt*16 + m];
#pragma unroll
    for (int i = 0; i < 4; i++) encR[nt][i] = (encR[nt][i] + b2) * fl4[i];
  }

  // ---- P3': scores = enc @ W_att1 via MFMA; per-wave 16x36 LDS transpose region.
  // All waves must be done reading stage B-frags before we overwrite stage:
  __syncthreads();
  {
  }
  float* tb = sm_stage + g * 576;   // 16 rows x 36 (4 waves -> 2304 <= 4096)
  float4x sacc = {0.f, 0.f, 0.f, 0.f};
#pragma unroll
  for (int ksc = 0; ksc < 4; ksc++) {
    // write enc chunk [edge][32 chans] (chans ksc*32..+31)
#pragma unroll
    for (int ntl = 0; ntl < 2; ntl++) {
#pragma unroll
      for (int i = 0; i < 4; i++)
        tb[(q*4 + i)*36 + ntl*16 + m] = encR[2*ksc + ntl][i];
    }
    __builtin_amdgcn_s_waitcnt(0);   // wave-synchronous: all 64 lanes' writes drained
    float a8[8];
    {
      const float4* tp = (const float4*)(tb + m*36 + q*8);
      float4 t0 = tp[0], t1 = tp[1];
      a8[0]=t0.x; a8[1]=t0.y; a8[2]=t0.z; a8[3]=t0.w;
      a8[4]=t1.x; a8[5]=t1.y; a8[6]=t1.z; a8[7]=t1.w;
    }
    __builtin_amdgcn_s_waitcnt(0);   // reads drained before next iter's writes
    short8x aH, aL;
    split8(a8, aH, aL);
    short8x bh = *(const short8x*)(wattA + ksc*512 + lane*8);
    sacc = __builtin_amdgcn_mfma_f32_16x16x32_bf16(aL, bh, sacc, 0, 0, 0);
    sacc = __builtin_amdgcn_mfma_f32_16x16x32_bf16(aH, bh, sacc, 0, 0, 0);
  }
  // sacc: lane (q,m) holds score[edge=q*4+i][a=m]

  // ---- P5: softmax + ctx
  float relw;
  {
    float4 rv = *(const float4*)&sm_relv[g*4];
    relw = rv.x * sm_watt2[m] + rv.y * sm_watt2[16 + m]
         + rv.z * sm_watt2[32 + m] + rv.w * sm_watt2[48 + m];
  }
  float vat = sm_vatt[m];
  float val[4];
#pragma unroll
  for (int i = 0; i < 4; i++) val[i] = tanhf_fast(sacc[i] + relw) * vat;
#pragma unroll
  for (int msk = 1; msk < 16; msk <<= 1) {
#pragma unroll
    for (int i = 0; i < 4; i++) val[i] += __shfl_xor(val[i], msk);
  }
  if (q == 3) val[3] = -3.0e38f;
  float mx = fmaxf(fmaxf(val[0], val[1]), fmaxf(val[2], val[3]));
  mx = fmaxf(mx, __shfl_xor(mx, 16));
  mx = fmaxf(mx, __shfl_xor(mx, 32));
  float4x ev;
  float ssum = 0.f;
#pragma unroll
  for (int i = 0; i < 4; i++) { ev[i] = __expf(val[i] - mx); ssum += ev[i]; }
  ssum += __shfl_xor(ssum, 16);
  ssum += __shfl_xor(ssum, 32);
  float inv = 1.f / ssum;
#pragma unroll
  for (int i = 0; i < 4; i++) ev[i] *= inv;

  float cpart[8];
#pragma unroll
  for (int nt = 0; nt < 8; nt++) {
    float cv = ev[0]*encR[nt][0] + ev[1]*encR[nt][1] + ev[2]*encR[nt][2] + ev[3]*encR[nt][3];
    cv += __shfl_xor(cv, 16);
    cv += __shfl_xor(cv, 32);
    cpart[nt] = cv;
  }
  float v0 = (q == 0) ? cpart[0] : (q == 1) ? cpart[2] : (q == 2) ? cpart[4] : cpart[6];
  float v1 = (q == 0) ? cpart[1] : (q == 1) ? cpart[3] : (q == 2) ? cpart[5] : cpart[7];
  size_t cb = (size_t)(n0 + g) * 128 + q*32 + m;
  ctx[cb]      = v0;
  ctx[cb + 16] = v1;
}

// ---------------------------------------------------------------- finalize scalars
__global__ void k_final(const float* __restrict__ ss, float* __restrict__ out) {
  if (threadIdx.x == 0) {
    float t = 0.f;
    for (int i = 0; i < FTS; i++) t += sqrtf(ss[i]);
    out[(size_t)FTS * N_ * 6]     = t / (float)N_;
    out[(size_t)FTS * N_ * 6 + 1] = ss[FTS];
  }
}

// ================================================================ launch
extern "C" void kernel_launch(void* const* d_in, const int* in_sizes, int n_in,
                              void* d_out, int out_size, void* d_ws, size_t ws_size,
                              hipStream_t stream) {
  (void)in_sizes; (void)n_in; (void)out_size;
  const float* x_last    = (const float*)d_in[0];
  const float* x_st_last = (const float*)d_in[1];
  const float* hist_enc  = (const float*)d_in[2];
  const float* z         = (const float*)d_in[3];
  const float* node_size = (const float*)d_in[4];
  const float* W_h0 = (const float*)d_in[5];
  const float* b_h0 = (const float*)d_in[6];
  const float* W_c0 = (const float*)d_in[7];
  const float* b_c0 = (const float*)d_in[8];
  const float* W_gh = (const float*)d_in[9];
  const float* b_gh = (const float*)d_in[10];
  const float* W_gih = (const float*)d_in[11];
  const float* W_ghh = (const float*)d_in[12];
  const float* b_gih = (const float*)d_in[13];
  const float* b_ghh = (const float*)d_in[14];
  const float* W_proj = (const float*)d_in[15];
  const float* b_proj = (const float*)d_in[16];
  const float* W_att1 = (const float*)d_in[17];
  const float* W_att2 = (const float*)d_in[18];
  const float* v_att  = (const float*)d_in[19];
  const float* W_lih = (const float*)d_in[20];
  const float* W_lhh = (const float*)d_in[21];
  const float* b_lih = (const float*)d_in[22];
  const float* b_lhh = (const float*)d_in[23];
  const float* W_e1 = (const float*)d_in[24];
  const float* b_e1 = (const float*)d_in[25];
  const float* W_e2 = (const float*)d_in[26];
  const float* b_e2 = (const float*)d_in[27];
  const float* W_a1 = (const float*)d_in[28];
  const float* b_a1 = (const float*)d_in[29];
  const float* W_a2 = (const float*)d_in[30];
  const float* b_a2 = (const float*)d_in[31];
  const int* e1   = (const int*)d_in[32];
  const int* e2   = (const int*)d_in[33];
  const int* nobs = (const int*)d_in[34];
  float* out = (float*)d_out;

  // workspace carve (floats)
  float* wsf     = (float*)d_ws;
  float* prev    = wsf;
  float* prev_st = wsf + 32768;
  float* des     = wsf + 65536;
  float* ss      = wsf + 262144;
  float* rad     = wsf + 262160;
  float* szf     = wsf + 385040;            // -> end 876560
  float* baseA   = wsf + 876560;            // union region, 5 units of N*256 -> end 11362320
  // serial-phase aliased view
  float* gh0 = baseA;
  float* gh1 = baseA + (size_t)N_ * 256;
  float* gi  = baseA + (size_t)2 * N_ * 256;
  // main phase view
  float* hA   = baseA;
  float* hB   = baseA + (size_t)N_ * 256;
  float* cbuf = baseA + (size_t)2 * N_ * 256;
  float* ctx  = baseA + (size_t)3 * N_ * 256;
  float* rel  = baseA + (size_t)4 * N_ * 256;
  float* nwp  = rel + (size_t)N_ * 4;
  float* nwp2 = nwp + (size_t)N_ * 2;
  // prepped B fragments (hi-only)
  unsigned short* wsBe = (unsigned short*)(wsf + 11362320);
  unsigned short* wsBg = (unsigned short*)(wsf + 11427856);
  unsigned short* wsBl = (unsigned short*)(wsf + 11624464);
  unsigned short* wsBx = (unsigned short*)(wsf + 12017680);
  unsigned short* wsBa = (unsigned short*)(wsf + 12312592);
  unsigned short* wattA = (unsigned short*)(wsf + 12386320);  // 4 frags (2048 ush) in old wattT slot
  // fused-path GRU buffers (disjoint from main-phase aliases)
  float* ext = wsf + 12388368;
  const size_t needF = 12388368ull + 5ull * N_ * 256ull;
  const bool fuse = ws_size >= needF * 4ull;
  float* gh0F = fuse ? ext : gh0;
  float* gh1F = fuse ? (ext + (size_t)N_ * 256) : gh1;
  float* giF  = fuse ? (ext + (size_t)2 * N_ * 256) : gi;

  k_zero<<<1, 64, 0, stream>>>(ss);
  k_edge_static<<<(E_ + 255) / 256, 256, 0, stream>>>(e1, e2, node_size, rad, szf);
  k_init_des<<<FTS * N_ / 256, 256, 0, stream>>>(b_proj, des);

  k_prep_hi<<<16, 256, 0, stream>>>(W_e2, wsBe);
  k_prep1<<<96,  256, 0, stream>>>(W_ghh, W_ghh, 0, 256, 768,  768,  256, 48, 384, wsBg);
  k_prep1<<<192, 256, 0, stream>>>(W_lih, W_lhh, 0, 128, 1024, 1024, 384, 64, 768, wsBl);
  k_prep1<<<144, 256, 0, stream>>>(W_gh,  W_gih, 1, 256, 256,  768,  264, 64, 576, wsBx);
  k_prep1<<<36,  256, 0, stream>>>(W_a1,  W_a1,  0, 272, 256,  256,  272, 16, 144, wsBa);
  k_prep1<<<1,   256, 0, stream>>>(W_att1, W_att1, 0, 128, 16, 16, 128, 1, 4, wattA);

  // guide GRU: prologue steps (2 if fused, all 12 otherwise)
  k_xz_mfma<<<dim3(128, 4), 256, 0, stream>>>(hist_enc, z, wsBx, b_gh, b_gih, gh0F, giF);
  const int pre = fuse ? 2 : FTS;
  float* gcur = gh0F;
  float* gnxt = gh1F;
  for (int t = 0; t < pre; t++) {
    k_gru_mfma<<<dim3(128, 4), 256, 0, stream>>>(gcur, wsBg, b_ghh, giF, W_proj,
                                                 des + (size_t)t * N_ * 2, gnxt);
    float* tmp = gcur; gcur = gnxt; gnxt = tmp;
  }

  // main rollout (gru step t+2 fused into edge dispatch when enabled)
  k_init_hc<<<N_, 256, 0, stream>>>(x_last, x_st_last, W_h0, b_h0, W_c0, b_c0,
                                    hA, cbuf, prev, prev_st);
  float* hcur = hA;
  float* hnxt = hB;
  for (int t = 0; t < FTS; t++) {
    const float* des_t = des + (size_t)t * N_ * 2;
    const float* des_n = des + (size_t)((t + 1 < FTS) ? t + 1 : FTS - 1) * N_ * 2;
    const float* des_p = (t > 0) ? des + (size_t)(t - 1) * N_ * 2 : nullptr;
    const int gs = t + 2;
    const int gru_on = (fuse && gs < FTS) ? 1 : 0;
    const float* gin = (gs & 1) ? gh1F : gh0F;
    float* gout      = (gs & 1) ? gh0F : gh1F;
    float* des_g = des + (size_t)((gs < FTS) ? gs : 0) * N_ * 2;
    k_edge_gru<<<2560, 256, 0, stream>>>(prev, prev_st, x_st_last, szf, rad,
                                         nobs, e1, e2, W_e1, b_e1, wsBe, b_e2,
                                         wattA, W_att2, v_att,
                                         des_p, des_t, des_n,
                                         rel, nwp, nwp2, ctx, ss + t, ss + 12,
                                         gin, wsBg, b_ghh, giF, W_proj, des_g, gout, gru_on);
    k_lstm_mfma<<<dim3(128, 8), 256, 0, stream>>>(ctx, hcur, wsBl, b_lih, b_lhh,
                                                  cbuf, hnxt);
    k_action_mfma<<<256, 256, 0, stream>>>(hnxt, z, rel, nwp, nwp2,
                                           wsBa, b_a1, W_a2, b_a2,
                                           prev, prev_st,
                                           out + (size_t)t * N_ * 4,
                                           out + (size_t)FTS * N_ * 4 + (size_t)t * N_ * 2);
    float* tmp = hcur; hcur = hnxt; hnxt = tmp;
  }
  k_final<<<1, 64, 0, stream>>>(ss, out);
}